// Round 14
// baseline (199.867 us; speedup 1.0000x reference)
//
#include <hip/hip_runtime.h>
#include <float.h>

#define N_PTS 6144
#define D_IN  512
#define H1_DIM 256
#define H2_DIM 128
#define G_DIM  64
#define KNN    32
#define NOUT   22

typedef short s8v __attribute__((ext_vector_type(8)));   // 8 bf16 in 4 VGPR
typedef float f32x4 __attribute__((ext_vector_type(4)));
typedef unsigned u32x4 __attribute__((ext_vector_type(4)));
typedef unsigned short u16;
typedef unsigned long long u64;

__device__ __forceinline__ u16 f2bf(float f) {
  unsigned u = __float_as_uint(f);
  u += 0x7FFFu + ((u >> 16) & 1u);          // RNE to bf16
  return (u16)(u >> 16);
}
__device__ __forceinline__ float bf2f(u16 s) {
  return __uint_as_float(((unsigned)s) << 16);
}
__device__ __forceinline__ void split3(float v, u16& a0, u16& a1, u16& a2) {
  a0 = f2bf(v);
  float r1 = v - bf2f(a0);
  a1 = f2bf(r1);
  a2 = f2bf(r1 - bf2f(a1));
}

// ---------------------------------------------------------------------------
// MFMA GEMM, 3-way bf16 split, 6-term schedule (fp32-equivalent).
// C[M,N] = A[M,K] * B^T[N,K].  BN=64, BK=32, 4 waves (2x2), wave tile (BM/2)x32.
// WKEY: epilogue writes sortable-u32 kNN keys (sq[col] - 2*val; diag=UINT_MAX).
// ---------------------------------------------------------------------------
template<int BM, bool AF32, bool SPLITK, bool BIAS, bool RELU, bool WF32, bool WSPLIT, bool WKEY>
__global__ __launch_bounds__(256, 4) void mfma_gemm(
    const void* __restrict__ A0any, const u16* __restrict__ A1_, const u16* __restrict__ A2_,
    const u16* __restrict__ B0_, const u16* __restrict__ B1_, const u16* __restrict__ B2_,
    const float* __restrict__ bias,
    float* __restrict__ Cf, u16* __restrict__ C0, u16* __restrict__ C1, u16* __restrict__ C2,
    int Ktot, int Ks, int ldC, size_t MN, int rowoff)
{
  const int MT = BM / 32, NT = 2;
  __shared__ u16 lds[(BM + 64) * 32 * 3];
  u16* Ap[3] = { lds, lds + BM * 32, lds + 2 * BM * 32 };
  u16* Bp[3] = { lds + 3 * BM * 32, lds + 3 * BM * 32 + 2048, lds + 3 * BM * 32 + 4096 };

  const int t = threadIdx.x;
  const int lane = t & 63, wave = t >> 6;
  const int wm = wave >> 1, wn = wave & 1;
  const int m0 = blockIdx.y * BM, n0 = blockIdx.x * 64;
  const int kz = blockIdx.z * Ks;

  f32x4 acc[MT][NT] = {};

  for (int k0 = 0; k0 < Ks; k0 += 32) {
    if (k0) __syncthreads();
    const int kb = kz + k0;
    if (AF32) {
      const float* A = (const float*)A0any;
      #pragma unroll
      for (int c0 = 0; c0 < BM * 4; c0 += 256) {
        int c = c0 + t;
        int row = c >> 2, slot = c & 3;
        const float* g = A + (size_t)(m0 + row) * Ktot + kb + slot * 8;
        f32x4 fa = *(const f32x4*)g;
        f32x4 fb = *(const f32x4*)(g + 4);
        int dst = row * 32 + ((slot ^ ((row >> 1) & 3)) << 3);
        s8v v0, v1, v2;
        #pragma unroll
        for (int e = 0; e < 4; ++e) {
          u16 a0, a1, a2; split3(fa[e], a0, a1, a2);
          v0[e] = (short)a0; v1[e] = (short)a1; v2[e] = (short)a2;
        }
        #pragma unroll
        for (int e = 0; e < 4; ++e) {
          u16 a0, a1, a2; split3(fb[e], a0, a1, a2);
          v0[4 + e] = (short)a0; v1[4 + e] = (short)a1; v2[4 + e] = (short)a2;
        }
        *(s8v*)(Ap[0] + dst) = v0;
        *(s8v*)(Ap[1] + dst) = v1;
        *(s8v*)(Ap[2] + dst) = v2;
      }
    } else {
      const u16* As[3] = { (const u16*)A0any, A1_, A2_ };
      #pragma unroll
      for (int c0 = 0; c0 < BM * 4; c0 += 256) {
        int c = c0 + t;
        int row = c >> 2, slot = c & 3;
        size_t g = (size_t)(m0 + row) * Ktot + kb + slot * 8;
        int dst = row * 32 + ((slot ^ ((row >> 1) & 3)) << 3);
        #pragma unroll
        for (int p = 0; p < 3; ++p)
          *(s8v*)(Ap[p] + dst) = *(const s8v*)(As[p] + g);
      }
    }
    {
      const u16* Bs[3] = { B0_, B1_, B2_ };
      int row = t >> 2, slot = t & 3;
      size_t g = (size_t)(n0 + row) * Ktot + kb + slot * 8;
      int dst = row * 32 + ((slot ^ ((row >> 1) & 3)) << 3);
      #pragma unroll
      for (int p = 0; p < 3; ++p)
        *(s8v*)(Bp[p] + dst) = *(const s8v*)(Bs[p] + g);
    }
    __syncthreads();

    s8v af[3][MT], bf[3][NT];
    #pragma unroll
    for (int mt = 0; mt < MT; ++mt) {
      int r = wm * (BM / 2) + mt * 16 + (lane & 15);
      int off = r * 32 + (((lane >> 4) ^ ((r >> 1) & 3)) << 3);
      #pragma unroll
      for (int p = 0; p < 3; ++p) af[p][mt] = *(const s8v*)(Ap[p] + off);
    }
    #pragma unroll
    for (int nt = 0; nt < NT; ++nt) {
      int r = wn * 32 + nt * 16 + (lane & 15);
      int off = r * 32 + (((lane >> 4) ^ ((r >> 1) & 3)) << 3);
      #pragma unroll
      for (int p = 0; p < 3; ++p) bf[p][nt] = *(const s8v*)(Bp[p] + off);
    }
    #pragma unroll
    for (int mt = 0; mt < MT; ++mt)
      #pragma unroll
      for (int nt = 0; nt < NT; ++nt) {
        f32x4 a = acc[mt][nt];
        a = __builtin_amdgcn_mfma_f32_16x16x32_bf16(af[0][mt], bf[0][nt], a, 0, 0, 0);
        a = __builtin_amdgcn_mfma_f32_16x16x32_bf16(af[0][mt], bf[1][nt], a, 0, 0, 0);
        a = __builtin_amdgcn_mfma_f32_16x16x32_bf16(af[1][mt], bf[0][nt], a, 0, 0, 0);
        a = __builtin_amdgcn_mfma_f32_16x16x32_bf16(af[1][mt], bf[1][nt], a, 0, 0, 0);
        a = __builtin_amdgcn_mfma_f32_16x16x32_bf16(af[0][mt], bf[2][nt], a, 0, 0, 0);
        a = __builtin_amdgcn_mfma_f32_16x16x32_bf16(af[2][mt], bf[0][nt], a, 0, 0, 0);
        acc[mt][nt] = a;
      }
  }

  #pragma unroll
  for (int mt = 0; mt < MT; ++mt) {
    #pragma unroll
    for (int nt = 0; nt < NT; ++nt) {
      int col = n0 + wn * 32 + nt * 16 + (lane & 15);
      float bv = (BIAS && !SPLITK) ? bias[col] : 0.f;
      float sqc = WKEY ? bias[col] : 0.f;
      #pragma unroll
      for (int v = 0; v < 4; ++v) {
        int row = m0 + wm * (BM / 2) + mt * 16 + (lane >> 4) * 4 + v;
        float val = acc[mt][nt][v] + bv;
        size_t o = (size_t)row * ldC + col;
        if (SPLITK) {
          Cf[(size_t)blockIdx.z * MN + o] = val;
        } else if (WKEY) {
          float f = fmaf(-2.f, val, sqc);
          unsigned ub = __float_as_uint(f);
          unsigned uu = (ub & 0x80000000u) ? ~ub : (ub | 0x80000000u);
          if (rowoff + row == col) uu = 0xFFFFFFFFu;
          ((unsigned*)Cf)[o] = uu;
        } else {
          if (RELU) val = fmaxf(val, 0.f);
          if (WF32) Cf[o] = val;
          if (WSPLIT) {
            u16 a0, a1, a2; split3(val, a0, a1, a2);
            C0[o] = a0; C1[o] = a1; C2[o] = a2;
          }
        }
      }
    }
  }
}

template<int S, bool BIAS, bool RELU, bool WF32, bool WSPLIT>
__global__ void combine(const float* __restrict__ P, const float* __restrict__ bias,
                        size_t MN, int Ncols,
                        float* __restrict__ Cf, u16* __restrict__ C0,
                        u16* __restrict__ C1, u16* __restrict__ C2)
{
  size_t idx = ((size_t)blockIdx.x * 256 + threadIdx.x) * 4;
  if (idx >= MN) return;
  f32x4 s = *(const f32x4*)(P + idx);
  #pragma unroll
  for (int z = 1; z < S; ++z) s += *(const f32x4*)(P + (size_t)z * MN + idx);
  int n = (int)(idx % (size_t)Ncols);
  #pragma unroll
  for (int e = 0; e < 4; ++e) {
    float v = s[e] + (BIAS ? bias[n + e] : 0.f);
    if (RELU) v = fmaxf(v, 0.f);
    if (WF32) Cf[idx + e] = v;
    if (WSPLIT) {
      u16 a0, a1, a2; split3(v, a0, a1, a2);
      C0[idx + e] = a0; C1[idx + e] = a1; C2[idx + e] = a2;
    }
  }
}

// all three weight transposes+splits in one launch
__global__ void trans_split3(const float* __restrict__ W0, u16* __restrict__ a0,
                             u16* __restrict__ a1, u16* __restrict__ a2,
                             const float* __restrict__ W1, u16* __restrict__ b0,
                             u16* __restrict__ b1, u16* __restrict__ b2,
                             const float* __restrict__ gW, u16* __restrict__ c0,
                             u16* __restrict__ c1, u16* __restrict__ c2)
{
  int id = blockIdx.x * 256 + threadIdx.x;
  const int S0 = D_IN * H1_DIM, S1 = H1_DIM * H2_DIM, S2 = H2_DIM * G_DIM;
  const float* W; u16 *p0, *p1, *p2; int K, N;
  if (id < S0)           { W = W0; p0 = a0; p1 = a1; p2 = a2; K = D_IN;   N = H1_DIM; }
  else if (id < S0 + S1) { id -= S0; W = W1; p0 = b0; p1 = b1; p2 = b2; K = H1_DIM; N = H2_DIM; }
  else if (id < S0 + S1 + S2) { id -= S0 + S1; W = gW; p0 = c0; p1 = c1; p2 = c2; K = H2_DIM; N = G_DIM; }
  else return;
  int k = id / N, n = id % N;
  u16 x0, x1, x2;
  split3(W[id], x0, x1, x2);
  size_t o = (size_t)n * K + k;
  p0[o] = x0; p1[o] = x1; p2[o] = x2;
}

__global__ void prep_head(const float* __restrict__ cW, const float* __restrict__ cb,
                          const float* __restrict__ dW, const float* __restrict__ db,
                          float* __restrict__ Wc, float* __restrict__ bc)
{
  int t = threadIdx.x;
  for (int idx = t; idx < 64 * NOUT; idx += 256) {
    int g = idx / NOUT, c = idx % NOUT;
    float s = 0.f;
    if (c < 16) {
      for (int r = 0; r < 8; ++r) s += cW[(r * 64 + g) * 16 + c];
    } else {
      int k = (c - 16) >> 1, o = (c - 16) & 1;
      for (int r = 0; r < 8; ++r) s += dW[k * 1024 + (r * 64 + g) * 2 + o];
    }
    Wc[idx] = s;
  }
  if (t < NOUT) bc[t] = (t < 16) ? cb[t] : db[t - 16];
}

__global__ void row_stats(const float* __restrict__ h, const float* __restrict__ Wh,
                          const float* __restrict__ ga, float* __restrict__ sq,
                          float* __restrict__ f1, float* __restrict__ f2)
{
  int i = blockIdx.x * 256 + threadIdx.x;
  const float* hr = h + (size_t)i * H2_DIM;
  float s = 0.f;
  for (int k = 0; k < H2_DIM; ++k) { float v = hr[k]; s = fmaf(v, v, s); }
  sq[i] = s;
  const float* wr = Wh + (size_t)i * G_DIM;
  float a = 0.f, b = 0.f;
  for (int g = 0; g < G_DIM; ++g) {
    float w = wr[g];
    a = fmaf(w, ga[g], a);
    b = fmaf(w, ga[G_DIM + g], b);
  }
  f1[i] = a; f2[i] = b;
}

// ---------------------------------------------------------------------------
// TWO WAVES PER ROW, 2 rows/block. Each wave selects the exact top-32 of its
// HALF-row (12 quads/lane: lane-min 64-sort -> Q=s[31] >= T_half; ballot
// collect <=64 quads; bisect-refine fallback; bitonic sort on (key<<13|j)).
// One bitonic 64-merge of the two sorted 32-lists -> exact row top-32 with
// np tie-break. Wave-local softmax + PV + head in the merging wave.
// 2 block barriers total.
// ---------------------------------------------------------------------------
__global__ __launch_bounds__(256) void topk_att(const unsigned* __restrict__ Sb,
    const float* __restrict__ f1, const float* __restrict__ f2,
    const float* __restrict__ Wh, const float* __restrict__ Wc, const float* __restrict__ bc,
    float* __restrict__ out, int m0)
{
  const int t = threadIdx.x;
  const int lane = t & 63, wv = t >> 6;
  const int rloc = wv >> 1, half = wv & 1;
  const int row2 = blockIdx.x * 2 + rloc;
  const int i = m0 + row2;
  const unsigned* Srow = Sb + (size_t)row2 * N_PTS;
  const int hbase = half * 3072;

  __shared__ float WcL[64 * NOUT];
  __shared__ u64 candS[4][256];
  __shared__ u64 mergeS[4][32];
  __shared__ int neighS[2][33];
  __shared__ float attS[2][33];
  __shared__ float hpfS[2][64];

  for (int idx = t; idx < 64 * NOUT; idx += 256) WcL[idx] = Wc[idx];
  __syncthreads();                       // barrier 1

  // ---- stream half-row, keep quad-mins: j = hbase + (c<<8) + (lane<<2) + e ----
  unsigned q[12];
  #pragma unroll
  for (int c = 0; c < 12; ++c) {
    u32x4 v = *(const u32x4*)(Srow + hbase + (c << 8) + (lane << 2));
    unsigned a = v[0] < v[1] ? v[0] : v[1];
    unsigned b = v[2] < v[3] ? v[2] : v[3];
    q[c] = a < b ? a : b;
  }

  unsigned lmin = q[0];
  #pragma unroll
  for (int c = 1; c < 12; ++c) lmin = q[c] < lmin ? q[c] : lmin;

  // register bitonic sort of the 64 lane-mins (ascending across lanes)
  unsigned sv = lmin;
  for (int k = 2; k <= 64; k <<= 1) {
    for (int j = k >> 1; j >= 1; j >>= 1) {
      unsigned o = __shfl_xor(sv, j);
      bool up = ((lane & k) == 0) == ((lane & j) == 0);
      sv = up ? (sv < o ? sv : o) : (sv > o ? sv : o);
    }
  }
  unsigned Q = __shfl(sv, 31);          // 32nd-smallest lane-min >= T_half
  const unsigned s0 = __shfl(sv, 0);

  const u64 below = (lane == 0) ? 0ull : (~0ull >> (64 - lane));

  // ---- collection (capacity 64 quads = 256 keys) ----
  candS[wv][lane] = ~0ull;
  candS[wv][64 + lane] = ~0ull;
  candS[wv][128 + lane] = ~0ull;
  candS[wv][192 + lane] = ~0ull;
  int cnt = 0;
  #pragma unroll
  for (int c = 0; c < 12; ++c) {
    bool act = (q[c] <= Q);
    u64 mask = __ballot(act);
    if (act) {
      int pos = cnt + (int)__popcll(mask & below);
      if (pos < 64) {
        u32x4 v = *(const u32x4*)(Srow + hbase + (c << 8) + (lane << 2));
        #pragma unroll
        for (int e = 0; e < 4; ++e) {
          int j = hbase + (c << 8) + (lane << 2) + e;
          candS[wv][pos * 4 + e] = ((u64)v[e] << 13) | (unsigned)j;
        }
      }
    }
    cnt += (int)__popcll(mask);
  }

  if (cnt > 64) {
    // rare: refine to exact 32nd-smallest quad-min by quaternary bisection
    long long lo = (long long)s0 - 1, hi = (long long)Q;
    while (hi - lo > 1) {
      long long span = hi - lo;
      unsigned m1 = (unsigned)(lo + (span >> 2));
      unsigned m2 = (unsigned)(lo + (span >> 1));
      unsigned m3 = (unsigned)(hi - (span >> 2));
      int c1 = 0, c2 = 0, c3 = 0;
      #pragma unroll
      for (int c = 0; c < 12; ++c) {
        c1 += (q[c] <= m1);
        c2 += (q[c] <= m2);
        c3 += (q[c] <= m3);
      }
      #pragma unroll
      for (int off = 32; off > 0; off >>= 1) {
        c1 += __shfl_xor(c1, off);
        c2 += __shfl_xor(c2, off);
        c3 += __shfl_xor(c3, off);
      }
      if (c1 >= KNN)       { hi = m1; }
      else if (c2 >= KNN)  { lo = m1; hi = m2; }
      else if (c3 >= KNN)  { lo = m2; hi = m3; }
      else                 { lo = m3; }
    }
    Q = (unsigned)hi;
    candS[wv][lane] = ~0ull;
    candS[wv][64 + lane] = ~0ull;
    candS[wv][128 + lane] = ~0ull;
    candS[wv][192 + lane] = ~0ull;
    cnt = 0;
    #pragma unroll
    for (int c = 0; c < 12; ++c) {
      bool act = (q[c] <= Q);
      u64 mask = __ballot(act);
      if (act) {
        int pos = cnt + (int)__popcll(mask & below);
        if (pos < 64) {
          u32x4 v = *(const u32x4*)(Srow + hbase + (c << 8) + (lane << 2));
          #pragma unroll
          for (int e = 0; e < 4; ++e) {
            int j = hbase + (c << 8) + (lane << 2) + e;
            candS[wv][pos * 4 + e] = ((u64)v[e] << 13) | (unsigned)j;
          }
        }
      }
      cnt += (int)__popcll(mask);
    }
  }

  if (cnt <= 32) {
    // register bitonic sort of 128 candidates, 2 elems/lane
    u64 v0 = candS[wv][2 * lane], v1 = candS[wv][2 * lane + 1];
    const int e0 = 2 * lane, e1 = e0 + 1;
    for (int k = 2; k <= 128; k <<= 1) {
      for (int j = k >> 1; j >= 2; j >>= 1) {
        int hf = j >> 1;
        u64 o0 = __shfl_xor(v0, hf);
        u64 o1 = __shfl_xor(v1, hf);
        bool up0 = ((e0 & k) == 0) == ((e0 & j) == 0);
        bool up1 = ((e1 & k) == 0) == ((e1 & j) == 0);
        v0 = up0 ? (v0 < o0 ? v0 : o0) : (v0 > o0 ? v0 : o0);
        v1 = up1 ? (v1 < o1 ? v1 : o1) : (v1 > o1 ? v1 : o1);
      }
      bool asc = ((e0 & k) == 0);
      u64 a = v0 < v1 ? v0 : v1, b = v0 < v1 ? v1 : v0;
      v0 = asc ? a : b;
      v1 = asc ? b : a;
    }
    if (lane < 16) {
      mergeS[wv][2 * lane]     = v0;
      mergeS[wv][2 * lane + 1] = v1;
    }
  } else {
    // in-LDS 256-elem bitonic (up to 64 quads)
    for (int k = 2; k <= 256; k <<= 1) {
      for (int j = k >> 1; j >= 1; j >>= 1) {
        #pragma unroll
        for (int s = 0; s < 4; ++s) {
          int e = lane + s * 64;
          int p = e ^ j;
          if (p > e) {
            u64 a = candS[wv][e], b = candS[wv][p];
            bool asc = ((e & k) == 0);
            if ((a > b) == asc) { candS[wv][e] = b; candS[wv][p] = a; }
          }
        }
      }
    }
    if (lane < 32) mergeS[wv][lane] = candS[wv][lane];
  }
  __syncthreads();                       // barrier 2

  // ---- merging wave (half==0): bitonic 64-merge of two sorted 32-runs ----
  if (half == 0) {
    u64 v = (lane < 32) ? mergeS[wv][lane] : mergeS[wv + 1][63 - lane];
    #pragma unroll
    for (int j = 32; j >= 1; j >>= 1) {
      u64 o = __shfl_xor(v, j);
      bool up = (lane & j) == 0;
      v = up ? (v < o ? v : o) : (v > o ? v : o);
    }
    if (lane < KNN) neighS[rloc][lane] = (int)(v & 0x1FFFu);
    if (lane == 0) neighS[rloc][32] = i;

    // wave-local masked softmax over 33 entries
    {
      float e = -FLT_MAX;
      if (lane < 33) {
        float raw = f1[i] + f2[neighS[rloc][lane]];
        e = raw > 0.f ? raw : 0.2f * raw;
      }
      float mx = e;
      #pragma unroll
      for (int off = 32; off > 0; off >>= 1) mx = fmaxf(mx, __shfl_xor(mx, off));
      float ex = (lane < 33) ? expf(e - mx) : 0.f;
      float sm = ex;
      #pragma unroll
      for (int off = 32; off > 0; off >>= 1) sm += __shfl_xor(sm, off);
      if (lane < 33) attS[rloc][lane] = ex / sm;
    }

    // PV: lane = g
    {
      float s = 0.f;
      for (int m = 0; m < 33; ++m)
        s = fmaf(attS[rloc][m], Wh[(size_t)neighS[rloc][m] * G_DIM + lane], s);
      hpfS[rloc][lane] = s > 0.f ? s : expm1f(s);
    }

    // head: 64 -> 22
    if (lane < NOUT) {
      float o = bc[lane];
      for (int g = 0; g < 64; ++g) o = fmaf(hpfS[rloc][g], WcL[g * NOUT + lane], o);
      out[(size_t)i * NOUT + lane] = o;
    }
  }
}

extern "C" void kernel_launch(void* const* d_in, const int* in_sizes, int n_in,
                              void* d_out, int out_size, void* d_ws, size_t ws_size,
                              hipStream_t stream)
{
  const float* x  = (const float*)d_in[0];
  const float* W0 = (const float*)d_in[1];
  const float* b0 = (const float*)d_in[2];
  const float* W1 = (const float*)d_in[3];
  const float* b1 = (const float*)d_in[4];
  const float* gW = (const float*)d_in[5];
  const float* ga = (const float*)d_in[6];
  const float* cW = (const float*)d_in[7];
  const float* cb = (const float*)d_in[8];
  const float* dW = (const float*)d_in[9];
  const float* db = (const float*)d_in[10];
  float* out = (float*)d_out;

  char* base = (char*)d_ws;
  char* w = base;
  auto alloc = [&](size_t bytes) { char* p = w; w += (bytes + 255) & ~(size_t)255; return p; };
  u16 *W0p[3], *W1p[3], *gWp[3], *h1p[3], *hp[3];
  for (int p = 0; p < 3; ++p) W0p[p] = (u16*)alloc((size_t)D_IN * H1_DIM * 2);
  for (int p = 0; p < 3; ++p) W1p[p] = (u16*)alloc((size_t)H1_DIM * H2_DIM * 2);
  for (int p = 0; p < 3; ++p) gWp[p] = (u16*)alloc((size_t)H2_DIM * G_DIM * 2);
  for (int p = 0; p < 3; ++p) h1p[p] = (u16*)alloc((size_t)N_PTS * H1_DIM * 2);
  for (int p = 0; p < 3; ++p) hp[p]  = (u16*)alloc((size_t)N_PTS * H2_DIM * 2);
  float* hF  = (float*)alloc((size_t)N_PTS * H2_DIM * 4);
  float* WhF = (float*)alloc((size_t)N_PTS * G_DIM * 4);
  float* sqv = (float*)alloc(N_PTS * 4);
  float* f1v = (float*)alloc(N_PTS * 4);
  float* f2v = (float*)alloc(N_PTS * 4);
  float* Wc  = (float*)alloc(64 * NOUT * 4);
  float* bc  = (float*)alloc(64 * 4);

  char* pbase = w;
  const size_t MN1 = (size_t)N_PTS * H1_DIM;
  const size_t MN2 = (size_t)N_PTS * H2_DIM;
  const size_t MN3 = (size_t)N_PTS * G_DIM;
  float* P1 = (float*)alloc(4 * MN1 * 4);
  float* P2 = (float*)alloc(4 * MN2 * 4);
  float* P3 = (float*)alloc(4 * MN3 * 4);
  float* Sb = (float*)pbase;

  size_t used_persist = (size_t)(pbase - base);
  size_t avail = (ws_size > used_persist) ? (ws_size - used_persist) / 4 : 0;
  int rowblk = 128;
  const int rcand[] = {6144, 3072, 1536, 768, 384, 256, 128};
  for (int c : rcand) { if ((size_t)c * N_PTS <= avail) { rowblk = c; break; } }

  const int TS = D_IN * H1_DIM + H1_DIM * H2_DIM + H2_DIM * G_DIM;
  trans_split3<<<(TS + 255) / 256, 256, 0, stream>>>(
      W0, W0p[0], W0p[1], W0p[2], W1, W1p[0], W1p[1], W1p[2], gW, gWp[0], gWp[1], gWp[2]);
  prep_head<<<1, 256, 0, stream>>>(cW, cb, dW, db, Wc, bc);

  mfma_gemm<64, true, true, false, false, false, false, false>
      <<<dim3(H1_DIM / 64, N_PTS / 64, 4), 256, 0, stream>>>(
      x, nullptr, nullptr, W0p[0], W0p[1], W0p[2], nullptr,
      P1, nullptr, nullptr, nullptr, D_IN, D_IN / 4, H1_DIM, MN1, 0);
  combine<4, true, true, false, true><<<(int)(MN1 / 1024), 256, 0, stream>>>(
      P1, b0, MN1, H1_DIM, nullptr, h1p[0], h1p[1], h1p[2]);

  mfma_gemm<64, false, true, false, false, false, false, false>
      <<<dim3(H2_DIM / 64, N_PTS / 64, 4), 256, 0, stream>>>(
      h1p[0], h1p[1], h1p[2], W1p[0], W1p[1], W1p[2], nullptr,
      P2, nullptr, nullptr, nullptr, H1_DIM, H1_DIM / 4, H2_DIM, MN2, 0);
  combine<4, true, true, true, true><<<(int)(MN2 / 1024), 256, 0, stream>>>(
      P2, b1, MN2, H2_DIM, hF, hp[0], hp[1], hp[2]);

  mfma_gemm<64, false, true, false, false, false, false, false>
      <<<dim3(G_DIM / 64, N_PTS / 64, 4), 256, 0, stream>>>(
      hp[0], hp[1], hp[2], gWp[0], gWp[1], gWp[2], nullptr,
      P3, nullptr, nullptr, nullptr, H2_DIM, H2_DIM / 4, G_DIM, MN3, 0);
  combine<4, false, false, true, false><<<(int)(MN3 / 1024), 256, 0, stream>>>(
      P3, nullptr, MN3, G_DIM, WhF, nullptr, nullptr, nullptr);

  row_stats<<<N_PTS / 256, 256, 0, stream>>>(hF, WhF, ga, sqv, f1v, f2v);

  // Gram panel(s) writing sortable keys directly, then fused select/att/head
  for (int b = 0; b < N_PTS / rowblk; ++b) {
    mfma_gemm<128, false, false, false, false, false, false, true>
        <<<dim3(N_PTS / 64, rowblk / 128, 1), 256, 0, stream>>>(
        hp[0] + (size_t)b * rowblk * H2_DIM, hp[1] + (size_t)b * rowblk * H2_DIM,
        hp[2] + (size_t)b * rowblk * H2_DIM, hp[0], hp[1], hp[2], sqv,
        Sb, nullptr, nullptr, nullptr, H2_DIM, H2_DIM, N_PTS, 0, b * rowblk);
    topk_att<<<rowblk / 2, 256, 0, stream>>>((const unsigned*)Sb, f1v, f2v, WhF, Wc, bc, out, b * rowblk);
  }
}

// Round 16
// 193.172 us; speedup vs baseline: 1.0347x; 1.0347x over previous
//
#include <hip/hip_runtime.h>
#include <float.h>

#define N_PTS 6144
#define D_IN  512
#define H1_DIM 256
#define H2_DIM 128
#define G_DIM  64
#define KNN    32
#define NOUT   22

typedef short s8v __attribute__((ext_vector_type(8)));   // 8 bf16 in 4 VGPR
typedef float f32x4 __attribute__((ext_vector_type(4)));
typedef unsigned u32x4 __attribute__((ext_vector_type(4)));
typedef unsigned short u16;
typedef unsigned long long u64;

__device__ __forceinline__ u16 f2bf(float f) {
  unsigned u = __float_as_uint(f);
  u += 0x7FFFu + ((u >> 16) & 1u);          // RNE to bf16
  return (u16)(u >> 16);
}
__device__ __forceinline__ float bf2f(u16 s) {
  return __uint_as_float(((unsigned)s) << 16);
}
__device__ __forceinline__ void split3(float v, u16& a0, u16& a1, u16& a2) {
  a0 = f2bf(v);
  float r1 = v - bf2f(a0);
  a1 = f2bf(r1);
  a2 = f2bf(r1 - bf2f(a1));
}

// ---------------------------------------------------------------------------
// MFMA GEMM, 3-way bf16 split, 6-term schedule (fp32-equivalent).
// C[M,N] = A[M,K] * B^T[N,K].  BN=64, BK=32, 4 waves (2x2), wave tile (BM/2)x32.
// Staging via global_load_lds (direct-to-LDS DMA, 16B/lane): LDS stays linear
// (base + lane*16); the XOR slot-swizzle is realized by inverse-swizzling the
// per-lane global SOURCE slot. No LDS pointer arrays (addrspacecast issue) —
// all LDS addressing is lds + integer offset.
// WKEY: epilogue writes sortable-u32 kNN keys (sq[col] - 2*val; diag=UINT_MAX).
// ---------------------------------------------------------------------------
template<int BM, bool AF32, bool SPLITK, bool BIAS, bool RELU, bool WF32, bool WSPLIT, bool WKEY>
__global__ __launch_bounds__(256, 4) void mfma_gemm(
    const void* __restrict__ A0any, const u16* __restrict__ A1_, const u16* __restrict__ A2_,
    const u16* __restrict__ B0_, const u16* __restrict__ B1_, const u16* __restrict__ B2_,
    const float* __restrict__ bias,
    float* __restrict__ Cf, u16* __restrict__ C0, u16* __restrict__ C1, u16* __restrict__ C2,
    int Ktot, int Ks, int ldC, size_t MN, int rowoff)
{
  const int MT = BM / 32, NT = 2;
  const int APL = BM * 32;              // u16 per A plane
  const int BBASE = 3 * APL;            // u16 offset of B region
  __shared__ u16 lds[(BM + 64) * 32 * 3];

  const int t = threadIdx.x;
  const int lane = t & 63, wave = t >> 6;
  const int wm = wave >> 1, wn = wave & 1;
  const int m0 = blockIdx.y * BM, n0 = blockIdx.x * 64;
  const int kz = blockIdx.z * Ks;

  f32x4 acc[MT][NT] = {};

  const int pA = BM / 16;               // 1KB chunks per A plane
  const int NC = 3 * pA + 12;           // total chunks (A + B planes)

  for (int k0 = 0; k0 < Ks; k0 += 32) {
    if (k0) __syncthreads();
    const int kb = kz + k0;
    if (AF32) {
      const float* A = (const float*)A0any;
      #pragma unroll
      for (int c0 = 0; c0 < BM * 4; c0 += 256) {
        int c = c0 + t;
        int row = c >> 2, slot = c & 3;
        const float* g = A + (size_t)(m0 + row) * Ktot + kb + slot * 8;
        f32x4 fa = *(const f32x4*)g;
        f32x4 fb = *(const f32x4*)(g + 4);
        int dst = row * 32 + ((slot ^ ((row >> 1) & 3)) << 3);
        s8v v0, v1, v2;
        #pragma unroll
        for (int e = 0; e < 4; ++e) {
          u16 a0, a1, a2; split3(fa[e], a0, a1, a2);
          v0[e] = (short)a0; v1[e] = (short)a1; v2[e] = (short)a2;
        }
        #pragma unroll
        for (int e = 0; e < 4; ++e) {
          u16 a0, a1, a2; split3(fb[e], a0, a1, a2);
          v0[4 + e] = (short)a0; v1[4 + e] = (short)a1; v2[4 + e] = (short)a2;
        }
        *(s8v*)(lds + dst) = v0;
        *(s8v*)(lds + APL + dst) = v1;
        *(s8v*)(lds + 2 * APL + dst) = v2;
      }
      // B staging via direct-to-LDS (12 chunks of 1KB)
      for (int c = wave; c < 12; c += 4) {
        int p = c >> 2, lc = c & 3;
        int row = lc * 16 + (lane >> 2);
        int srcslot = (lane & 3) ^ ((row >> 1) & 3);
        const u16* src = (p == 0) ? B0_ : (p == 1) ? B1_ : B2_;
        const u16* g = src + (size_t)(n0 + row) * Ktot + kb + srcslot * 8;
        __builtin_amdgcn_global_load_lds(
            (const __attribute__((address_space(1))) unsigned*)g,
            (__attribute__((address_space(3))) unsigned*)(lds + BBASE + p * 2048 + lc * 512),
            16, 0, 0);
      }
    } else {
      for (int c = wave; c < NC; c += 4) {
        const u16* src; int dstoff; int row0; int lc;
        if (c < 3 * pA) {
          int p = c / pA; lc = c % pA;
          src = (p == 0) ? (const u16*)A0any : (p == 1) ? A1_ : A2_;
          dstoff = p * APL + lc * 512;
          row0 = m0;
        } else {
          int cb = c - 3 * pA;
          int p = cb >> 2; lc = cb & 3;
          src = (p == 0) ? B0_ : (p == 1) ? B1_ : B2_;
          dstoff = BBASE + p * 2048 + lc * 512;
          row0 = n0;
        }
        int row = lc * 16 + (lane >> 2);
        int srcslot = (lane & 3) ^ ((row >> 1) & 3);
        const u16* g = src + (size_t)(row0 + row) * Ktot + kb + srcslot * 8;
        __builtin_amdgcn_global_load_lds(
            (const __attribute__((address_space(1))) unsigned*)g,
            (__attribute__((address_space(3))) unsigned*)(lds + dstoff),
            16, 0, 0);
      }
    }
    __syncthreads();

    s8v af[3][MT], bf[3][NT];
    #pragma unroll
    for (int mt = 0; mt < MT; ++mt) {
      int r = wm * (BM / 2) + mt * 16 + (lane & 15);
      int off = r * 32 + (((lane >> 4) ^ ((r >> 1) & 3)) << 3);
      #pragma unroll
      for (int p = 0; p < 3; ++p) af[p][mt] = *(const s8v*)(lds + p * APL + off);
    }
    #pragma unroll
    for (int nt = 0; nt < NT; ++nt) {
      int r = wn * 32 + nt * 16 + (lane & 15);
      int off = r * 32 + (((lane >> 4) ^ ((r >> 1) & 3)) << 3);
      #pragma unroll
      for (int p = 0; p < 3; ++p) bf[p][nt] = *(const s8v*)(lds + BBASE + p * 2048 + off);
    }
    #pragma unroll
    for (int mt = 0; mt < MT; ++mt)
      #pragma unroll
      for (int nt = 0; nt < NT; ++nt) {
        f32x4 a = acc[mt][nt];
        a = __builtin_amdgcn_mfma_f32_16x16x32_bf16(af[0][mt], bf[0][nt], a, 0, 0, 0);
        a = __builtin_amdgcn_mfma_f32_16x16x32_bf16(af[0][mt], bf[1][nt], a, 0, 0, 0);
        a = __builtin_amdgcn_mfma_f32_16x16x32_bf16(af[1][mt], bf[0][nt], a, 0, 0, 0);
        a = __builtin_amdgcn_mfma_f32_16x16x32_bf16(af[1][mt], bf[1][nt], a, 0, 0, 0);
        a = __builtin_amdgcn_mfma_f32_16x16x32_bf16(af[0][mt], bf[2][nt], a, 0, 0, 0);
        a = __builtin_amdgcn_mfma_f32_16x16x32_bf16(af[2][mt], bf[0][nt], a, 0, 0, 0);
        acc[mt][nt] = a;
      }
  }

  #pragma unroll
  for (int mt = 0; mt < MT; ++mt) {
    #pragma unroll
    for (int nt = 0; nt < NT; ++nt) {
      int col = n0 + wn * 32 + nt * 16 + (lane & 15);
      float bv = (BIAS && !SPLITK) ? bias[col] : 0.f;
      float sqc = WKEY ? bias[col] : 0.f;
      #pragma unroll
      for (int v = 0; v < 4; ++v) {
        int row = m0 + wm * (BM / 2) + mt * 16 + (lane >> 4) * 4 + v;
        float val = acc[mt][nt][v] + bv;
        size_t o = (size_t)row * ldC + col;
        if (SPLITK) {
          Cf[(size_t)blockIdx.z * MN + o] = val;
        } else if (WKEY) {
          float f = fmaf(-2.f, val, sqc);
          unsigned ub = __float_as_uint(f);
          unsigned uu = (ub & 0x80000000u) ? ~ub : (ub | 0x80000000u);
          if (rowoff + row == col) uu = 0xFFFFFFFFu;
          ((unsigned*)Cf)[o] = uu;
        } else {
          if (RELU) val = fmaxf(val, 0.f);
          if (WF32) Cf[o] = val;
          if (WSPLIT) {
            u16 a0, a1, a2; split3(val, a0, a1, a2);
            C0[o] = a0; C1[o] = a1; C2[o] = a2;
          }
        }
      }
    }
  }
}

template<int S, bool BIAS, bool RELU, bool WF32, bool WSPLIT>
__global__ void combine(const float* __restrict__ P, const float* __restrict__ bias,
                        size_t MN, int Ncols,
                        float* __restrict__ Cf, u16* __restrict__ C0,
                        u16* __restrict__ C1, u16* __restrict__ C2)
{
  size_t idx = ((size_t)blockIdx.x * 256 + threadIdx.x) * 4;
  if (idx >= MN) return;
  f32x4 s = *(const f32x4*)(P + idx);
  #pragma unroll
  for (int z = 1; z < S; ++z) s += *(const f32x4*)(P + (size_t)z * MN + idx);
  int n = (int)(idx % (size_t)Ncols);
  #pragma unroll
  for (int e = 0; e < 4; ++e) {
    float v = s[e] + (BIAS ? bias[n + e] : 0.f);
    if (RELU) v = fmaxf(v, 0.f);
    if (WF32) Cf[idx + e] = v;
    if (WSPLIT) {
      u16 a0, a1, a2; split3(v, a0, a1, a2);
      C0[idx + e] = a0; C1[idx + e] = a1; C2[idx + e] = a2;
    }
  }
}

// all three weight transposes+splits in one launch
__global__ void trans_split3(const float* __restrict__ W0, u16* __restrict__ a0,
                             u16* __restrict__ a1, u16* __restrict__ a2,
                             const float* __restrict__ W1, u16* __restrict__ b0,
                             u16* __restrict__ b1, u16* __restrict__ b2,
                             const float* __restrict__ gW, u16* __restrict__ c0,
                             u16* __restrict__ c1, u16* __restrict__ c2)
{
  int id = blockIdx.x * 256 + threadIdx.x;
  const int S0 = D_IN * H1_DIM, S1 = H1_DIM * H2_DIM, S2 = H2_DIM * G_DIM;
  const float* W; u16 *p0, *p1, *p2; int K, N;
  if (id < S0)           { W = W0; p0 = a0; p1 = a1; p2 = a2; K = D_IN;   N = H1_DIM; }
  else if (id < S0 + S1) { id -= S0; W = W1; p0 = b0; p1 = b1; p2 = b2; K = H1_DIM; N = H2_DIM; }
  else if (id < S0 + S1 + S2) { id -= S0 + S1; W = gW; p0 = c0; p1 = c1; p2 = c2; K = H2_DIM; N = G_DIM; }
  else return;
  int k = id / N, n = id % N;
  u16 x0, x1, x2;
  split3(W[id], x0, x1, x2);
  size_t o = (size_t)n * K + k;
  p0[o] = x0; p1[o] = x1; p2[o] = x2;
}

__global__ void prep_head(const float* __restrict__ cW, const float* __restrict__ cb,
                          const float* __restrict__ dW, const float* __restrict__ db,
                          float* __restrict__ Wc, float* __restrict__ bc)
{
  int t = threadIdx.x;
  for (int idx = t; idx < 64 * NOUT; idx += 256) {
    int g = idx / NOUT, c = idx % NOUT;
    float s = 0.f;
    if (c < 16) {
      for (int r = 0; r < 8; ++r) s += cW[(r * 64 + g) * 16 + c];
    } else {
      int k = (c - 16) >> 1, o = (c - 16) & 1;
      for (int r = 0; r < 8; ++r) s += dW[k * 1024 + (r * 64 + g) * 2 + o];
    }
    Wc[idx] = s;
  }
  if (t < NOUT) bc[t] = (t < 16) ? cb[t] : db[t - 16];
}

__global__ void row_stats(const float* __restrict__ h, const float* __restrict__ Wh,
                          const float* __restrict__ ga, float* __restrict__ sq,
                          float* __restrict__ f1, float* __restrict__ f2)
{
  int i = blockIdx.x * 256 + threadIdx.x;
  const float* hr = h + (size_t)i * H2_DIM;
  float s = 0.f;
  for (int k = 0; k < H2_DIM; ++k) { float v = hr[k]; s = fmaf(v, v, s); }
  sq[i] = s;
  const float* wr = Wh + (size_t)i * G_DIM;
  float a = 0.f, b = 0.f;
  for (int g = 0; g < G_DIM; ++g) {
    float w = wr[g];
    a = fmaf(w, ga[g], a);
    b = fmaf(w, ga[G_DIM + g], b);
  }
  f1[i] = a; f2[i] = b;
}

// ---------------------------------------------------------------------------
// r12-proven: one wave per row (4 rows/block), quad-min tournament ->
// quaternary bisection for Q = exact 32nd-smallest quad-min -> ballot
// collect (capacity 64 quads, all 256 slots initialized) -> register
// 128-bitonic (cnt<=32, common case) or LDS 256-bitonic on (key<<13|j) ->
// exact top-32 with np tie-break; wave-local softmax + PV + head.
// ---------------------------------------------------------------------------
__global__ __launch_bounds__(256) void topk_att(const unsigned* __restrict__ Sb,
    const float* __restrict__ f1, const float* __restrict__ f2,
    const float* __restrict__ Wh, const float* __restrict__ Wc, const float* __restrict__ bc,
    float* __restrict__ out, int m0)
{
  const int t = threadIdx.x;
  const int lane = t & 63, wv = t >> 6;
  const int row4 = blockIdx.x * 4 + wv;
  const int i = m0 + row4;
  const unsigned* Srow = Sb + (size_t)row4 * N_PTS;

  __shared__ float WcL[64 * NOUT];
  __shared__ u64 candS[4][256];
  __shared__ int neighS[4][33];
  __shared__ float attS[4][33];
  __shared__ float hpfS[4][64];

  for (int idx = t; idx < 64 * NOUT; idx += 256) WcL[idx] = Wc[idx];
  __syncthreads();                       // only block barrier

  unsigned q[24];
  #pragma unroll
  for (int c = 0; c < 24; ++c) {
    u32x4 v = *(const u32x4*)(Srow + (c << 8) + (lane << 2));
    unsigned a = v[0] < v[1] ? v[0] : v[1];
    unsigned b = v[2] < v[3] ? v[2] : v[3];
    q[c] = a < b ? a : b;
  }

  unsigned lmin = q[0];
  #pragma unroll
  for (int c = 1; c < 24; ++c) lmin = q[c] < lmin ? q[c] : lmin;

  unsigned mnl = lmin, mxl = lmin;
  #pragma unroll
  for (int off = 32; off > 0; off >>= 1) {
    unsigned o1 = __shfl_xor(mnl, off); mnl = o1 < mnl ? o1 : mnl;
    unsigned o2 = __shfl_xor(mxl, off); mxl = o2 > mxl ? o2 : mxl;
  }

  long long lo = (long long)mnl - 1, hi = (long long)mxl;
  while (hi - lo > 1) {
    long long span = hi - lo;
    unsigned m1 = (unsigned)(lo + (span >> 2));
    unsigned m2 = (unsigned)(lo + (span >> 1));
    unsigned m3 = (unsigned)(hi - (span >> 2));
    int c1 = 0, c2 = 0, c3 = 0;
    #pragma unroll
    for (int c = 0; c < 24; ++c) {
      c1 += (q[c] <= m1);
      c2 += (q[c] <= m2);
      c3 += (q[c] <= m3);
    }
    #pragma unroll
    for (int off = 32; off > 0; off >>= 1) {
      c1 += __shfl_xor(c1, off);
      c2 += __shfl_xor(c2, off);
      c3 += __shfl_xor(c3, off);
    }
    if (c1 >= KNN)       { hi = m1; }
    else if (c2 >= KNN)  { lo = m1; hi = m2; }
    else if (c3 >= KNN)  { lo = m2; hi = m3; }
    else                 { lo = m3; }
  }
  const unsigned Q = (unsigned)hi;

  candS[wv][lane] = ~0ull;
  candS[wv][64 + lane] = ~0ull;
  candS[wv][128 + lane] = ~0ull;
  candS[wv][192 + lane] = ~0ull;
  const u64 below = (lane == 0) ? 0ull : (~0ull >> (64 - lane));
  int cnt = 0;
  #pragma unroll
  for (int c = 0; c < 24; ++c) {
    bool act = (q[c] <= Q);
    u64 mask = __ballot(act);
    if (act) {
      int pos = cnt + (int)__popcll(mask & below);
      if (pos < 64) {
        u32x4 v = *(const u32x4*)(Srow + (c << 8) + (lane << 2));
        #pragma unroll
        for (int e = 0; e < 4; ++e) {
          int j = (c << 8) + (lane << 2) + e;
          candS[wv][pos * 4 + e] = ((u64)v[e] << 13) | (unsigned)j;
        }
      }
    }
    cnt += (int)__popcll(mask);
  }

  if (cnt <= 32) {
    u64 v0 = candS[wv][2 * lane], v1 = candS[wv][2 * lane + 1];
    const int e0 = 2 * lane, e1 = e0 + 1;
    for (int k = 2; k <= 128; k <<= 1) {
      for (int j = k >> 1; j >= 2; j >>= 1) {
        int half = j >> 1;
        u64 o0 = __shfl_xor(v0, half);
        u64 o1 = __shfl_xor(v1, half);
        bool up0 = ((e0 & k) == 0) == ((e0 & j) == 0);
        bool up1 = ((e1 & k) == 0) == ((e1 & j) == 0);
        v0 = up0 ? (v0 < o0 ? v0 : o0) : (v0 > o0 ? v0 : o0);
        v1 = up1 ? (v1 < o1 ? v1 : o1) : (v1 > o1 ? v1 : o1);
      }
      bool asc = ((e0 & k) == 0);
      u64 a = v0 < v1 ? v0 : v1, b = v0 < v1 ? v1 : v0;
      v0 = asc ? a : b;
      v1 = asc ? b : a;
    }
    if (lane < 16) {
      neighS[wv][2 * lane]     = (int)(v0 & 0x1FFFu);
      neighS[wv][2 * lane + 1] = (int)(v1 & 0x1FFFu);
    }
    if (lane == 0) neighS[wv][32] = i;
  } else {
    for (int k = 2; k <= 256; k <<= 1) {
      for (int j = k >> 1; j >= 1; j >>= 1) {
        #pragma unroll
        for (int s = 0; s < 4; ++s) {
          int e = lane + s * 64;
          int p = e ^ j;
          if (p > e) {
            u64 a = candS[wv][e], b = candS[wv][p];
            bool asc = ((e & k) == 0);
            if ((a > b) == asc) { candS[wv][e] = b; candS[wv][p] = a; }
          }
        }
      }
    }
    if (lane < KNN) neighS[wv][lane] = (int)(candS[wv][lane] & 0x1FFFu);
    if (lane == 0) neighS[wv][32] = i;
  }

  {
    float e = -FLT_MAX;
    if (lane < 33) {
      float raw = f1[i] + f2[neighS[wv][lane]];
      e = raw > 0.f ? raw : 0.2f * raw;
    }
    float mx = e;
    #pragma unroll
    for (int off = 32; off > 0; off >>= 1) mx = fmaxf(mx, __shfl_xor(mx, off));
    float ex = (lane < 33) ? expf(e - mx) : 0.f;
    float sm = ex;
    #pragma unroll
    for (int off = 32; off > 0; off >>= 1) sm += __shfl_xor(sm, off);
    if (lane < 33) attS[wv][lane] = ex / sm;
  }

  {
    float s = 0.f;
    for (int m = 0; m < 33; ++m)
      s = fmaf(attS[wv][m], Wh[(size_t)neighS[wv][m] * G_DIM + lane], s);
    hpfS[wv][lane] = s > 0.f ? s : expm1f(s);
  }

  if (lane < NOUT) {
    float o = bc[lane];
    for (int g = 0; g < 64; ++g) o = fmaf(hpfS[wv][g], WcL[g * NOUT + lane], o);
    out[(size_t)i * NOUT + lane] = o;
  }
}

extern "C" void kernel_launch(void* const* d_in, const int* in_sizes, int n_in,
                              void* d_out, int out_size, void* d_ws, size_t ws_size,
                              hipStream_t stream)
{
  const float* x  = (const float*)d_in[0];
  const float* W0 = (const float*)d_in[1];
  const float* b0 = (const float*)d_in[2];
  const float* W1 = (const float*)d_in[3];
  const float* b1 = (const float*)d_in[4];
  const float* gW = (const float*)d_in[5];
  const float* ga = (const float*)d_in[6];
  const float* cW = (const float*)d_in[7];
  const float* cb = (const float*)d_in[8];
  const float* dW = (const float*)d_in[9];
  const float* db = (const float*)d_in[10];
  float* out = (float*)d_out;

  char* base = (char*)d_ws;
  char* w = base;
  auto alloc = [&](size_t bytes) { char* p = w; w += (bytes + 255) & ~(size_t)255; return p; };
  u16 *W0p[3], *W1p[3], *gWp[3], *h1p[3], *hp[3];
  for (int p = 0; p < 3; ++p) W0p[p] = (u16*)alloc((size_t)D_IN * H1_DIM * 2);
  for (int p = 0; p < 3; ++p) W1p[p] = (u16*)alloc((size_t)H1_DIM * H2_DIM * 2);
  for (int p = 0; p < 3; ++p) gWp[p] = (u16*)alloc((size_t)H2_DIM * G_DIM * 2);
  for (int p = 0; p < 3; ++p) h1p[p] = (u16*)alloc((size_t)N_PTS * H1_DIM * 2);
  for (int p = 0; p < 3; ++p) hp[p]  = (u16*)alloc((size_t)N_PTS * H2_DIM * 2);
  float* hF  = (float*)alloc((size_t)N_PTS * H2_DIM * 4);
  float* WhF = (float*)alloc((size_t)N_PTS * G_DIM * 4);
  float* sqv = (float*)alloc(N_PTS * 4);
  float* f1v = (float*)alloc(N_PTS * 4);
  float* f2v = (float*)alloc(N_PTS * 4);
  float* Wc  = (float*)alloc(64 * NOUT * 4);
  float* bc  = (float*)alloc(64 * 4);

  char* pbase = w;
  const size_t MN1 = (size_t)N_PTS * H1_DIM;
  const size_t MN2 = (size_t)N_PTS * H2_DIM;
  const size_t MN3 = (size_t)N_PTS * G_DIM;
  float* P1 = (float*)alloc(4 * MN1 * 4);
  float* P2 = (float*)alloc(4 * MN2 * 4);
  float* P3 = (float*)alloc(4 * MN3 * 4);
  float* Sb = (float*)pbase;

  size_t used_persist = (size_t)(pbase - base);
  size_t avail = (ws_size > used_persist) ? (ws_size - used_persist) / 4 : 0;
  int rowblk = 128;
  const int rcand[] = {6144, 3072, 1536, 768, 384, 256, 128};
  for (int c : rcand) { if ((size_t)c * N_PTS <= avail) { rowblk = c; break; } }

  const int TS = D_IN * H1_DIM + H1_DIM * H2_DIM + H2_DIM * G_DIM;
  trans_split3<<<(TS + 255) / 256, 256, 0, stream>>>(
      W0, W0p[0], W0p[1], W0p[2], W1, W1p[0], W1p[1], W1p[2], gW, gWp[0], gWp[1], gWp[2]);
  prep_head<<<1, 256, 0, stream>>>(cW, cb, dW, db, Wc, bc);

  mfma_gemm<64, true, true, false, false, false, false, false>
      <<<dim3(H1_DIM / 64, N_PTS / 64, 4), 256, 0, stream>>>(
      x, nullptr, nullptr, W0p[0], W0p[1], W0p[2], nullptr,
      P1, nullptr, nullptr, nullptr, D_IN, D_IN / 4, H1_DIM, MN1, 0);
  combine<4, true, true, false, true><<<(int)(MN1 / 1024), 256, 0, stream>>>(
      P1, b0, MN1, H1_DIM, nullptr, h1p[0], h1p[1], h1p[2]);

  mfma_gemm<64, false, true, false, false, false, false, false>
      <<<dim3(H2_DIM / 64, N_PTS / 64, 4), 256, 0, stream>>>(
      h1p[0], h1p[1], h1p[2], W1p[0], W1p[1], W1p[2], nullptr,
      P2, nullptr, nullptr, nullptr, H1_DIM, H1_DIM / 4, H2_DIM, MN2, 0);
  combine<4, true, true, true, true><<<(int)(MN2 / 1024), 256, 0, stream>>>(
      P2, b1, MN2, H2_DIM, hF, hp[0], hp[1], hp[2]);

  mfma_gemm<64, false, true, false, false, false, false, false>
      <<<dim3(G_DIM / 64, N_PTS / 64, 4), 256, 0, stream>>>(
      hp[0], hp[1], hp[2], gWp[0], gWp[1], gWp[2], nullptr,
      P3, nullptr, nullptr, nullptr, H2_DIM, H2_DIM / 4, G_DIM, MN3, 0);
  combine<4, false, false, true, false><<<(int)(MN3 / 1024), 256, 0, stream>>>(
      P3, nullptr, MN3, G_DIM, WhF, nullptr, nullptr, nullptr);

  row_stats<<<N_PTS / 256, 256, 0, stream>>>(hF, WhF, ga, sqv, f1v, f2v);

  // Gram panel(s) writing sortable keys directly, then fused select/att/head
  for (int b = 0; b < N_PTS / rowblk; ++b) {
    mfma_gemm<128, false, false, false, false, false, false, true>
        <<<dim3(N_PTS / 64, rowblk / 128, 1), 256, 0, stream>>>(
        hp[0] + (size_t)b * rowblk * H2_DIM, hp[1] + (size_t)b * rowblk * H2_DIM,
        hp[2] + (size_t)b * rowblk * H2_DIM, hp[0], hp[1], hp[2], sqv,
        Sb, nullptr, nullptr, nullptr, H2_DIM, H2_DIM, N_PTS, 0, b * rowblk);
    topk_att<<<rowblk / 4, 256, 0, stream>>>((const unsigned*)Sb, f1v, f2v, WhF, Wc, bc, out, b * rowblk);
  }
}

// Round 17
// 187.883 us; speedup vs baseline: 1.0638x; 1.0282x over previous
//
#include <hip/hip_runtime.h>
#include <float.h>

#define N_PTS 6144
#define D_IN  512
#define H1_DIM 256
#define H2_DIM 128
#define G_DIM  64
#define KNN    32
#define NOUT   22

typedef short s8v __attribute__((ext_vector_type(8)));   // 8 bf16 in 4 VGPR
typedef float f32x4 __attribute__((ext_vector_type(4)));
typedef unsigned u32x4 __attribute__((ext_vector_type(4)));
typedef unsigned short u16;
typedef unsigned long long u64;

__device__ __forceinline__ u16 f2bf(float f) {
  unsigned u = __float_as_uint(f);
  u += 0x7FFFu + ((u >> 16) & 1u);          // RNE to bf16
  return (u16)(u >> 16);
}
__device__ __forceinline__ float bf2f(u16 s) {
  return __uint_as_float(((unsigned)s) << 16);
}
__device__ __forceinline__ void split3(float v, u16& a0, u16& a1, u16& a2) {
  a0 = f2bf(v);
  float r1 = v - bf2f(a0);
  a1 = f2bf(r1);
  a2 = f2bf(r1 - bf2f(a1));
}
__device__ __forceinline__ unsigned sortkey(float f) {
  unsigned ub = __float_as_uint(f);
  return (ub & 0x80000000u) ? ~ub : (ub | 0x80000000u);
}

// ---------------------------------------------------------------------------
// MFMA GEMM, 3-way bf16 split, 6-term schedule (fp32-equivalent).
// C[M,N] = A[M,K] * B^T[N,K].  BN=64, BK=32, 4 waves (2x2), wave tile (BM/2)x32.
// Staging via global_load_lds; XOR slot-swizzle realized by inverse-swizzling
// the per-lane global SOURCE slot (LDS dest linear).
// WKEY: epilogue writes sortable-u32 kNN keys (sq[col]-2*val; diag=UINT_MAX).
// SYMM (with WKEY): only super-tiles (x>>1)>=y computed; strictly-upper tiles
// also emit the mirrored keys (sq[row]-2*val) at (col,row), transposed through
// LDS (stride 129, conflict-free) and written coalesced.
// ---------------------------------------------------------------------------
template<int BM, bool AF32, bool SPLITK, bool BIAS, bool RELU, bool WF32, bool WSPLIT, bool WKEY, bool SYMM>
__global__ __launch_bounds__(256, 4) void mfma_gemm(
    const void* __restrict__ A0any, const u16* __restrict__ A1_, const u16* __restrict__ A2_,
    const u16* __restrict__ B0_, const u16* __restrict__ B1_, const u16* __restrict__ B2_,
    const float* __restrict__ bias,
    float* __restrict__ Cf, u16* __restrict__ C0, u16* __restrict__ C1, u16* __restrict__ C2,
    int Ktot, int Ks, int ldC, size_t MN, int rowoff)
{
  if (SYMM) {
    if ((int)(blockIdx.x >> 1) < (int)blockIdx.y) return;   // block-uniform
  }
  const int MT = BM / 32, NT = 2;
  const int APL = BM * 32;              // u16 per A plane
  const int BBASE = 3 * APL;            // u16 offset of B region
  __shared__ u16 lds[(BM + 64) * 32 * 3];

  const int t = threadIdx.x;
  const int lane = t & 63, wave = t >> 6;
  const int wm = wave >> 1, wn = wave & 1;
  const int m0 = blockIdx.y * BM, n0 = blockIdx.x * 64;
  const int kz = blockIdx.z * Ks;

  f32x4 acc[MT][NT] = {};

  const int pA = BM / 16;               // 1KB chunks per A plane
  const int NC = 3 * pA + 12;           // total chunks (A + B planes)

  for (int k0 = 0; k0 < Ks; k0 += 32) {
    if (k0) __syncthreads();
    const int kb = kz + k0;
    if (AF32) {
      const float* A = (const float*)A0any;
      #pragma unroll
      for (int c0 = 0; c0 < BM * 4; c0 += 256) {
        int c = c0 + t;
        int row = c >> 2, slot = c & 3;
        const float* g = A + (size_t)(m0 + row) * Ktot + kb + slot * 8;
        f32x4 fa = *(const f32x4*)g;
        f32x4 fb = *(const f32x4*)(g + 4);
        int dst = row * 32 + ((slot ^ ((row >> 1) & 3)) << 3);
        s8v v0, v1, v2;
        #pragma unroll
        for (int e = 0; e < 4; ++e) {
          u16 a0, a1, a2; split3(fa[e], a0, a1, a2);
          v0[e] = (short)a0; v1[e] = (short)a1; v2[e] = (short)a2;
        }
        #pragma unroll
        for (int e = 0; e < 4; ++e) {
          u16 a0, a1, a2; split3(fb[e], a0, a1, a2);
          v0[4 + e] = (short)a0; v1[4 + e] = (short)a1; v2[4 + e] = (short)a2;
        }
        *(s8v*)(lds + dst) = v0;
        *(s8v*)(lds + APL + dst) = v1;
        *(s8v*)(lds + 2 * APL + dst) = v2;
      }
      for (int c = wave; c < 12; c += 4) {
        int p = c >> 2, lc = c & 3;
        int row = lc * 16 + (lane >> 2);
        int srcslot = (lane & 3) ^ ((row >> 1) & 3);
        const u16* src = (p == 0) ? B0_ : (p == 1) ? B1_ : B2_;
        const u16* g = src + (size_t)(n0 + row) * Ktot + kb + srcslot * 8;
        __builtin_amdgcn_global_load_lds(
            (const __attribute__((address_space(1))) unsigned*)g,
            (__attribute__((address_space(3))) unsigned*)(lds + BBASE + p * 2048 + lc * 512),
            16, 0, 0);
      }
    } else {
      for (int c = wave; c < NC; c += 4) {
        const u16* src; int dstoff; int row0; int lc;
        if (c < 3 * pA) {
          int p = c / pA; lc = c % pA;
          src = (p == 0) ? (const u16*)A0any : (p == 1) ? A1_ : A2_;
          dstoff = p * APL + lc * 512;
          row0 = m0;
        } else {
          int cb = c - 3 * pA;
          int p = cb >> 2; lc = cb & 3;
          src = (p == 0) ? B0_ : (p == 1) ? B1_ : B2_;
          dstoff = BBASE + p * 2048 + lc * 512;
          row0 = n0;
        }
        int row = lc * 16 + (lane >> 2);
        int srcslot = (lane & 3) ^ ((row >> 1) & 3);
        const u16* g = src + (size_t)(row0 + row) * Ktot + kb + srcslot * 8;
        __builtin_amdgcn_global_load_lds(
            (const __attribute__((address_space(1))) unsigned*)g,
            (__attribute__((address_space(3))) unsigned*)(lds + dstoff),
            16, 0, 0);
      }
    }
    __syncthreads();

    s8v af[3][MT], bf[3][NT];
    #pragma unroll
    for (int mt = 0; mt < MT; ++mt) {
      int r = wm * (BM / 2) + mt * 16 + (lane & 15);
      int off = r * 32 + (((lane >> 4) ^ ((r >> 1) & 3)) << 3);
      #pragma unroll
      for (int p = 0; p < 3; ++p) af[p][mt] = *(const s8v*)(lds + p * APL + off);
    }
    #pragma unroll
    for (int nt = 0; nt < NT; ++nt) {
      int r = wn * 32 + nt * 16 + (lane & 15);
      int off = r * 32 + (((lane >> 4) ^ ((r >> 1) & 3)) << 3);
      #pragma unroll
      for (int p = 0; p < 3; ++p) bf[p][nt] = *(const s8v*)(lds + BBASE + p * 2048 + off);
    }
    #pragma unroll
    for (int mt = 0; mt < MT; ++mt)
      #pragma unroll
      for (int nt = 0; nt < NT; ++nt) {
        f32x4 a = acc[mt][nt];
        a = __builtin_amdgcn_mfma_f32_16x16x32_bf16(af[0][mt], bf[0][nt], a, 0, 0, 0);
        a = __builtin_amdgcn_mfma_f32_16x16x32_bf16(af[0][mt], bf[1][nt], a, 0, 0, 0);
        a = __builtin_amdgcn_mfma_f32_16x16x32_bf16(af[1][mt], bf[0][nt], a, 0, 0, 0);
        a = __builtin_amdgcn_mfma_f32_16x16x32_bf16(af[1][mt], bf[1][nt], a, 0, 0, 0);
        a = __builtin_amdgcn_mfma_f32_16x16x32_bf16(af[0][mt], bf[2][nt], a, 0, 0, 0);
        a = __builtin_amdgcn_mfma_f32_16x16x32_bf16(af[2][mt], bf[0][nt], a, 0, 0, 0);
        acc[mt][nt] = a;
      }
  }

  const bool mirror = SYMM && ((int)(blockIdx.x >> 1) > (int)blockIdx.y);
  unsigned* ldsT = (unsigned*)lds;      // reused post-compute (barrier below)

  #pragma unroll
  for (int mt = 0; mt < MT; ++mt) {
    #pragma unroll
    for (int nt = 0; nt < NT; ++nt) {
      int col = n0 + wn * 32 + nt * 16 + (lane & 15);
      float bv = (BIAS && !SPLITK) ? bias[col] : 0.f;
      float sqc = WKEY ? bias[col] : 0.f;
      #pragma unroll
      for (int v = 0; v < 4; ++v) {
        int row = m0 + wm * (BM / 2) + mt * 16 + (lane >> 4) * 4 + v;
        float val = acc[mt][nt][v] + bv;
        size_t o = (size_t)row * ldC + col;
        if (SPLITK) {
          Cf[(size_t)blockIdx.z * MN + o] = val;
        } else if (WKEY) {
          float f = fmaf(-2.f, val, sqc);
          unsigned uu = sortkey(f);
          if (rowoff + row == col) uu = 0xFFFFFFFFu;
          ((unsigned*)Cf)[o] = uu;
          if (mirror) {
            // stash (col,row) key in registers via acc slot reuse: compute now
            float fb2 = fmaf(-2.f, val, bias[row]);
            acc[mt][nt][v] = __uint_as_float(sortkey(fb2));   // reuse acc as key store
          }
        } else {
          if (RELU) val = fmaxf(val, 0.f);
          if (WF32) Cf[o] = val;
          if (WSPLIT) {
            u16 a0, a1, a2; split3(val, a0, a1, a2);
            C0[o] = a0; C1[o] = a1; C2[o] = a2;
          }
        }
      }
    }
  }

  if (WKEY && mirror) {
    __syncthreads();                    // all LDS operand reads complete
    #pragma unroll
    for (int mt = 0; mt < MT; ++mt) {
      #pragma unroll
      for (int nt = 0; nt < NT; ++nt) {
        int cl = wn * 32 + nt * 16 + (lane & 15);     // local col 0..63
        #pragma unroll
        for (int v = 0; v < 4; ++v) {
          int rl = wm * (BM / 2) + mt * 16 + (lane >> 4) * 4 + v;   // local row
          ldsT[cl * 129 + rl] = __float_as_uint(acc[mt][nt][v]);
        }
      }
    }
    __syncthreads();
    // coalesced write-out: 64 rows (global col j) x 128 keys each
    unsigned* Cu = (unsigned*)Cf;
    for (int e = t; e < 64 * 32; e += 256) {
      int jr = e >> 5, cq = e & 31;
      u32x4 vv;
      #pragma unroll
      for (int x = 0; x < 4; ++x) vv[x] = ldsT[jr * 129 + cq * 4 + x];
      *(u32x4*)(Cu + (size_t)(n0 + jr) * ldC + m0 + cq * 4) = vv;
    }
  }
}

template<int S, bool BIAS, bool RELU, bool WF32, bool WSPLIT>
__global__ void combine(const float* __restrict__ P, const float* __restrict__ bias,
                        size_t MN, int Ncols,
                        float* __restrict__ Cf, u16* __restrict__ C0,
                        u16* __restrict__ C1, u16* __restrict__ C2)
{
  size_t idx = ((size_t)blockIdx.x * 256 + threadIdx.x) * 4;
  if (idx >= MN) return;
  f32x4 s = *(const f32x4*)(P + idx);
  #pragma unroll
  for (int z = 1; z < S; ++z) s += *(const f32x4*)(P + (size_t)z * MN + idx);
  int n = (int)(idx % (size_t)Ncols);
  #pragma unroll
  for (int e = 0; e < 4; ++e) {
    float v = s[e] + (BIAS ? bias[n + e] : 0.f);
    if (RELU) v = fmaxf(v, 0.f);
    if (WF32) Cf[idx + e] = v;
    if (WSPLIT) {
      u16 a0, a1, a2; split3(v, a0, a1, a2);
      C0[idx + e] = a0; C1[idx + e] = a1; C2[idx + e] = a2;
    }
  }
}

__global__ void trans_split3(const float* __restrict__ W0, u16* __restrict__ a0,
                             u16* __restrict__ a1, u16* __restrict__ a2,
                             const float* __restrict__ W1, u16* __restrict__ b0,
                             u16* __restrict__ b1, u16* __restrict__ b2,
                             const float* __restrict__ gW, u16* __restrict__ c0,
                             u16* __restrict__ c1, u16* __restrict__ c2)
{
  int id = blockIdx.x * 256 + threadIdx.x;
  const int S0 = D_IN * H1_DIM, S1 = H1_DIM * H2_DIM, S2 = H2_DIM * G_DIM;
  const float* W; u16 *p0, *p1, *p2; int K, N;
  if (id < S0)           { W = W0; p0 = a0; p1 = a1; p2 = a2; K = D_IN;   N = H1_DIM; }
  else if (id < S0 + S1) { id -= S0; W = W1; p0 = b0; p1 = b1; p2 = b2; K = H1_DIM; N = H2_DIM; }
  else if (id < S0 + S1 + S2) { id -= S0 + S1; W = gW; p0 = c0; p1 = c1; p2 = c2; K = H2_DIM; N = G_DIM; }
  else return;
  int k = id / N, n = id % N;
  u16 x0, x1, x2;
  split3(W[id], x0, x1, x2);
  size_t o = (size_t)n * K + k;
  p0[o] = x0; p1[o] = x1; p2[o] = x2;
}

__global__ void prep_head(const float* __restrict__ cW, const float* __restrict__ cb,
                          const float* __restrict__ dW, const float* __restrict__ db,
                          float* __restrict__ Wc, float* __restrict__ bc)
{
  int t = threadIdx.x;
  for (int idx = t; idx < 64 * NOUT; idx += 256) {
    int g = idx / NOUT, c = idx % NOUT;
    float s = 0.f;
    if (c < 16) {
      for (int r = 0; r < 8; ++r) s += cW[(r * 64 + g) * 16 + c];
    } else {
      int k = (c - 16) >> 1, o = (c - 16) & 1;
      for (int r = 0; r < 8; ++r) s += dW[k * 1024 + (r * 64 + g) * 2 + o];
    }
    Wc[idx] = s;
  }
  if (t < NOUT) bc[t] = (t < 16) ? cb[t] : db[t - 16];
}

__global__ void row_stats(const float* __restrict__ h, const float* __restrict__ Wh,
                          const float* __restrict__ ga, float* __restrict__ sq,
                          float* __restrict__ f1, float* __restrict__ f2)
{
  int i = blockIdx.x * 256 + threadIdx.x;
  const float* hr = h + (size_t)i * H2_DIM;
  float s = 0.f;
  for (int k = 0; k < H2_DIM; ++k) { float v = hr[k]; s = fmaf(v, v, s); }
  sq[i] = s;
  const float* wr = Wh + (size_t)i * G_DIM;
  float a = 0.f, b = 0.f;
  for (int g = 0; g < G_DIM; ++g) {
    float w = wr[g];
    a = fmaf(w, ga[g], a);
    b = fmaf(w, ga[G_DIM + g], b);
  }
  f1[i] = a; f2[i] = b;
}

// ---------------------------------------------------------------------------
// r12-proven topk: one wave per row, quad-min tournament -> quaternary
// bisection -> ballot collect (cap 64 quads) -> register 128-bitonic /
// LDS 256-bitonic on (key<<13|j) -> exact top-32 with np tie-break;
// wave-local softmax + PV + head.
// ---------------------------------------------------------------------------
__global__ __launch_bounds__(256) void topk_att(const unsigned* __restrict__ Sb,
    const float* __restrict__ f1, const float* __restrict__ f2,
    const float* __restrict__ Wh, const float* __restrict__ Wc, const float* __restrict__ bc,
    float* __restrict__ out, int m0)
{
  const int t = threadIdx.x;
  const int lane = t & 63, wv = t >> 6;
  const int row4 = blockIdx.x * 4 + wv;
  const int i = m0 + row4;
  const unsigned* Srow = Sb + (size_t)row4 * N_PTS;

  __shared__ float WcL[64 * NOUT];
  __shared__ u64 candS[4][256];
  __shared__ int neighS[4][33];
  __shared__ float attS[4][33];
  __shared__ float hpfS[4][64];

  for (int idx = t; idx < 64 * NOUT; idx += 256) WcL[idx] = Wc[idx];
  __syncthreads();

  unsigned q[24];
  #pragma unroll
  for (int c = 0; c < 24; ++c) {
    u32x4 v = *(const u32x4*)(Srow + (c << 8) + (lane << 2));
    unsigned a = v[0] < v[1] ? v[0] : v[1];
    unsigned b = v[2] < v[3] ? v[2] : v[3];
    q[c] = a < b ? a : b;
  }

  unsigned lmin = q[0];
  #pragma unroll
  for (int c = 1; c < 24; ++c) lmin = q[c] < lmin ? q[c] : lmin;

  unsigned mnl = lmin, mxl = lmin;
  #pragma unroll
  for (int off = 32; off > 0; off >>= 1) {
    unsigned o1 = __shfl_xor(mnl, off); mnl = o1 < mnl ? o1 : mnl;
    unsigned o2 = __shfl_xor(mxl, off); mxl = o2 > mxl ? o2 : mxl;
  }

  long long lo = (long long)mnl - 1, hi = (long long)mxl;
  while (hi - lo > 1) {
    long long span = hi - lo;
    unsigned m1 = (unsigned)(lo + (span >> 2));
    unsigned m2 = (unsigned)(lo + (span >> 1));
    unsigned m3 = (unsigned)(hi - (span >> 2));
    int c1 = 0, c2 = 0, c3 = 0;
    #pragma unroll
    for (int c = 0; c < 24; ++c) {
      c1 += (q[c] <= m1);
      c2 += (q[c] <= m2);
      c3 += (q[c] <= m3);
    }
    #pragma unroll
    for (int off = 32; off > 0; off >>= 1) {
      c1 += __shfl_xor(c1, off);
      c2 += __shfl_xor(c2, off);
      c3 += __shfl_xor(c3, off);
    }
    if (c1 >= KNN)       { hi = m1; }
    else if (c2 >= KNN)  { lo = m1; hi = m2; }
    else if (c3 >= KNN)  { lo = m2; hi = m3; }
    else                 { lo = m3; }
  }
  const unsigned Q = (unsigned)hi;

  candS[wv][lane] = ~0ull;
  candS[wv][64 + lane] = ~0ull;
  candS[wv][128 + lane] = ~0ull;
  candS[wv][192 + lane] = ~0ull;
  const u64 below = (lane == 0) ? 0ull : (~0ull >> (64 - lane));
  int cnt = 0;
  #pragma unroll
  for (int c = 0; c < 24; ++c) {
    bool act = (q[c] <= Q);
    u64 mask = __ballot(act);
    if (act) {
      int pos = cnt + (int)__popcll(mask & below);
      if (pos < 64) {
        u32x4 v = *(const u32x4*)(Srow + (c << 8) + (lane << 2));
        #pragma unroll
        for (int e = 0; e < 4; ++e) {
          int j = (c << 8) + (lane << 2) + e;
          candS[wv][pos * 4 + e] = ((u64)v[e] << 13) | (unsigned)j;
        }
      }
    }
    cnt += (int)__popcll(mask);
  }

  if (cnt <= 32) {
    u64 v0 = candS[wv][2 * lane], v1 = candS[wv][2 * lane + 1];
    const int e0 = 2 * lane, e1 = e0 + 1;
    for (int k = 2; k <= 128; k <<= 1) {
      for (int j = k >> 1; j >= 2; j >>= 1) {
        int half = j >> 1;
        u64 o0 = __shfl_xor(v0, half);
        u64 o1 = __shfl_xor(v1, half);
        bool up0 = ((e0 & k) == 0) == ((e0 & j) == 0);
        bool up1 = ((e1 & k) == 0) == ((e1 & j) == 0);
        v0 = up0 ? (v0 < o0 ? v0 : o0) : (v0 > o0 ? v0 : o0);
        v1 = up1 ? (v1 < o1 ? v1 : o1) : (v1 > o1 ? v1 : o1);
      }
      bool asc = ((e0 & k) == 0);
      u64 a = v0 < v1 ? v0 : v1, b = v0 < v1 ? v1 : v0;
      v0 = asc ? a : b;
      v1 = asc ? b : a;
    }
    if (lane < 16) {
      neighS[wv][2 * lane]     = (int)(v0 & 0x1FFFu);
      neighS[wv][2 * lane + 1] = (int)(v1 & 0x1FFFu);
    }
    if (lane == 0) neighS[wv][32] = i;
  } else {
    for (int k = 2; k <= 256; k <<= 1) {
      for (int j = k >> 1; j >= 1; j >>= 1) {
        #pragma unroll
        for (int s = 0; s < 4; ++s) {
          int e = lane + s * 64;
          int p = e ^ j;
          if (p > e) {
            u64 a = candS[wv][e], b = candS[wv][p];
            bool asc = ((e & k) == 0);
            if ((a > b) == asc) { candS[wv][e] = b; candS[wv][p] = a; }
          }
        }
      }
    }
    if (lane < KNN) neighS[wv][lane] = (int)(candS[wv][lane] & 0x1FFFu);
    if (lane == 0) neighS[wv][32] = i;
  }

  {
    float e = -FLT_MAX;
    if (lane < 33) {
      float raw = f1[i] + f2[neighS[wv][lane]];
      e = raw > 0.f ? raw : 0.2f * raw;
    }
    float mx = e;
    #pragma unroll
    for (int off = 32; off > 0; off >>= 1) mx = fmaxf(mx, __shfl_xor(mx, off));
    float ex = (lane < 33) ? expf(e - mx) : 0.f;
    float sm = ex;
    #pragma unroll
    for (int off = 32; off > 0; off >>= 1) sm += __shfl_xor(sm, off);
    if (lane < 33) attS[wv][lane] = ex / sm;
  }

  {
    float s = 0.f;
    for (int m = 0; m < 33; ++m)
      s = fmaf(attS[wv][m], Wh[(size_t)neighS[wv][m] * G_DIM + lane], s);
    hpfS[wv][lane] = s > 0.f ? s : expm1f(s);
  }

  if (lane < NOUT) {
    float o = bc[lane];
    for (int g = 0; g < 64; ++g) o = fmaf(hpfS[wv][g], WcL[g * NOUT + lane], o);
    out[(size_t)i * NOUT + lane] = o;
  }
}

extern "C" void kernel_launch(void* const* d_in, const int* in_sizes, int n_in,
                              void* d_out, int out_size, void* d_ws, size_t ws_size,
                              hipStream_t stream)
{
  const float* x  = (const float*)d_in[0];
  const float* W0 = (const float*)d_in[1];
  const float* b0 = (const float*)d_in[2];
  const float* W1 = (const float*)d_in[3];
  const float* b1 = (const float*)d_in[4];
  const float* gW = (const float*)d_in[5];
  const float* ga = (const float*)d_in[6];
  const float* cW = (const float*)d_in[7];
  const float* cb = (const float*)d_in[8];
  const float* dW = (const float*)d_in[9];
  const float* db = (const float*)d_in[10];
  float* out = (float*)d_out;

  char* base = (char*)d_ws;
  char* w = base;
  auto alloc = [&](size_t bytes) { char* p = w; w += (bytes + 255) & ~(size_t)255; return p; };
  u16 *W0p[3], *W1p[3], *gWp[3], *h1p[3], *hp[3];
  for (int p = 0; p < 3; ++p) W0p[p] = (u16*)alloc((size_t)D_IN * H1_DIM * 2);
  for (int p = 0; p < 3; ++p) W1p[p] = (u16*)alloc((size_t)H1_DIM * H2_DIM * 2);
  for (int p = 0; p < 3; ++p) gWp[p] = (u16*)alloc((size_t)H2_DIM * G_DIM * 2);
  for (int p = 0; p < 3; ++p) h1p[p] = (u16*)alloc((size_t)N_PTS * H1_DIM * 2);
  for (int p = 0; p < 3; ++p) hp[p]  = (u16*)alloc((size_t)N_PTS * H2_DIM * 2);
  float* hF  = (float*)alloc((size_t)N_PTS * H2_DIM * 4);
  float* WhF = (float*)alloc((size_t)N_PTS * G_DIM * 4);
  float* sqv = (float*)alloc(N_PTS * 4);
  float* f1v = (float*)alloc(N_PTS * 4);
  float* f2v = (float*)alloc(N_PTS * 4);
  float* Wc  = (float*)alloc(64 * NOUT * 4);
  float* bc  = (float*)alloc(64 * 4);

  char* pbase = w;
  const size_t MN1 = (size_t)N_PTS * H1_DIM;
  const size_t MN2 = (size_t)N_PTS * H2_DIM;
  const size_t MN3 = (size_t)N_PTS * G_DIM;
  float* P1 = (float*)alloc(4 * MN1 * 4);
  float* P2 = (float*)alloc(4 * MN2 * 4);
  float* P3 = (float*)alloc(4 * MN3 * 4);
  float* Sb = (float*)pbase;

  size_t used_persist = (size_t)(pbase - base);
  size_t avail = (ws_size > used_persist) ? (ws_size - used_persist) / 4 : 0;
  int rowblk = 128;
  const int rcand[] = {6144, 3072, 1536, 768, 384, 256, 128};
  for (int c : rcand) { if ((size_t)c * N_PTS <= avail) { rowblk = c; break; } }

  const int TS = D_IN * H1_DIM + H1_DIM * H2_DIM + H2_DIM * G_DIM;
  trans_split3<<<(TS + 255) / 256, 256, 0, stream>>>(
      W0, W0p[0], W0p[1], W0p[2], W1, W1p[0], W1p[1], W1p[2], gW, gWp[0], gWp[1], gWp[2]);
  prep_head<<<1, 256, 0, stream>>>(cW, cb, dW, db, Wc, bc);

  mfma_gemm<64, true, true, false, false, false, false, false, false>
      <<<dim3(H1_DIM / 64, N_PTS / 64, 4), 256, 0, stream>>>(
      x, nullptr, nullptr, W0p[0], W0p[1], W0p[2], nullptr,
      P1, nullptr, nullptr, nullptr, D_IN, D_IN / 4, H1_DIM, MN1, 0);
  combine<4, true, true, false, true><<<(int)(MN1 / 1024), 256, 0, stream>>>(
      P1, b0, MN1, H1_DIM, nullptr, h1p[0], h1p[1], h1p[2]);

  mfma_gemm<64, false, true, false, false, false, false, false, false>
      <<<dim3(H2_DIM / 64, N_PTS / 64, 4), 256, 0, stream>>>(
      h1p[0], h1p[1], h1p[2], W1p[0], W1p[1], W1p[2], nullptr,
      P2, nullptr, nullptr, nullptr, H1_DIM, H1_DIM / 4, H2_DIM, MN2, 0);
  combine<4, true, true, true, true><<<(int)(MN2 / 1024), 256, 0, stream>>>(
      P2, b1, MN2, H2_DIM, hF, hp[0], hp[1], hp[2]);

  mfma_gemm<64, false, true, false, false, false, false, false, false>
      <<<dim3(G_DIM / 64, N_PTS / 64, 4), 256, 0, stream>>>(
      hp[0], hp[1], hp[2], gWp[0], gWp[1], gWp[2], nullptr,
      P3, nullptr, nullptr, nullptr, H2_DIM, H2_DIM / 4, G_DIM, MN3, 0);
  combine<4, false, false, true, false><<<(int)(MN3 / 1024), 256, 0, stream>>>(
      P3, nullptr, MN3, G_DIM, WhF, nullptr, nullptr, nullptr);

  row_stats<<<N_PTS / 256, 256, 0, stream>>>(hF, WhF, ga, sqv, f1v, f2v);

  if (rowblk == N_PTS) {
    // symmetric Gram: only super-tiles (x>>1)>=y computed; mirrored keys
    // written transposed through LDS.
    mfma_gemm<128, false, false, false, false, false, false, true, true>
        <<<dim3(N_PTS / 64, N_PTS / 128, 1), 256, 0, stream>>>(
        hp[0], hp[1], hp[2], hp[0], hp[1], hp[2], sqv,
        Sb, nullptr, nullptr, nullptr, H2_DIM, H2_DIM, N_PTS, 0, 0);
    topk_att<<<N_PTS / 4, 256, 0, stream>>>((const unsigned*)Sb, f1v, f2v, WhF, Wc, bc, out, 0);
  } else {
    for (int b = 0; b < N_PTS / rowblk; ++b) {
      mfma_gemm<128, false, false, false, false, false, false, true, false>
          <<<dim3(N_PTS / 64, rowblk / 128, 1), 256, 0, stream>>>(
          hp[0] + (size_t)b * rowblk * H2_DIM, hp[1] + (size_t)b * rowblk * H2_DIM,
          hp[2] + (size_t)b * rowblk * H2_DIM, hp[0], hp[1], hp[2], sqv,
          Sb, nullptr, nullptr, nullptr, H2_DIM, H2_DIM, N_PTS, 0, b * rowblk);
      topk_att<<<rowblk / 4, 256, 0, stream>>>((const unsigned*)Sb, f1v, f2v, WhF, Wc, bc, out, b * rowblk);
    }
  }
}

// Round 18
// 182.994 us; speedup vs baseline: 1.0922x; 1.0267x over previous
//
#include <hip/hip_runtime.h>
#include <float.h>

#define N_PTS 6144
#define D_IN  512
#define H1_DIM 256
#define H2_DIM 128
#define G_DIM  64
#define KNN    32
#define NOUT   22

typedef short s8v __attribute__((ext_vector_type(8)));   // 8 bf16 in 4 VGPR
typedef float f32x4 __attribute__((ext_vector_type(4)));
typedef unsigned u32x4 __attribute__((ext_vector_type(4)));
typedef unsigned short u16;
typedef unsigned long long u64;

__device__ __forceinline__ u16 f2bf(float f) {
  unsigned u = __float_as_uint(f);
  u += 0x7FFFu + ((u >> 16) & 1u);          // RNE to bf16
  return (u16)(u >> 16);
}
__device__ __forceinline__ float bf2f(u16 s) {
  return __uint_as_float(((unsigned)s) << 16);
}
__device__ __forceinline__ void split3(float v, u16& a0, u16& a1, u16& a2) {
  a0 = f2bf(v);
  float r1 = v - bf2f(a0);
  a1 = f2bf(r1);
  a2 = f2bf(r1 - bf2f(a1));
}
__device__ __forceinline__ unsigned sortkey(float f) {
  unsigned ub = __float_as_uint(f);
  return (ub & 0x80000000u) ? ~ub : (ub | 0x80000000u);
}

// ---------------------------------------------------------------------------
// MFMA GEMM, 3-way bf16 split, 6-term schedule (fp32-equivalent).
// C[M,N] = A[M,K] * B^T[N,K].  BN=64, BK=32, 4 waves (2x2), wave tile (BM/2)x32.
// Staging via global_load_lds; XOR slot-swizzle realized by inverse-swizzling
// the per-lane global SOURCE slot (LDS dest linear).
// WKEY: epilogue writes sortable-u32 kNN keys (sq[col]-2*val; diag=UINT_MAX).
// SYMM (with WKEY): only super-tiles (x>>1)>=y computed; strictly-upper tiles
// also emit the mirrored keys (sq[row]-2*val) at (col,row), transposed through
// LDS (stride 129) and written coalesced.
// ---------------------------------------------------------------------------
template<int BM, bool AF32, bool SPLITK, bool BIAS, bool RELU, bool WF32, bool WSPLIT, bool WKEY, bool SYMM>
__global__ __launch_bounds__(256, 4) void mfma_gemm(
    const void* __restrict__ A0any, const u16* __restrict__ A1_, const u16* __restrict__ A2_,
    const u16* __restrict__ B0_, const u16* __restrict__ B1_, const u16* __restrict__ B2_,
    const float* __restrict__ bias,
    float* __restrict__ Cf, u16* __restrict__ C0, u16* __restrict__ C1, u16* __restrict__ C2,
    int Ktot, int Ks, int ldC, size_t MN, int rowoff)
{
  if (SYMM) {
    if ((int)(blockIdx.x >> 1) < (int)blockIdx.y) return;   // block-uniform
  }
  const int MT = BM / 32, NT = 2;
  const int APL = BM * 32;              // u16 per A plane
  const int BBASE = 3 * APL;            // u16 offset of B region
  __shared__ u16 lds[(BM + 64) * 32 * 3];

  const int t = threadIdx.x;
  const int lane = t & 63, wave = t >> 6;
  const int wm = wave >> 1, wn = wave & 1;
  const int m0 = blockIdx.y * BM, n0 = blockIdx.x * 64;
  const int kz = blockIdx.z * Ks;

  f32x4 acc[MT][NT] = {};

  const int pA = BM / 16;               // 1KB chunks per A plane
  const int NC = 3 * pA + 12;           // total chunks (A + B planes)

  for (int k0 = 0; k0 < Ks; k0 += 32) {
    if (k0) __syncthreads();
    const int kb = kz + k0;
    if (AF32) {
      const float* A = (const float*)A0any;
      #pragma unroll
      for (int c0 = 0; c0 < BM * 4; c0 += 256) {
        int c = c0 + t;
        int row = c >> 2, slot = c & 3;
        const float* g = A + (size_t)(m0 + row) * Ktot + kb + slot * 8;
        f32x4 fa = *(const f32x4*)g;
        f32x4 fb = *(const f32x4*)(g + 4);
        int dst = row * 32 + ((slot ^ ((row >> 1) & 3)) << 3);
        s8v v0, v1, v2;
        #pragma unroll
        for (int e = 0; e < 4; ++e) {
          u16 a0, a1, a2; split3(fa[e], a0, a1, a2);
          v0[e] = (short)a0; v1[e] = (short)a1; v2[e] = (short)a2;
        }
        #pragma unroll
        for (int e = 0; e < 4; ++e) {
          u16 a0, a1, a2; split3(fb[e], a0, a1, a2);
          v0[4 + e] = (short)a0; v1[4 + e] = (short)a1; v2[4 + e] = (short)a2;
        }
        *(s8v*)(lds + dst) = v0;
        *(s8v*)(lds + APL + dst) = v1;
        *(s8v*)(lds + 2 * APL + dst) = v2;
      }
      for (int c = wave; c < 12; c += 4) {
        int p = c >> 2, lc = c & 3;
        int row = lc * 16 + (lane >> 2);
        int srcslot = (lane & 3) ^ ((row >> 1) & 3);
        const u16* src = (p == 0) ? B0_ : (p == 1) ? B1_ : B2_;
        const u16* g = src + (size_t)(n0 + row) * Ktot + kb + srcslot * 8;
        __builtin_amdgcn_global_load_lds(
            (const __attribute__((address_space(1))) unsigned*)g,
            (__attribute__((address_space(3))) unsigned*)(lds + BBASE + p * 2048 + lc * 512),
            16, 0, 0);
      }
    } else {
      for (int c = wave; c < NC; c += 4) {
        const u16* src; int dstoff; int row0; int lc;
        if (c < 3 * pA) {
          int p = c / pA; lc = c % pA;
          src = (p == 0) ? (const u16*)A0any : (p == 1) ? A1_ : A2_;
          dstoff = p * APL + lc * 512;
          row0 = m0;
        } else {
          int cb = c - 3 * pA;
          int p = cb >> 2; lc = cb & 3;
          src = (p == 0) ? B0_ : (p == 1) ? B1_ : B2_;
          dstoff = BBASE + p * 2048 + lc * 512;
          row0 = n0;
        }
        int row = lc * 16 + (lane >> 2);
        int srcslot = (lane & 3) ^ ((row >> 1) & 3);
        const u16* g = src + (size_t)(row0 + row) * Ktot + kb + srcslot * 8;
        __builtin_amdgcn_global_load_lds(
            (const __attribute__((address_space(1))) unsigned*)g,
            (__attribute__((address_space(3))) unsigned*)(lds + dstoff),
            16, 0, 0);
      }
    }
    __syncthreads();

    s8v af[3][MT], bf[3][NT];
    #pragma unroll
    for (int mt = 0; mt < MT; ++mt) {
      int r = wm * (BM / 2) + mt * 16 + (lane & 15);
      int off = r * 32 + (((lane >> 4) ^ ((r >> 1) & 3)) << 3);
      #pragma unroll
      for (int p = 0; p < 3; ++p) af[p][mt] = *(const s8v*)(lds + p * APL + off);
    }
    #pragma unroll
    for (int nt = 0; nt < NT; ++nt) {
      int r = wn * 32 + nt * 16 + (lane & 15);
      int off = r * 32 + (((lane >> 4) ^ ((r >> 1) & 3)) << 3);
      #pragma unroll
      for (int p = 0; p < 3; ++p) bf[p][nt] = *(const s8v*)(lds + BBASE + p * 2048 + off);
    }
    #pragma unroll
    for (int mt = 0; mt < MT; ++mt)
      #pragma unroll
      for (int nt = 0; nt < NT; ++nt) {
        f32x4 a = acc[mt][nt];
        a = __builtin_amdgcn_mfma_f32_16x16x32_bf16(af[0][mt], bf[0][nt], a, 0, 0, 0);
        a = __builtin_amdgcn_mfma_f32_16x16x32_bf16(af[0][mt], bf[1][nt], a, 0, 0, 0);
        a = __builtin_amdgcn_mfma_f32_16x16x32_bf16(af[1][mt], bf[0][nt], a, 0, 0, 0);
        a = __builtin_amdgcn_mfma_f32_16x16x32_bf16(af[1][mt], bf[1][nt], a, 0, 0, 0);
        a = __builtin_amdgcn_mfma_f32_16x16x32_bf16(af[0][mt], bf[2][nt], a, 0, 0, 0);
        a = __builtin_amdgcn_mfma_f32_16x16x32_bf16(af[2][mt], bf[0][nt], a, 0, 0, 0);
        acc[mt][nt] = a;
      }
  }

  const bool mirror = SYMM && ((int)(blockIdx.x >> 1) > (int)blockIdx.y);
  unsigned* ldsT = (unsigned*)lds;      // reused post-compute (barrier below)

  #pragma unroll
  for (int mt = 0; mt < MT; ++mt) {
    #pragma unroll
    for (int nt = 0; nt < NT; ++nt) {
      int col = n0 + wn * 32 + nt * 16 + (lane & 15);
      float bv = (BIAS && !SPLITK) ? bias[col] : 0.f;
      float sqc = WKEY ? bias[col] : 0.f;
      #pragma unroll
      for (int v = 0; v < 4; ++v) {
        int row = m0 + wm * (BM / 2) + mt * 16 + (lane >> 4) * 4 + v;
        float val = acc[mt][nt][v] + bv;
        size_t o = (size_t)row * ldC + col;
        if (SPLITK) {
          Cf[(size_t)blockIdx.z * MN + o] = val;
        } else if (WKEY) {
          float f = fmaf(-2.f, val, sqc);
          unsigned uu = sortkey(f);
          if (rowoff + row == col) uu = 0xFFFFFFFFu;
          ((unsigned*)Cf)[o] = uu;
          if (mirror) {
            float fb2 = fmaf(-2.f, val, bias[row]);
            acc[mt][nt][v] = __uint_as_float(sortkey(fb2));   // reuse acc as key store
          }
        } else {
          if (RELU) val = fmaxf(val, 0.f);
          if (WF32) Cf[o] = val;
          if (WSPLIT) {
            u16 a0, a1, a2; split3(val, a0, a1, a2);
            C0[o] = a0; C1[o] = a1; C2[o] = a2;
          }
        }
      }
    }
  }

  if (WKEY && mirror) {
    __syncthreads();                    // all LDS operand reads complete
    #pragma unroll
    for (int mt = 0; mt < MT; ++mt) {
      #pragma unroll
      for (int nt = 0; nt < NT; ++nt) {
        int cl = wn * 32 + nt * 16 + (lane & 15);     // local col 0..63
        #pragma unroll
        for (int v = 0; v < 4; ++v) {
          int rl = wm * (BM / 2) + mt * 16 + (lane >> 4) * 4 + v;   // local row
          ldsT[cl * 129 + rl] = __float_as_uint(acc[mt][nt][v]);
        }
      }
    }
    __syncthreads();
    unsigned* Cu = (unsigned*)Cf;
    for (int e = t; e < 64 * 32; e += 256) {
      int jr = e >> 5, cq = e & 31;
      u32x4 vv;
      #pragma unroll
      for (int x = 0; x < 4; ++x) vv[x] = ldsT[jr * 129 + cq * 4 + x];
      *(u32x4*)(Cu + (size_t)(n0 + jr) * ldC + m0 + cq * 4) = vv;
    }
  }
}

template<int S, bool BIAS, bool RELU, bool WF32, bool WSPLIT>
__global__ void combine(const float* __restrict__ P, const float* __restrict__ bias,
                        size_t MN, int Ncols,
                        float* __restrict__ Cf, u16* __restrict__ C0,
                        u16* __restrict__ C1, u16* __restrict__ C2)
{
  size_t idx = ((size_t)blockIdx.x * 256 + threadIdx.x) * 4;
  if (idx >= MN) return;
  f32x4 s = *(const f32x4*)(P + idx);
  #pragma unroll
  for (int z = 1; z < S; ++z) s += *(const f32x4*)(P + (size_t)z * MN + idx);
  int n = (int)(idx % (size_t)Ncols);
  #pragma unroll
  for (int e = 0; e < 4; ++e) {
    float v = s[e] + (BIAS ? bias[n + e] : 0.f);
    if (RELU) v = fmaxf(v, 0.f);
    if (WF32) Cf[idx + e] = v;
    if (WSPLIT) {
      u16 a0, a1, a2; split3(v, a0, a1, a2);
      C0[idx + e] = a0; C1[idx + e] = a1; C2[idx + e] = a2;
    }
  }
}

// weight transposes+splits AND head collapse in one launch
__global__ void prep_all(const float* __restrict__ W0, u16* __restrict__ a0,
                         u16* __restrict__ a1, u16* __restrict__ a2,
                         const float* __restrict__ W1, u16* __restrict__ b0,
                         u16* __restrict__ b1, u16* __restrict__ b2,
                         const float* __restrict__ gW, u16* __restrict__ c0,
                         u16* __restrict__ c1, u16* __restrict__ c2,
                         const float* __restrict__ cW, const float* __restrict__ cb,
                         const float* __restrict__ dW, const float* __restrict__ db,
                         float* __restrict__ Wc, float* __restrict__ bc)
{
  int id = blockIdx.x * 256 + threadIdx.x;
  const int S0 = D_IN * H1_DIM, S1 = H1_DIM * H2_DIM, S2 = H2_DIM * G_DIM;
  const int SW = S0 + S1 + S2;
  if (id < SW) {
    const float* W; u16 *p0, *p1, *p2; int K, N;
    if (id < S0)           { W = W0; p0 = a0; p1 = a1; p2 = a2; K = D_IN;   N = H1_DIM; }
    else if (id < S0 + S1) { id -= S0; W = W1; p0 = b0; p1 = b1; p2 = b2; K = H1_DIM; N = H2_DIM; }
    else                   { id -= S0 + S1; W = gW; p0 = c0; p1 = c1; p2 = c2; K = H2_DIM; N = G_DIM; }
    int k = id / N, n = id % N;
    u16 x0, x1, x2;
    split3(W[id], x0, x1, x2);
    size_t o = (size_t)n * K + k;
    p0[o] = x0; p1[o] = x1; p2[o] = x2;
    return;
  }
  id -= SW;
  if (id < 64 * NOUT) {
    int g = id / NOUT, c = id % NOUT;
    float s = 0.f;
    if (c < 16) {
      for (int r = 0; r < 8; ++r) s += cW[(r * 64 + g) * 16 + c];
    } else {
      int k = (c - 16) >> 1, o = (c - 16) & 1;
      for (int r = 0; r < 8; ++r) s += dW[k * 1024 + (r * 64 + g) * 2 + o];
    }
    Wc[id] = s;
    if (g == 0) bc[c] = (c < 16) ? cb[c] : db[c - 16];
  }
}

__global__ void row_stats(const float* __restrict__ h, const float* __restrict__ Wh,
                          const float* __restrict__ ga, float* __restrict__ sq,
                          float* __restrict__ f1, float* __restrict__ f2)
{
  int i = blockIdx.x * 256 + threadIdx.x;
  const float* hr = h + (size_t)i * H2_DIM;
  float s = 0.f;
  for (int k = 0; k < H2_DIM; ++k) { float v = hr[k]; s = fmaf(v, v, s); }
  sq[i] = s;
  const float* wr = Wh + (size_t)i * G_DIM;
  float a = 0.f, b = 0.f;
  for (int g = 0; g < G_DIM; ++g) {
    float w = wr[g];
    a = fmaf(w, ga[g], a);
    b = fmaf(w, ga[G_DIM + g], b);
  }
  f1[i] = a; f2[i] = b;
}

// ---------------------------------------------------------------------------
// r12-proven topk, REVERSED row order: first-dispatched blocks process the
// LAST-written key rows (L3-hot), converting read misses to hits.
// One wave per row: quad-min tournament -> quaternary bisection -> ballot
// collect (cap 64 quads) -> register 128-bitonic / LDS 256-bitonic on
// (key<<13|j) -> exact top-32 with np tie-break; softmax + PV + head.
// ---------------------------------------------------------------------------
__global__ __launch_bounds__(256) void topk_att(const unsigned* __restrict__ Sb,
    const float* __restrict__ f1, const float* __restrict__ f2,
    const float* __restrict__ Wh, const float* __restrict__ Wc, const float* __restrict__ bc,
    float* __restrict__ out, int m0, int nrows)
{
  const int t = threadIdx.x;
  const int lane = t & 63, wv = t >> 6;
  const int row4 = (nrows - 4 - blockIdx.x * 4) + wv;   // reversed mapping
  const int i = m0 + row4;
  const unsigned* Srow = Sb + (size_t)row4 * N_PTS;

  __shared__ float WcL[64 * NOUT];
  __shared__ u64 candS[4][256];
  __shared__ int neighS[4][33];
  __shared__ float attS[4][33];
  __shared__ float hpfS[4][64];

  for (int idx = t; idx < 64 * NOUT; idx += 256) WcL[idx] = Wc[idx];
  __syncthreads();

  unsigned q[24];
  #pragma unroll
  for (int c = 0; c < 24; ++c) {
    u32x4 v = *(const u32x4*)(Srow + (c << 8) + (lane << 2));
    unsigned a = v[0] < v[1] ? v[0] : v[1];
    unsigned b = v[2] < v[3] ? v[2] : v[3];
    q[c] = a < b ? a : b;
  }

  unsigned lmin = q[0];
  #pragma unroll
  for (int c = 1; c < 24; ++c) lmin = q[c] < lmin ? q[c] : lmin;

  unsigned mnl = lmin, mxl = lmin;
  #pragma unroll
  for (int off = 32; off > 0; off >>= 1) {
    unsigned o1 = __shfl_xor(mnl, off); mnl = o1 < mnl ? o1 : mnl;
    unsigned o2 = __shfl_xor(mxl, off); mxl = o2 > mxl ? o2 : mxl;
  }

  long long lo = (long long)mnl - 1, hi = (long long)mxl;
  while (hi - lo > 1) {
    long long span = hi - lo;
    unsigned m1 = (unsigned)(lo + (span >> 2));
    unsigned m2 = (unsigned)(lo + (span >> 1));
    unsigned m3 = (unsigned)(hi - (span >> 2));
    int c1 = 0, c2 = 0, c3 = 0;
    #pragma unroll
    for (int c = 0; c < 24; ++c) {
      c1 += (q[c] <= m1);
      c2 += (q[c] <= m2);
      c3 += (q[c] <= m3);
    }
    #pragma unroll
    for (int off = 32; off > 0; off >>= 1) {
      c1 += __shfl_xor(c1, off);
      c2 += __shfl_xor(c2, off);
      c3 += __shfl_xor(c3, off);
    }
    if (c1 >= KNN)       { hi = m1; }
    else if (c2 >= KNN)  { lo = m1; hi = m2; }
    else if (c3 >= KNN)  { lo = m2; hi = m3; }
    else                 { lo = m3; }
  }
  const unsigned Q = (unsigned)hi;

  candS[wv][lane] = ~0ull;
  candS[wv][64 + lane] = ~0ull;
  candS[wv][128 + lane] = ~0ull;
  candS[wv][192 + lane] = ~0ull;
  const u64 below = (lane == 0) ? 0ull : (~0ull >> (64 - lane));
  int cnt = 0;
  #pragma unroll
  for (int c = 0; c < 24; ++c) {
    bool act = (q[c] <= Q);
    u64 mask = __ballot(act);
    if (act) {
      int pos = cnt + (int)__popcll(mask & below);
      if (pos < 64) {
        u32x4 v = *(const u32x4*)(Srow + (c << 8) + (lane << 2));
        #pragma unroll
        for (int e = 0; e < 4; ++e) {
          int j = (c << 8) + (lane << 2) + e;
          candS[wv][pos * 4 + e] = ((u64)v[e] << 13) | (unsigned)j;
        }
      }
    }
    cnt += (int)__popcll(mask);
  }

  if (cnt <= 32) {
    u64 v0 = candS[wv][2 * lane], v1 = candS[wv][2 * lane + 1];
    const int e0 = 2 * lane, e1 = e0 + 1;
    for (int k = 2; k <= 128; k <<= 1) {
      for (int j = k >> 1; j >= 2; j >>= 1) {
        int half = j >> 1;
        u64 o0 = __shfl_xor(v0, half);
        u64 o1 = __shfl_xor(v1, half);
        bool up0 = ((e0 & k) == 0) == ((e0 & j) == 0);
        bool up1 = ((e1 & k) == 0) == ((e1 & j) == 0);
        v0 = up0 ? (v0 < o0 ? v0 : o0) : (v0 > o0 ? v0 : o0);
        v1 = up1 ? (v1 < o1 ? v1 : o1) : (v1 > o1 ? v1 : o1);
      }
      bool asc = ((e0 & k) == 0);
      u64 a = v0 < v1 ? v0 : v1, b = v0 < v1 ? v1 : v0;
      v0 = asc ? a : b;
      v1 = asc ? b : a;
    }
    if (lane < 16) {
      neighS[wv][2 * lane]     = (int)(v0 & 0x1FFFu);
      neighS[wv][2 * lane + 1] = (int)(v1 & 0x1FFFu);
    }
    if (lane == 0) neighS[wv][32] = i;
  } else {
    for (int k = 2; k <= 256; k <<= 1) {
      for (int j = k >> 1; j >= 1; j >>= 1) {
        #pragma unroll
        for (int s = 0; s < 4; ++s) {
          int e = lane + s * 64;
          int p = e ^ j;
          if (p > e) {
            u64 a = candS[wv][e], b = candS[wv][p];
            bool asc = ((e & k) == 0);
            if ((a > b) == asc) { candS[wv][e] = b; candS[wv][p] = a; }
          }
        }
      }
    }
    if (lane < KNN) neighS[wv][lane] = (int)(candS[wv][lane] & 0x1FFFu);
    if (lane == 0) neighS[wv][32] = i;
  }

  {
    float e = -FLT_MAX;
    if (lane < 33) {
      float raw = f1[i] + f2[neighS[wv][lane]];
      e = raw > 0.f ? raw : 0.2f * raw;
    }
    float mx = e;
    #pragma unroll
    for (int off = 32; off > 0; off >>= 1) mx = fmaxf(mx, __shfl_xor(mx, off));
    float ex = (lane < 33) ? expf(e - mx) : 0.f;
    float sm = ex;
    #pragma unroll
    for (int off = 32; off > 0; off >>= 1) sm += __shfl_xor(sm, off);
    if (lane < 33) attS[wv][lane] = ex / sm;
  }

  {
    float s = 0.f;
    for (int m = 0; m < 33; ++m)
      s = fmaf(attS[wv][m], Wh[(size_t)neighS[wv][m] * G_DIM + lane], s);
    hpfS[wv][lane] = s > 0.f ? s : expm1f(s);
  }

  if (lane < NOUT) {
    float o = bc[lane];
    for (int g = 0; g < 64; ++g) o = fmaf(hpfS[wv][g], WcL[g * NOUT + lane], o);
    out[(size_t)i * NOUT + lane] = o;
  }
}

extern "C" void kernel_launch(void* const* d_in, const int* in_sizes, int n_in,
                              void* d_out, int out_size, void* d_ws, size_t ws_size,
                              hipStream_t stream)
{
  const float* x  = (const float*)d_in[0];
  const float* W0 = (const float*)d_in[1];
  const float* b0 = (const float*)d_in[2];
  const float* W1 = (const float*)d_in[3];
  const float* b1 = (const float*)d_in[4];
  const float* gW = (const float*)d_in[5];
  const float* ga = (const float*)d_in[6];
  const float* cW = (const float*)d_in[7];
  const float* cb = (const float*)d_in[8];
  const float* dW = (const float*)d_in[9];
  const float* db = (const float*)d_in[10];
  float* out = (float*)d_out;

  char* base = (char*)d_ws;
  char* w = base;
  auto alloc = [&](size_t bytes) { char* p = w; w += (bytes + 255) & ~(size_t)255; return p; };
  u16 *W0p[3], *W1p[3], *gWp[3], *h1p[3], *hp[3];
  for (int p = 0; p < 3; ++p) W0p[p] = (u16*)alloc((size_t)D_IN * H1_DIM * 2);
  for (int p = 0; p < 3; ++p) W1p[p] = (u16*)alloc((size_t)H1_DIM * H2_DIM * 2);
  for (int p = 0; p < 3; ++p) gWp[p] = (u16*)alloc((size_t)H2_DIM * G_DIM * 2);
  for (int p = 0; p < 3; ++p) h1p[p] = (u16*)alloc((size_t)N_PTS * H1_DIM * 2);
  for (int p = 0; p < 3; ++p) hp[p]  = (u16*)alloc((size_t)N_PTS * H2_DIM * 2);
  float* hF  = (float*)alloc((size_t)N_PTS * H2_DIM * 4);
  float* WhF = (float*)alloc((size_t)N_PTS * G_DIM * 4);
  float* sqv = (float*)alloc(N_PTS * 4);
  float* f1v = (float*)alloc(N_PTS * 4);
  float* f2v = (float*)alloc(N_PTS * 4);
  float* Wc  = (float*)alloc(64 * NOUT * 4);
  float* bc  = (float*)alloc(64 * 4);

  char* pbase = w;
  const size_t MN1 = (size_t)N_PTS * H1_DIM;
  const size_t MN2 = (size_t)N_PTS * H2_DIM;
  const size_t MN3 = (size_t)N_PTS * G_DIM;
  float* P1 = (float*)alloc(4 * MN1 * 4);
  float* P2 = (float*)alloc(4 * MN2 * 4);
  float* P3 = (float*)alloc(4 * MN3 * 4);
  float* Sb = (float*)pbase;

  size_t used_persist = (size_t)(pbase - base);
  size_t avail = (ws_size > used_persist) ? (ws_size - used_persist) / 4 : 0;
  int rowblk = 128;
  const int rcand[] = {6144, 3072, 1536, 768, 384, 256, 128};
  for (int c : rcand) { if ((size_t)c * N_PTS <= avail) { rowblk = c; break; } }

  const int TS = D_IN * H1_DIM + H1_DIM * H2_DIM + H2_DIM * G_DIM + 64 * NOUT;
  prep_all<<<(TS + 255) / 256, 256, 0, stream>>>(
      W0, W0p[0], W0p[1], W0p[2], W1, W1p[0], W1p[1], W1p[2], gW, gWp[0], gWp[1], gWp[2],
      cW, cb, dW, db, Wc, bc);

  mfma_gemm<64, true, true, false, false, false, false, false, false>
      <<<dim3(H1_DIM / 64, N_PTS / 64, 4), 256, 0, stream>>>(
      x, nullptr, nullptr, W0p[0], W0p[1], W0p[2], nullptr,
      P1, nullptr, nullptr, nullptr, D_IN, D_IN / 4, H1_DIM, MN1, 0);
  combine<4, true, true, false, true><<<(int)(MN1 / 1024), 256, 0, stream>>>(
      P1, b0, MN1, H1_DIM, nullptr, h1p[0], h1p[1], h1p[2]);

  mfma_gemm<64, false, true, false, false, false, false, false, false>
      <<<dim3(H2_DIM / 64, N_PTS / 64, 4), 256, 0, stream>>>(
      h1p[0], h1p[1], h1p[2], W1p[0], W1p[1], W1p[2], nullptr,
      P2, nullptr, nullptr, nullptr, H1_DIM, H1_DIM / 4, H2_DIM, MN2, 0);
  combine<4, true, true, true, true><<<(int)(MN2 / 1024), 256, 0, stream>>>(
      P2, b1, MN2, H2_DIM, hF, hp[0], hp[1], hp[2]);

  mfma_gemm<64, false, true, false, false, false, false, false, false>
      <<<dim3(G_DIM / 64, N_PTS / 64, 4), 256, 0, stream>>>(
      hp[0], hp[1], hp[2], gWp[0], gWp[1], gWp[2], nullptr,
      P3, nullptr, nullptr, nullptr, H2_DIM, H2_DIM / 4, G_DIM, MN3, 0);
  combine<4, false, false, true, false><<<(int)(MN3 / 1024), 256, 0, stream>>>(
      P3, nullptr, MN3, G_DIM, WhF, nullptr, nullptr, nullptr);

  row_stats<<<N_PTS / 256, 256, 0, stream>>>(hF, WhF, ga, sqv, f1v, f2v);

  if (rowblk == N_PTS) {
    mfma_gemm<128, false, false, false, false, false, false, true, true>
        <<<dim3(N_PTS / 64, N_PTS / 128, 1), 256, 0, stream>>>(
        hp[0], hp[1], hp[2], hp[0], hp[1], hp[2], sqv,
        Sb, nullptr, nullptr, nullptr, H2_DIM, H2_DIM, N_PTS, 0, 0);
    topk_att<<<N_PTS / 4, 256, 0, stream>>>((const unsigned*)Sb, f1v, f2v, WhF, Wc, bc, out, 0, N_PTS);
  } else {
    for (int b = 0; b < N_PTS / rowblk; ++b) {
      mfma_gemm<128, false, false, false, false, false, false, true, false>
          <<<dim3(N_PTS / 64, rowblk / 128, 1), 256, 0, stream>>>(
          hp[0] + (size_t)b * rowblk * H2_DIM, hp[1] + (size_t)b * rowblk * H2_DIM,
          hp[2] + (size_t)b * rowblk * H2_DIM, hp[0], hp[1], hp[2], sqv,
          Sb, nullptr, nullptr, nullptr, H2_DIM, H2_DIM, N_PTS, 0, b * rowblk);
      topk_att<<<rowblk / 4, 256, 0, stream>>>((const unsigned*)Sb, f1v, f2v, WhF, Wc, bc, out, b * rowblk, rowblk);
    }
  }
}

// Round 19
// 170.670 us; speedup vs baseline: 1.1711x; 1.0722x over previous
//
#include <hip/hip_runtime.h>
#include <float.h>

#define N_PTS 6144
#define D_IN  512
#define H1_DIM 256
#define H2_DIM 128
#define G_DIM  64
#define KNN    32
#define NOUT   22

typedef short s8v __attribute__((ext_vector_type(8)));   // 8 bf16 in 4 VGPR
typedef float f32x4 __attribute__((ext_vector_type(4)));
typedef unsigned u32x4 __attribute__((ext_vector_type(4)));
typedef unsigned short u16;
typedef unsigned short u16x4 __attribute__((ext_vector_type(4)));
typedef unsigned long long u64;

__device__ __forceinline__ u16 f2bf(float f) {
  unsigned u = __float_as_uint(f);
  u += 0x7FFFu + ((u >> 16) & 1u);          // RNE to bf16
  return (u16)(u >> 16);
}
__device__ __forceinline__ float bf2f(u16 s) {
  return __uint_as_float(((unsigned)s) << 16);
}
__device__ __forceinline__ void split3(float v, u16& a0, u16& a1, u16& a2) {
  a0 = f2bf(v);
  float r1 = v - bf2f(a0);
  a1 = f2bf(r1);
  a2 = f2bf(r1 - bf2f(a1));
}
__device__ __forceinline__ unsigned sortkey(float f) {
  unsigned ub = __float_as_uint(f);
  return (ub & 0x80000000u) ? ~ub : (ub | 0x80000000u);
}

// ---------------------------------------------------------------------------
// MFMA GEMM, 3-way bf16 split, 6-term schedule (fp32-equivalent).
// C[M,N] = A[M,K] * B^T[N,K].  BN=64, BK=32, 4 waves (2x2), wave tile (BM/2)x32.
// Staging via global_load_lds; XOR slot-swizzle via inverse-swizzled source.
// WKEY: epilogue writes u16 keys = top16(sortable-u32(sq[col]-2*val)); diag =
// 0xFFFF. Keys staged in LDS, written as coalesced 16B chunks.
// SYMM: super-tiles (x>>1)>=y only; strictly-upper tiles also write the
// mirrored u16 keys at (col,row) (transposed through LDS).
// ---------------------------------------------------------------------------
template<int BM, bool AF32, bool SPLITK, bool BIAS, bool RELU, bool WF32, bool WSPLIT, bool WKEY, bool SYMM>
__global__ __launch_bounds__(256, 4) void mfma_gemm(
    const void* __restrict__ A0any, const u16* __restrict__ A1_, const u16* __restrict__ A2_,
    const u16* __restrict__ B0_, const u16* __restrict__ B1_, const u16* __restrict__ B2_,
    const float* __restrict__ bias,
    float* __restrict__ Cf, u16* __restrict__ C0, u16* __restrict__ C1, u16* __restrict__ C2,
    int Ktot, int Ks, int ldC, size_t MN, int rowoff)
{
  if (SYMM) {
    if ((int)(blockIdx.x >> 1) < (int)blockIdx.y) return;   // block-uniform
  }
  const int MT = BM / 32, NT = 2;
  const int APL = BM * 32;              // u16 per A plane
  const int BBASE = 3 * APL;            // u16 offset of B region
  __shared__ u16 lds[(BM + 64) * 32 * 3];

  const int t = threadIdx.x;
  const int lane = t & 63, wave = t >> 6;
  const int wm = wave >> 1, wn = wave & 1;
  const int m0 = blockIdx.y * BM, n0 = blockIdx.x * 64;
  const int kz = blockIdx.z * Ks;

  f32x4 acc[MT][NT] = {};

  const int pA = BM / 16;               // 1KB chunks per A plane
  const int NC = 3 * pA + 12;           // total chunks (A + B planes)

  for (int k0 = 0; k0 < Ks; k0 += 32) {
    if (k0) __syncthreads();
    const int kb = kz + k0;
    if (AF32) {
      const float* A = (const float*)A0any;
      #pragma unroll
      for (int c0 = 0; c0 < BM * 4; c0 += 256) {
        int c = c0 + t;
        int row = c >> 2, slot = c & 3;
        const float* g = A + (size_t)(m0 + row) * Ktot + kb + slot * 8;
        f32x4 fa = *(const f32x4*)g;
        f32x4 fb = *(const f32x4*)(g + 4);
        int dst = row * 32 + ((slot ^ ((row >> 1) & 3)) << 3);
        s8v v0, v1, v2;
        #pragma unroll
        for (int e = 0; e < 4; ++e) {
          u16 a0, a1, a2; split3(fa[e], a0, a1, a2);
          v0[e] = (short)a0; v1[e] = (short)a1; v2[e] = (short)a2;
        }
        #pragma unroll
        for (int e = 0; e < 4; ++e) {
          u16 a0, a1, a2; split3(fb[e], a0, a1, a2);
          v0[4 + e] = (short)a0; v1[4 + e] = (short)a1; v2[4 + e] = (short)a2;
        }
        *(s8v*)(lds + dst) = v0;
        *(s8v*)(lds + APL + dst) = v1;
        *(s8v*)(lds + 2 * APL + dst) = v2;
      }
      for (int c = wave; c < 12; c += 4) {
        int p = c >> 2, lc = c & 3;
        int row = lc * 16 + (lane >> 2);
        int srcslot = (lane & 3) ^ ((row >> 1) & 3);
        const u16* src = (p == 0) ? B0_ : (p == 1) ? B1_ : B2_;
        const u16* g = src + (size_t)(n0 + row) * Ktot + kb + srcslot * 8;
        __builtin_amdgcn_global_load_lds(
            (const __attribute__((address_space(1))) unsigned*)g,
            (__attribute__((address_space(3))) unsigned*)(lds + BBASE + p * 2048 + lc * 512),
            16, 0, 0);
      }
    } else {
      for (int c = wave; c < NC; c += 4) {
        const u16* src; int dstoff; int row0; int lc;
        if (c < 3 * pA) {
          int p = c / pA; lc = c % pA;
          src = (p == 0) ? (const u16*)A0any : (p == 1) ? A1_ : A2_;
          dstoff = p * APL + lc * 512;
          row0 = m0;
        } else {
          int cb = c - 3 * pA;
          int p = cb >> 2; lc = cb & 3;
          src = (p == 0) ? B0_ : (p == 1) ? B1_ : B2_;
          dstoff = BBASE + p * 2048 + lc * 512;
          row0 = n0;
        }
        int row = lc * 16 + (lane >> 2);
        int srcslot = (lane & 3) ^ ((row >> 1) & 3);
        const u16* g = src + (size_t)(row0 + row) * Ktot + kb + srcslot * 8;
        __builtin_amdgcn_global_load_lds(
            (const __attribute__((address_space(1))) unsigned*)g,
            (__attribute__((address_space(3))) unsigned*)(lds + dstoff),
            16, 0, 0);
      }
    }
    __syncthreads();

    s8v af[3][MT], bf[3][NT];
    #pragma unroll
    for (int mt = 0; mt < MT; ++mt) {
      int r = wm * (BM / 2) + mt * 16 + (lane & 15);
      int off = r * 32 + (((lane >> 4) ^ ((r >> 1) & 3)) << 3);
      #pragma unroll
      for (int p = 0; p < 3; ++p) af[p][mt] = *(const s8v*)(lds + p * APL + off);
    }
    #pragma unroll
    for (int nt = 0; nt < NT; ++nt) {
      int r = wn * 32 + nt * 16 + (lane & 15);
      int off = r * 32 + (((lane >> 4) ^ ((r >> 1) & 3)) << 3);
      #pragma unroll
      for (int p = 0; p < 3; ++p) bf[p][nt] = *(const s8v*)(lds + BBASE + p * 2048 + off);
    }
    #pragma unroll
    for (int mt = 0; mt < MT; ++mt)
      #pragma unroll
      for (int nt = 0; nt < NT; ++nt) {
        f32x4 a = acc[mt][nt];
        a = __builtin_amdgcn_mfma_f32_16x16x32_bf16(af[0][mt], bf[0][nt], a, 0, 0, 0);
        a = __builtin_amdgcn_mfma_f32_16x16x32_bf16(af[0][mt], bf[1][nt], a, 0, 0, 0);
        a = __builtin_amdgcn_mfma_f32_16x16x32_bf16(af[1][mt], bf[0][nt], a, 0, 0, 0);
        a = __builtin_amdgcn_mfma_f32_16x16x32_bf16(af[1][mt], bf[1][nt], a, 0, 0, 0);
        a = __builtin_amdgcn_mfma_f32_16x16x32_bf16(af[0][mt], bf[2][nt], a, 0, 0, 0);
        a = __builtin_amdgcn_mfma_f32_16x16x32_bf16(af[2][mt], bf[0][nt], a, 0, 0, 0);
        acc[mt][nt] = a;
      }
  }

  if (WKEY) {
    const bool mirror = SYMM && ((int)(blockIdx.x >> 1) > (int)blockIdx.y);
    u16 mk[MT][NT][4];
    __syncthreads();                    // operand reads done; reuse lds
    u16* stD = lds;                     // [BM][72]
    #pragma unroll
    for (int mt = 0; mt < MT; ++mt) {
      #pragma unroll
      for (int nt = 0; nt < NT; ++nt) {
        int cl = wn * 32 + nt * 16 + (lane & 15);
        float sqc = bias[n0 + cl];
        #pragma unroll
        for (int v = 0; v < 4; ++v) {
          int rl = wm * (BM / 2) + mt * 16 + (lane >> 4) * 4 + v;
          float val = acc[mt][nt][v];
          float f = fmaf(-2.f, val, sqc);
          unsigned uu = sortkey(f);
          if (rowoff + m0 + rl == n0 + cl) uu = 0xFFFFFFFFu;
          stD[rl * 72 + cl] = (u16)(uu >> 16);
          if (mirror) {
            float fm = fmaf(-2.f, val, bias[m0 + rl]);
            mk[mt][nt][v] = (u16)(sortkey(fm) >> 16);
          }
        }
      }
    }
    __syncthreads();
    u16* Cu = (u16*)Cf;
    for (int e = t; e < BM * 8; e += 256) {
      int row = e >> 3, ch = e & 7;
      u32x4 vv = *(const u32x4*)(stD + row * 72 + ch * 8);
      *(u32x4*)(Cu + (size_t)(m0 + row) * ldC + n0 + ch * 8) = vv;
    }
    if (mirror) {
      __syncthreads();
      u16* stM = lds;                   // [64][136]
      #pragma unroll
      for (int mt = 0; mt < MT; ++mt) {
        #pragma unroll
        for (int nt = 0; nt < NT; ++nt) {
          int cl = wn * 32 + nt * 16 + (lane & 15);
          #pragma unroll
          for (int v = 0; v < 4; ++v) {
            int rl = wm * (BM / 2) + mt * 16 + (lane >> 4) * 4 + v;
            stM[cl * 136 + rl] = mk[mt][nt][v];
          }
        }
      }
      __syncthreads();
      for (int e = t; e < 64 * 16; e += 256) {
        int row = e >> 4, ch = e & 15;
        u32x4 vv = *(const u32x4*)(stM + row * 136 + ch * 8);
        *(u32x4*)(Cu + (size_t)(n0 + row) * ldC + m0 + ch * 8) = vv;
      }
    }
    return;
  }

  #pragma unroll
  for (int mt = 0; mt < MT; ++mt) {
    #pragma unroll
    for (int nt = 0; nt < NT; ++nt) {
      int col = n0 + wn * 32 + nt * 16 + (lane & 15);
      float bv = (BIAS && !SPLITK) ? bias[col] : 0.f;
      #pragma unroll
      for (int v = 0; v < 4; ++v) {
        int row = m0 + wm * (BM / 2) + mt * 16 + (lane >> 4) * 4 + v;
        float val = acc[mt][nt][v] + bv;
        size_t o = (size_t)row * ldC + col;
        if (SPLITK) {
          Cf[(size_t)blockIdx.z * MN + o] = val;
        } else {
          if (RELU) val = fmaxf(val, 0.f);
          if (WF32) Cf[o] = val;
          if (WSPLIT) {
            u16 a0, a1, a2; split3(val, a0, a1, a2);
            C0[o] = a0; C1[o] = a1; C2[o] = a2;
          }
        }
      }
    }
  }
}

template<int S, bool BIAS, bool RELU, bool WF32, bool WSPLIT>
__global__ void combine(const float* __restrict__ P, const float* __restrict__ bias,
                        size_t MN, int Ncols,
                        float* __restrict__ Cf, u16* __restrict__ C0,
                        u16* __restrict__ C1, u16* __restrict__ C2)
{
  size_t idx = ((size_t)blockIdx.x * 256 + threadIdx.x) * 4;
  if (idx >= MN) return;
  f32x4 s = *(const f32x4*)(P + idx);
  #pragma unroll
  for (int z = 1; z < S; ++z) s += *(const f32x4*)(P + (size_t)z * MN + idx);
  int n = (int)(idx % (size_t)Ncols);
  #pragma unroll
  for (int e = 0; e < 4; ++e) {
    float v = s[e] + (BIAS ? bias[n + e] : 0.f);
    if (RELU) v = fmaxf(v, 0.f);
    if (WF32) Cf[idx + e] = v;
    if (WSPLIT) {
      u16 a0, a1, a2; split3(v, a0, a1, a2);
      C0[idx + e] = a0; C1[idx + e] = a1; C2[idx + e] = a2;
    }
  }
}

// weight transposes+splits AND head collapse in one launch
__global__ void prep_all(const float* __restrict__ W0, u16* __restrict__ a0,
                         u16* __restrict__ a1, u16* __restrict__ a2,
                         const float* __restrict__ W1, u16* __restrict__ b0,
                         u16* __restrict__ b1, u16* __restrict__ b2,
                         const float* __restrict__ gW, u16* __restrict__ c0,
                         u16* __restrict__ c1, u16* __restrict__ c2,
                         const float* __restrict__ cW, const float* __restrict__ cb,
                         const float* __restrict__ dW, const float* __restrict__ db,
                         float* __restrict__ Wc, float* __restrict__ bc)
{
  int id = blockIdx.x * 256 + threadIdx.x;
  const int S0 = D_IN * H1_DIM, S1 = H1_DIM * H2_DIM, S2 = H2_DIM * G_DIM;
  const int SW = S0 + S1 + S2;
  if (id < SW) {
    const float* W; u16 *p0, *p1, *p2; int K, N;
    if (id < S0)           { W = W0; p0 = a0; p1 = a1; p2 = a2; K = D_IN;   N = H1_DIM; }
    else if (id < S0 + S1) { id -= S0; W = W1; p0 = b0; p1 = b1; p2 = b2; K = H1_DIM; N = H2_DIM; }
    else                   { id -= S0 + S1; W = gW; p0 = c0; p1 = c1; p2 = c2; K = H2_DIM; N = G_DIM; }
    int k = id / N, n = id % N;
    u16 x0, x1, x2;
    split3(W[id], x0, x1, x2);
    size_t o = (size_t)n * K + k;
    p0[o] = x0; p1[o] = x1; p2[o] = x2;
    return;
  }
  id -= SW;
  if (id < 64 * NOUT) {
    int g = id / NOUT, c = id % NOUT;
    float s = 0.f;
    if (c < 16) {
      for (int r = 0; r < 8; ++r) s += cW[(r * 64 + g) * 16 + c];
    } else {
      int k = (c - 16) >> 1, o = (c - 16) & 1;
      for (int r = 0; r < 8; ++r) s += dW[k * 1024 + (r * 64 + g) * 2 + o];
    }
    Wc[id] = s;
    if (g == 0) bc[c] = (c < 16) ? cb[c] : db[c - 16];
  }
}

__global__ void row_stats(const float* __restrict__ h, const float* __restrict__ Wh,
                          const float* __restrict__ ga, float* __restrict__ sq,
                          float* __restrict__ f1, float* __restrict__ f2)
{
  int i = blockIdx.x * 256 + threadIdx.x;
  const float* hr = h + (size_t)i * H2_DIM;
  float s = 0.f;
  for (int k = 0; k < H2_DIM; ++k) { float v = hr[k]; s = fmaf(v, v, s); }
  sq[i] = s;
  const float* wr = Wh + (size_t)i * G_DIM;
  float a = 0.f, b = 0.f;
  for (int g = 0; g < G_DIM; ++g) {
    float w = wr[g];
    a = fmaf(w, ga[g], a);
    b = fmaf(w, ga[G_DIM + g], b);
  }
  f1[i] = a; f2[i] = b;
}

// ---------------------------------------------------------------------------
// u16-key topk, one wave per row (reversed row order for L3 hits).
// (1) quad-min tournament on u16 keys; quaternary bisection -> Q = exact
//     32nd-smallest quad-min; ballot-collect quads <= Q (cap 96) as
//     u32 (k16<<13|j), ascending j.
// (2) second bisection over the <=384 collected keys (6/lane regs) ->
//     T = exact 32nd-smallest u16 key.
// (3) keys < T: unconditional winners (set semantics). keys == T: tie
//     bucket (cap 128, ascending j); resolved by recomputing exact fp32
//     keys (sq[j] - 2*h_i.h_j) and register-128-bitonic on (key<<13|j).
// Then wave-local softmax + PV + head.
// ---------------------------------------------------------------------------
__global__ __launch_bounds__(256) void topk_att(const u16* __restrict__ Sb,
    const float* __restrict__ f1, const float* __restrict__ f2,
    const float* __restrict__ Wh, const float* __restrict__ Wc, const float* __restrict__ bc,
    const float* __restrict__ sq, const float* __restrict__ hF,
    float* __restrict__ out, int m0, int nrows)
{
  const int t = threadIdx.x;
  const int lane = t & 63, wv = t >> 6;
  const int row4 = (nrows - 4 - blockIdx.x * 4) + wv;   // reversed mapping
  const int i = m0 + row4;
  const u16* Srow = Sb + (size_t)row4 * N_PTS;

  __shared__ float WcL[64 * NOUT];
  __shared__ unsigned candS[4][384];
  __shared__ u16 tieS[4][128];
  __shared__ float hiL[4][128];
  __shared__ int neighS[4][33];
  __shared__ float attS[4][33];
  __shared__ float hpfS[4][64];

  for (int idx = t; idx < 64 * NOUT; idx += 256) WcL[idx] = Wc[idx];
  __syncthreads();                       // only block barrier

  // h_i into per-wave LDS
  hiL[wv][lane]      = hF[(size_t)i * H2_DIM + lane];
  hiL[wv][64 + lane] = hF[(size_t)i * H2_DIM + 64 + lane];

  // ---- stream row (u16 keys), keep quad-mins: j = (c<<8)+(lane<<2)+e ----
  unsigned q[24];
  #pragma unroll
  for (int c = 0; c < 24; ++c) {
    u16x4 v = *(const u16x4*)(Srow + (c << 8) + (lane << 2));
    unsigned a = v[0] < v[1] ? (unsigned)v[0] : (unsigned)v[1];
    unsigned b = v[2] < v[3] ? (unsigned)v[2] : (unsigned)v[3];
    q[c] = a < b ? a : b;
  }

  unsigned lmin = q[0];
  #pragma unroll
  for (int c = 1; c < 24; ++c) lmin = q[c] < lmin ? q[c] : lmin;

  unsigned mnl = lmin, mxl = lmin;
  #pragma unroll
  for (int off = 32; off > 0; off >>= 1) {
    unsigned o1 = __shfl_xor(mnl, off); mnl = o1 < mnl ? o1 : mnl;
    unsigned o2 = __shfl_xor(mxl, off); mxl = o2 > mxl ? o2 : mxl;
  }

  // bisection 1: Q = exact 32nd-smallest quad-min (16-bit domain)
  long long lo = (long long)mnl - 1, hi = (long long)mxl;
  while (hi - lo > 1) {
    long long span = hi - lo;
    unsigned m1 = (unsigned)(lo + (span >> 2));
    unsigned m2 = (unsigned)(lo + (span >> 1));
    unsigned m3 = (unsigned)(hi - (span >> 2));
    int c1 = 0, c2 = 0, c3 = 0;
    #pragma unroll
    for (int c = 0; c < 24; ++c) {
      c1 += (q[c] <= m1);
      c2 += (q[c] <= m2);
      c3 += (q[c] <= m3);
    }
    #pragma unroll
    for (int off = 32; off > 0; off >>= 1) {
      c1 += __shfl_xor(c1, off);
      c2 += __shfl_xor(c2, off);
      c3 += __shfl_xor(c3, off);
    }
    if (c1 >= KNN)       { hi = m1; }
    else if (c2 >= KNN)  { lo = m1; hi = m2; }
    else if (c3 >= KNN)  { lo = m2; hi = m3; }
    else                 { lo = m3; }
  }
  const unsigned Q = (unsigned)hi;

  // collect quads with min <= Q (cap 96), ascending j
  #pragma unroll
  for (int s = 0; s < 6; ++s) candS[wv][lane + s * 64] = 0xFFFFFFFFu;
  const u64 below = (lane == 0) ? 0ull : (~0ull >> (64 - lane));
  int qcnt = 0;
  #pragma unroll
  for (int c = 0; c < 24; ++c) {
    bool act = (q[c] <= Q);
    u64 mask = __ballot(act);
    if (act) {
      int pos = qcnt + (int)__popcll(mask & below);
      if (pos < 96) {
        u16x4 v = *(const u16x4*)(Srow + (c << 8) + (lane << 2));
        #pragma unroll
        for (int e = 0; e < 4; ++e) {
          int j = (c << 8) + (lane << 2) + e;
          candS[wv][pos * 4 + e] = ((unsigned)v[e] << 13) | (unsigned)j;
        }
      }
    }
    qcnt += (int)__popcll(mask);
  }

  // pull collected keys into regs: 6/lane
  unsigned ck[6];
  #pragma unroll
  for (int s = 0; s < 6; ++s) ck[s] = candS[wv][lane + s * 64];

  // bisection 2: T = exact 32nd-smallest collected u16 key
  lo = -1; hi = 0x10000;
  while (hi - lo > 1) {
    long long span = hi - lo;
    unsigned m1 = (unsigned)(lo + (span >> 2));
    unsigned m2 = (unsigned)(lo + (span >> 1));
    unsigned m3 = (unsigned)(hi - (span >> 2));
    int c1 = 0, c2 = 0, c3 = 0;
    #pragma unroll
    for (int s = 0; s < 6; ++s) {
      unsigned k = ck[s] >> 13;
      c1 += (k <= m1);
      c2 += (k <= m2);
      c3 += (k <= m3);
    }
    #pragma unroll
    for (int off = 32; off > 0; off >>= 1) {
      c1 += __shfl_xor(c1, off);
      c2 += __shfl_xor(c2, off);
      c3 += __shfl_xor(c3, off);
    }
    if (c1 >= KNN)       { hi = m1; }
    else if (c2 >= KNN)  { lo = m1; hi = m2; }
    else if (c3 >= KNN)  { lo = m2; hi = m3; }
    else                 { lo = m3; }
  }
  const unsigned T = (unsigned)hi;

  // classify: strict winners (< T) -> neighS; ties (== T) -> tieS
  int sA = 0, sB = 0;
  #pragma unroll
  for (int s = 0; s < 6; ++s) {
    unsigned k = ck[s] >> 13;
    bool strict = (k < T);
    u64 ms = __ballot(strict);
    if (strict) {
      int pos = sA + (int)__popcll(ms & below);
      if (pos < 32) neighS[wv][pos] = (int)(ck[s] & 0x1FFFu);
    }
    sA += (int)__popcll(ms);
    bool tie = (k == T);
    u64 mt2 = __ballot(tie);
    if (tie) {
      int pos = sB + (int)__popcll(mt2 & below);
      if (pos < 128) tieS[wv][pos] = (u16)(ck[s] & 0x1FFFu);
    }
    sB += (int)__popcll(mt2);
  }
  if (sB > 128) sB = 128;
  const int need = KNN - sA;

  // refine ties: recompute exact fp32 keys, rank = (sortkey<<13)|j
  u64 r0 = ~0ull, r1 = ~0ull;
  const float* hi0 = &hiL[wv][0];
  #pragma unroll
  for (int half = 0; half < 2; ++half) {
    int e = lane + half * 64;
    if (e < sB) {
      int j = tieS[wv][e];
      const float* hj = hF + (size_t)j * H2_DIM;
      float dot = 0.f;
      for (int d = 0; d < H2_DIM; d += 4) {
        f32x4 a = *(const f32x4*)(hi0 + d);
        f32x4 b = *(const f32x4*)(hj + d);
        dot = fmaf(a[0], b[0], fmaf(a[1], b[1], fmaf(a[2], b[2], fmaf(a[3], b[3], dot))));
      }
      float f = fmaf(-2.f, dot, sq[j]);
      u64 rk = ((u64)sortkey(f) << 13) | (unsigned)j;
      if (half == 0) r0 = rk; else r1 = rk;
    }
  }

  // register bitonic sort of 128 tie ranks, 2 elems/lane (elements 2*lane, 2*lane+1)
  {
    // remap: element e0=2*lane holds r at index... use standard layout:
    // place r0 at e0, r1 at e1 by exchanging via shfl when lane>=32? Simpler:
    // r0 corresponds to e=lane, r1 to e=lane+64 — convert to (2*lane, 2*lane+1)
    // layout via LDS bounce.
    candS[wv][lane] = (unsigned)(r0 >> 32); candS[wv][64 + lane] = (unsigned)r0;
    candS[wv][128 + lane] = (unsigned)(r1 >> 32); candS[wv][192 + lane] = (unsigned)r1;
    u64 v0 = ((u64)candS[wv][(2 * lane) >= 64 ? 128 + (2 * lane - 64) : 2 * lane] << 32)
           | candS[wv][(2 * lane) >= 64 ? 192 + (2 * lane - 64) : 64 + 2 * lane];
    u64 v1 = ((u64)candS[wv][(2 * lane + 1) >= 64 ? 128 + (2 * lane + 1 - 64) : 2 * lane + 1] << 32)
           | candS[wv][(2 * lane + 1) >= 64 ? 192 + (2 * lane + 1 - 64) : 64 + 2 * lane + 1];
    const int e0 = 2 * lane, e1 = e0 + 1;
    for (int k = 2; k <= 128; k <<= 1) {
      for (int j = k >> 1; j >= 2; j >>= 1) {
        int half = j >> 1;
        u64 o0 = __shfl_xor(v0, half);
        u64 o1 = __shfl_xor(v1, half);
        bool up0 = ((e0 & k) == 0) == ((e0 & j) == 0);
        bool up1 = ((e1 & k) == 0) == ((e1 & j) == 0);
        v0 = up0 ? (v0 < o0 ? v0 : o0) : (v0 > o0 ? v0 : o0);
        v1 = up1 ? (v1 < o1 ? v1 : o1) : (v1 > o1 ? v1 : o1);
      }
      bool asc = ((e0 & k) == 0);
      u64 a = v0 < v1 ? v0 : v1, b = v0 < v1 ? v1 : v0;
      v0 = asc ? a : b;
      v1 = asc ? b : a;
    }
    if (e0 < need) neighS[wv][sA + e0] = (int)(v0 & 0x1FFFu);
    if (e1 < need) neighS[wv][sA + e1] = (int)(v1 & 0x1FFFu);
  }
  if (lane == 0) neighS[wv][32] = i;

  // ---- wave-local masked softmax over 33 entries ----
  {
    float e = -FLT_MAX;
    if (lane < 33) {
      float raw = f1[i] + f2[neighS[wv][lane]];
      e = raw > 0.f ? raw : 0.2f * raw;
    }
    float mx = e;
    #pragma unroll
    for (int off = 32; off > 0; off >>= 1) mx = fmaxf(mx, __shfl_xor(mx, off));
    float ex = (lane < 33) ? expf(e - mx) : 0.f;
    float sm = ex;
    #pragma unroll
    for (int off = 32; off > 0; off >>= 1) sm += __shfl_xor(sm, off);
    if (lane < 33) attS[wv][lane] = ex / sm;
  }

  // ---- PV: lane = g ----
  {
    float s = 0.f;
    for (int m = 0; m < 33; ++m)
      s = fmaf(attS[wv][m], Wh[(size_t)neighS[wv][m] * G_DIM + lane], s);
    hpfS[wv][lane] = s > 0.f ? s : expm1f(s);
  }

  // ---- head: 64 -> 22 ----
  if (lane < NOUT) {
    float o = bc[lane];
    for (int g = 0; g < 64; ++g) o = fmaf(hpfS[wv][g], WcL[g * NOUT + lane], o);
    out[(size_t)i * NOUT + lane] = o;
  }
}

extern "C" void kernel_launch(void* const* d_in, const int* in_sizes, int n_in,
                              void* d_out, int out_size, void* d_ws, size_t ws_size,
                              hipStream_t stream)
{
  const float* x  = (const float*)d_in[0];
  const float* W0 = (const float*)d_in[1];
  const float* b0 = (const float*)d_in[2];
  const float* W1 = (const float*)d_in[3];
  const float* b1 = (const float*)d_in[4];
  const float* gW = (const float*)d_in[5];
  const float* ga = (const float*)d_in[6];
  const float* cW = (const float*)d_in[7];
  const float* cb = (const float*)d_in[8];
  const float* dW = (const float*)d_in[9];
  const float* db = (const float*)d_in[10];
  float* out = (float*)d_out;

  char* base = (char*)d_ws;
  char* w = base;
  auto alloc = [&](size_t bytes) { char* p = w; w += (bytes + 255) & ~(size_t)255; return p; };
  u16 *W0p[3], *W1p[3], *gWp[3], *h1p[3], *hp[3];
  for (int p = 0; p < 3; ++p) W0p[p] = (u16*)alloc((size_t)D_IN * H1_DIM * 2);
  for (int p = 0; p < 3; ++p) W1p[p] = (u16*)alloc((size_t)H1_DIM * H2_DIM * 2);
  for (int p = 0; p < 3; ++p) gWp[p] = (u16*)alloc((size_t)H2_DIM * G_DIM * 2);
  for (int p = 0; p < 3; ++p) h1p[p] = (u16*)alloc((size_t)N_PTS * H1_DIM * 2);
  for (int p = 0; p < 3; ++p) hp[p]  = (u16*)alloc((size_t)N_PTS * H2_DIM * 2);
  float* hF  = (float*)alloc((size_t)N_PTS * H2_DIM * 4);
  float* WhF = (float*)alloc((size_t)N_PTS * G_DIM * 4);
  float* sqv = (float*)alloc(N_PTS * 4);
  float* f1v = (float*)alloc(N_PTS * 4);
  float* f2v = (float*)alloc(N_PTS * 4);
  float* Wc  = (float*)alloc(64 * NOUT * 4);
  float* bc  = (float*)alloc(64 * 4);

  char* pbase = w;
  const size_t MN1 = (size_t)N_PTS * H1_DIM;
  const size_t MN2 = (size_t)N_PTS * H2_DIM;
  const size_t MN3 = (size_t)N_PTS * G_DIM;
  float* P1 = (float*)alloc(4 * MN1 * 4);
  float* P2 = (float*)alloc(4 * MN2 * 4);
  float* P3 = (float*)alloc(4 * MN3 * 4);
  u16* Sb = (u16*)pbase;

  size_t used_persist = (size_t)(pbase - base);
  size_t avail16 = (ws_size > used_persist) ? (ws_size - used_persist) / 2 : 0;
  int rowblk = 128;
  const int rcand[] = {6144, 3072, 1536, 768, 384, 256, 128};
  for (int c : rcand) { if ((size_t)c * N_PTS <= avail16) { rowblk = c; break; } }

  const int TS = D_IN * H1_DIM + H1_DIM * H2_DIM + H2_DIM * G_DIM + 64 * NOUT;
  prep_all<<<(TS + 255) / 256, 256, 0, stream>>>(
      W0, W0p[0], W0p[1], W0p[2], W1, W1p[0], W1p[1], W1p[2], gW, gWp[0], gWp[1], gWp[2],
      cW, cb, dW, db, Wc, bc);

  mfma_gemm<64, true, true, false, false, false, false, false, false>
      <<<dim3(H1_DIM / 64, N_PTS / 64, 4), 256, 0, stream>>>(
      x, nullptr, nullptr, W0p[0], W0p[1], W0p[2], nullptr,
      P1, nullptr, nullptr, nullptr, D_IN, D_IN / 4, H1_DIM, MN1, 0);
  combine<4, true, true, false, true><<<(int)(MN1 / 1024), 256, 0, stream>>>(
      P1, b0, MN1, H1_DIM, nullptr, h1p[0], h1p[1], h1p[2]);

  mfma_gemm<64, false, true, false, false, false, false, false, false>
      <<<dim3(H2_DIM / 64, N_PTS / 64, 4), 256, 0, stream>>>(
      h1p[0], h1p[1], h1p[2], W1p[0], W1p[1], W1p[2], nullptr,
      P2, nullptr, nullptr, nullptr, H1_DIM, H1_DIM / 4, H2_DIM, MN2, 0);
  combine<4, true, true, true, true><<<(int)(MN2 / 1024), 256, 0, stream>>>(
      P2, b1, MN2, H2_DIM, hF, hp[0], hp[1], hp[2]);

  mfma_gemm<64, false, true, false, false, false, false, false, false>
      <<<dim3(G_DIM / 64, N_PTS / 64, 4), 256, 0, stream>>>(
      hp[0], hp[1], hp[2], gWp[0], gWp[1], gWp[2], nullptr,
      P3, nullptr, nullptr, nullptr, H2_DIM, H2_DIM / 4, G_DIM, MN3, 0);
  combine<4, false, false, true, false><<<(int)(MN3 / 1024), 256, 0, stream>>>(
      P3, nullptr, MN3, G_DIM, WhF, nullptr, nullptr, nullptr);

  row_stats<<<N_PTS / 256, 256, 0, stream>>>(hF, WhF, ga, sqv, f1v, f2v);

  if (rowblk == N_PTS) {
    mfma_gemm<128, false, false, false, false, false, false, true, true>
        <<<dim3(N_PTS / 64, N_PTS / 128, 1), 256, 0, stream>>>(
        hp[0], hp[1], hp[2], hp[0], hp[1], hp[2], sqv,
        (float*)Sb, nullptr, nullptr, nullptr, H2_DIM, H2_DIM, N_PTS, 0, 0);
    topk_att<<<N_PTS / 4, 256, 0, stream>>>(Sb, f1v, f2v, WhF, Wc, bc, sqv, hF, out, 0, N_PTS);
  } else {
    for (int b = 0; b < N_PTS / rowblk; ++b) {
      mfma_gemm<128, false, false, false, false, false, false, true, false>
          <<<dim3(N_PTS / 64, rowblk / 128, 1), 256, 0, stream>>>(
          hp[0] + (size_t)b * rowblk * H2_DIM, hp[1] + (size_t)b * rowblk * H2_DIM,
          hp[2] + (size_t)b * rowblk * H2_DIM, hp[0], hp[1], hp[2], sqv,
          (float*)Sb, nullptr, nullptr, nullptr, H2_DIM, H2_DIM, N_PTS, 0, b * rowblk);
      topk_att<<<rowblk / 4, 256, 0, stream>>>(Sb, f1v, f2v, WhF, Wc, bc, sqv, hF, out, b * rowblk, rowblk);
    }
  }
}

// Round 20
// 168.892 us; speedup vs baseline: 1.1834x; 1.0105x over previous
//
#include <hip/hip_runtime.h>
#include <float.h>

#define N_PTS 6144
#define D_IN  512
#define H1_DIM 256
#define H2_DIM 128
#define G_DIM  64
#define KNN    32
#define NOUT   22

typedef short s8v __attribute__((ext_vector_type(8)));   // 8 bf16 in 4 VGPR
typedef float f32x4 __attribute__((ext_vector_type(4)));
typedef unsigned u32x4 __attribute__((ext_vector_type(4)));
typedef unsigned short u16;
typedef unsigned short u16x4 __attribute__((ext_vector_type(4)));
typedef unsigned long long u64;

__device__ __forceinline__ u16 f2bf(float f) {
  unsigned u = __float_as_uint(f);
  u += 0x7FFFu + ((u >> 16) & 1u);          // RNE to bf16
  return (u16)(u >> 16);
}
__device__ __forceinline__ float bf2f(u16 s) {
  return __uint_as_float(((unsigned)s) << 16);
}
__device__ __forceinline__ void split3(float v, u16& a0, u16& a1, u16& a2) {
  a0 = f2bf(v);
  float r1 = v - bf2f(a0);
  a1 = f2bf(r1);
  a2 = f2bf(r1 - bf2f(a1));
}
__device__ __forceinline__ unsigned sortkey(float f) {
  unsigned ub = __float_as_uint(f);
  return (ub & 0x80000000u) ? ~ub : (ub | 0x80000000u);
}

// ---------------------------------------------------------------------------
// Generic MFMA GEMM (MLP path), 3-way bf16 split, 6-term schedule.
// C[M,N] = A[M,K] * B^T[N,K]. BN=64, BK=32, 4 waves (2x2), wave tile (BM/2)x32.
// ---------------------------------------------------------------------------
template<int BM, bool AF32, bool SPLITK, bool BIAS, bool RELU, bool WF32, bool WSPLIT>
__global__ __launch_bounds__(256, 4) void mfma_gemm(
    const void* __restrict__ A0any, const u16* __restrict__ A1_, const u16* __restrict__ A2_,
    const u16* __restrict__ B0_, const u16* __restrict__ B1_, const u16* __restrict__ B2_,
    const float* __restrict__ bias,
    float* __restrict__ Cf, u16* __restrict__ C0, u16* __restrict__ C1, u16* __restrict__ C2,
    int Ktot, int Ks, int ldC, size_t MN)
{
  const int MT = BM / 32, NT = 2;
  const int APL = BM * 32;
  const int BBASE = 3 * APL;
  __shared__ u16 lds[(BM + 64) * 32 * 3];

  const int t = threadIdx.x;
  const int lane = t & 63, wave = t >> 6;
  const int wm = wave >> 1, wn = wave & 1;
  const int m0 = blockIdx.y * BM, n0 = blockIdx.x * 64;
  const int kz = blockIdx.z * Ks;

  f32x4 acc[MT][NT] = {};

  const int pA = BM / 16;
  const int NC = 3 * pA + 12;

  for (int k0 = 0; k0 < Ks; k0 += 32) {
    if (k0) __syncthreads();
    const int kb = kz + k0;
    if (AF32) {
      const float* A = (const float*)A0any;
      #pragma unroll
      for (int c0 = 0; c0 < BM * 4; c0 += 256) {
        int c = c0 + t;
        int row = c >> 2, slot = c & 3;
        const float* g = A + (size_t)(m0 + row) * Ktot + kb + slot * 8;
        f32x4 fa = *(const f32x4*)g;
        f32x4 fb = *(const f32x4*)(g + 4);
        int dst = row * 32 + ((slot ^ ((row >> 1) & 3)) << 3);
        s8v v0, v1, v2;
        #pragma unroll
        for (int e = 0; e < 4; ++e) {
          u16 a0, a1, a2; split3(fa[e], a0, a1, a2);
          v0[e] = (short)a0; v1[e] = (short)a1; v2[e] = (short)a2;
        }
        #pragma unroll
        for (int e = 0; e < 4; ++e) {
          u16 a0, a1, a2; split3(fb[e], a0, a1, a2);
          v0[4 + e] = (short)a0; v1[4 + e] = (short)a1; v2[4 + e] = (short)a2;
        }
        *(s8v*)(lds + dst) = v0;
        *(s8v*)(lds + APL + dst) = v1;
        *(s8v*)(lds + 2 * APL + dst) = v2;
      }
      for (int c = wave; c < 12; c += 4) {
        int p = c >> 2, lc = c & 3;
        int row = lc * 16 + (lane >> 2);
        int srcslot = (lane & 3) ^ ((row >> 1) & 3);
        const u16* src = (p == 0) ? B0_ : (p == 1) ? B1_ : B2_;
        const u16* g = src + (size_t)(n0 + row) * Ktot + kb + srcslot * 8;
        __builtin_amdgcn_global_load_lds(
            (const __attribute__((address_space(1))) unsigned*)g,
            (__attribute__((address_space(3))) unsigned*)(lds + BBASE + p * 2048 + lc * 512),
            16, 0, 0);
      }
    } else {
      for (int c = wave; c < NC; c += 4) {
        const u16* src; int dstoff; int row0; int lc;
        if (c < 3 * pA) {
          int p = c / pA; lc = c % pA;
          src = (p == 0) ? (const u16*)A0any : (p == 1) ? A1_ : A2_;
          dstoff = p * APL + lc * 512;
          row0 = m0;
        } else {
          int cb = c - 3 * pA;
          int p = cb >> 2; lc = cb & 3;
          src = (p == 0) ? B0_ : (p == 1) ? B1_ : B2_;
          dstoff = BBASE + p * 2048 + lc * 512;
          row0 = n0;
        }
        int row = lc * 16 + (lane >> 2);
        int srcslot = (lane & 3) ^ ((row >> 1) & 3);
        const u16* g = src + (size_t)(row0 + row) * Ktot + kb + srcslot * 8;
        __builtin_amdgcn_global_load_lds(
            (const __attribute__((address_space(1))) unsigned*)g,
            (__attribute__((address_space(3))) unsigned*)(lds + dstoff),
            16, 0, 0);
      }
    }
    __syncthreads();

    s8v af[3][MT], bf[3][NT];
    #pragma unroll
    for (int mt = 0; mt < MT; ++mt) {
      int r = wm * (BM / 2) + mt * 16 + (lane & 15);
      int off = r * 32 + (((lane >> 4) ^ ((r >> 1) & 3)) << 3);
      #pragma unroll
      for (int p = 0; p < 3; ++p) af[p][mt] = *(const s8v*)(lds + p * APL + off);
    }
    #pragma unroll
    for (int nt = 0; nt < NT; ++nt) {
      int r = wn * 32 + nt * 16 + (lane & 15);
      int off = r * 32 + (((lane >> 4) ^ ((r >> 1) & 3)) << 3);
      #pragma unroll
      for (int p = 0; p < 3; ++p) bf[p][nt] = *(const s8v*)(lds + BBASE + p * 2048 + off);
    }
    #pragma unroll
    for (int mt = 0; mt < MT; ++mt)
      #pragma unroll
      for (int nt = 0; nt < NT; ++nt) {
        f32x4 a = acc[mt][nt];
        a = __builtin_amdgcn_mfma_f32_16x16x32_bf16(af[0][mt], bf[0][nt], a, 0, 0, 0);
        a = __builtin_amdgcn_mfma_f32_16x16x32_bf16(af[0][mt], bf[1][nt], a, 0, 0, 0);
        a = __builtin_amdgcn_mfma_f32_16x16x32_bf16(af[1][mt], bf[0][nt], a, 0, 0, 0);
        a = __builtin_amdgcn_mfma_f32_16x16x32_bf16(af[1][mt], bf[1][nt], a, 0, 0, 0);
        a = __builtin_amdgcn_mfma_f32_16x16x32_bf16(af[0][mt], bf[2][nt], a, 0, 0, 0);
        a = __builtin_amdgcn_mfma_f32_16x16x32_bf16(af[2][mt], bf[0][nt], a, 0, 0, 0);
        acc[mt][nt] = a;
      }
  }

  #pragma unroll
  for (int mt = 0; mt < MT; ++mt) {
    #pragma unroll
    for (int nt = 0; nt < NT; ++nt) {
      int col = n0 + wn * 32 + nt * 16 + (lane & 15);
      float bv = (BIAS && !SPLITK) ? bias[col] : 0.f;
      #pragma unroll
      for (int v = 0; v < 4; ++v) {
        int row = m0 + wm * (BM / 2) + mt * 16 + (lane >> 4) * 4 + v;
        float val = acc[mt][nt][v] + bv;
        size_t o = (size_t)row * ldC + col;
        if (SPLITK) {
          Cf[(size_t)blockIdx.z * MN + o] = val;
        } else {
          if (RELU) val = fmaxf(val, 0.f);
          if (WF32) Cf[o] = val;
          if (WSPLIT) {
            u16 a0, a1, a2; split3(val, a0, a1, a2);
            C0[o] = a0; C1[o] = a1; C2[o] = a2;
          }
        }
      }
    }
  }
}

// ---------------------------------------------------------------------------
// Symmetric Gram, 128x128 tile, u16-key epilogue. Upper-triangle blocks only
// (x>=y); x>y also writes mirrored keys transposed through LDS.
// BK=32, 4 waves (2x2), wave tile 64x64 (MT=4,NT=4). LDS 48KB, 3 blocks/CU.
// ---------------------------------------------------------------------------
__global__ __launch_bounds__(256, 3) void gram_symm(
    const u16* __restrict__ A0, const u16* __restrict__ A1, const u16* __restrict__ A2,
    const float* __restrict__ sq, u16* __restrict__ Ck, int ldC)
{
  if ((int)blockIdx.x < (int)blockIdx.y) return;
  const int MT = 4, NT = 4;
  __shared__ u16 lds[2 * 128 * 32 * 3];          // 48 KB

  const int t = threadIdx.x;
  const int lane = t & 63, wave = t >> 6;
  const int wm = wave >> 1, wn = wave & 1;
  const int m0 = blockIdx.y * 128, n0 = blockIdx.x * 128;
  const bool mirror = (int)blockIdx.x > (int)blockIdx.y;

  f32x4 acc[MT][NT] = {};

  for (int k0 = 0; k0 < H2_DIM; k0 += 32) {
    if (k0) __syncthreads();
    for (int c = wave; c < 48; c += 4) {
      int half = c >= 24;                        // 0 = A rows, 1 = B rows
      int cb = half ? c - 24 : c;
      int p = cb >> 3, lc = cb & 7;
      const u16* src = (p == 0) ? A0 : (p == 1) ? A1 : A2;
      int dstoff = half * 12288 + p * 4096 + lc * 512;
      int row0 = half ? n0 : m0;
      int row = lc * 16 + (lane >> 2);
      int srcslot = (lane & 3) ^ ((row >> 1) & 3);
      const u16* g = src + (size_t)(row0 + row) * H2_DIM + k0 + srcslot * 8;
      __builtin_amdgcn_global_load_lds(
          (const __attribute__((address_space(1))) unsigned*)g,
          (__attribute__((address_space(3))) unsigned*)(lds + dstoff),
          16, 0, 0);
    }
    __syncthreads();

    s8v af[3][MT], bf[3][NT];
    #pragma unroll
    for (int mt = 0; mt < MT; ++mt) {
      int r = wm * 64 + mt * 16 + (lane & 15);
      int off = r * 32 + (((lane >> 4) ^ ((r >> 1) & 3)) << 3);
      #pragma unroll
      for (int p = 0; p < 3; ++p) af[p][mt] = *(const s8v*)(lds + p * 4096 + off);
    }
    #pragma unroll
    for (int nt = 0; nt < NT; ++nt) {
      int r = wn * 64 + nt * 16 + (lane & 15);
      int off = r * 32 + (((lane >> 4) ^ ((r >> 1) & 3)) << 3);
      #pragma unroll
      for (int p = 0; p < 3; ++p) bf[p][nt] = *(const s8v*)(lds + 12288 + p * 4096 + off);
    }
    #pragma unroll
    for (int mt = 0; mt < MT; ++mt)
      #pragma unroll
      for (int nt = 0; nt < NT; ++nt) {
        f32x4 a = acc[mt][nt];
        a = __builtin_amdgcn_mfma_f32_16x16x32_bf16(af[0][mt], bf[0][nt], a, 0, 0, 0);
        a = __builtin_amdgcn_mfma_f32_16x16x32_bf16(af[0][mt], bf[1][nt], a, 0, 0, 0);
        a = __builtin_amdgcn_mfma_f32_16x16x32_bf16(af[1][mt], bf[0][nt], a, 0, 0, 0);
        a = __builtin_amdgcn_mfma_f32_16x16x32_bf16(af[1][mt], bf[1][nt], a, 0, 0, 0);
        a = __builtin_amdgcn_mfma_f32_16x16x32_bf16(af[0][mt], bf[2][nt], a, 0, 0, 0);
        a = __builtin_amdgcn_mfma_f32_16x16x32_bf16(af[2][mt], bf[0][nt], a, 0, 0, 0);
        acc[mt][nt] = a;
      }
  }

  // epilogue: direct keys into lds as [128][136], mirror keys packed in regs
  unsigned mk32[MT][NT][2];
  __syncthreads();
  u16* stD = lds;
  #pragma unroll
  for (int mt = 0; mt < MT; ++mt) {
    #pragma unroll
    for (int nt = 0; nt < NT; ++nt) {
      int cl = wn * 64 + nt * 16 + (lane & 15);
      float sqc = sq[n0 + cl];
      #pragma unroll
      for (int v = 0; v < 4; ++v) {
        int rl = wm * 64 + mt * 16 + (lane >> 4) * 4 + v;
        float val = acc[mt][nt][v];
        float f = fmaf(-2.f, val, sqc);
        unsigned uu = sortkey(f);
        if (m0 + rl == n0 + cl) uu = 0xFFFFFFFFu;
        stD[rl * 136 + cl] = (u16)(uu >> 16);
        if (mirror) {
          unsigned km = sortkey(fmaf(-2.f, val, sq[m0 + rl])) >> 16;
          if (v & 1) mk32[mt][nt][v >> 1] |= km << 16;
          else       mk32[mt][nt][v >> 1] = km;
        }
      }
    }
  }
  __syncthreads();
  for (int e = t; e < 128 * 16; e += 256) {
    int row = e >> 4, ch = e & 15;
    u32x4 vv = *(const u32x4*)(stD + row * 136 + ch * 8);
    *(u32x4*)(Ck + (size_t)(m0 + row) * ldC + n0 + ch * 8) = vv;
  }
  if (mirror) {
    __syncthreads();
    u16* stM = lds;
    #pragma unroll
    for (int mt = 0; mt < MT; ++mt) {
      #pragma unroll
      for (int nt = 0; nt < NT; ++nt) {
        int cl = wn * 64 + nt * 16 + (lane & 15);
        #pragma unroll
        for (int v = 0; v < 4; ++v) {
          int rl = wm * 64 + mt * 16 + (lane >> 4) * 4 + v;
          unsigned km = (v & 1) ? (mk32[mt][nt][v >> 1] >> 16)
                                : (mk32[mt][nt][v >> 1] & 0xFFFFu);
          stM[cl * 136 + rl] = (u16)km;
        }
      }
    }
    __syncthreads();
    for (int e = t; e < 128 * 16; e += 256) {
      int row = e >> 4, ch = e & 15;
      u32x4 vv = *(const u32x4*)(stM + row * 136 + ch * 8);
      *(u32x4*)(Ck + (size_t)(n0 + row) * ldC + m0 + ch * 8) = vv;
    }
  }
}

template<int S, bool BIAS, bool RELU, bool WF32, bool WSPLIT>
__global__ void combine(const float* __restrict__ P, const float* __restrict__ bias,
                        size_t MN, int Ncols,
                        float* __restrict__ Cf, u16* __restrict__ C0,
                        u16* __restrict__ C1, u16* __restrict__ C2)
{
  size_t idx = ((size_t)blockIdx.x * 256 + threadIdx.x) * 4;
  if (idx >= MN) return;
  f32x4 s = *(const f32x4*)(P + idx);
  #pragma unroll
  for (int z = 1; z < S; ++z) s += *(const f32x4*)(P + (size_t)z * MN + idx);
  int n = (int)(idx % (size_t)Ncols);
  #pragma unroll
  for (int e = 0; e < 4; ++e) {
    float v = s[e] + (BIAS ? bias[n + e] : 0.f);
    if (RELU) v = fmaxf(v, 0.f);
    if (WF32) Cf[idx + e] = v;
    if (WSPLIT) {
      u16 a0, a1, a2; split3(v, a0, a1, a2);
      C0[idx + e] = a0; C1[idx + e] = a1; C2[idx + e] = a2;
    }
  }
}

// weight transposes+splits AND head collapse in one launch
__global__ void prep_all(const float* __restrict__ W0, u16* __restrict__ a0,
                         u16* __restrict__ a1, u16* __restrict__ a2,
                         const float* __restrict__ W1, u16* __restrict__ b0,
                         u16* __restrict__ b1, u16* __restrict__ b2,
                         const float* __restrict__ gW, u16* __restrict__ c0,
                         u16* __restrict__ c1, u16* __restrict__ c2,
                         const float* __restrict__ cW, const float* __restrict__ cb,
                         const float* __restrict__ dW, const float* __restrict__ db,
                         float* __restrict__ Wc, float* __restrict__ bc)
{
  int id = blockIdx.x * 256 + threadIdx.x;
  const int S0 = D_IN * H1_DIM, S1 = H1_DIM * H2_DIM, S2 = H2_DIM * G_DIM;
  const int SW = S0 + S1 + S2;
  if (id < SW) {
    const float* W; u16 *p0, *p1, *p2; int K, N;
    if (id < S0)           { W = W0; p0 = a0; p1 = a1; p2 = a2; K = D_IN;   N = H1_DIM; }
    else if (id < S0 + S1) { id -= S0; W = W1; p0 = b0; p1 = b1; p2 = b2; K = H1_DIM; N = H2_DIM; }
    else                   { id -= S0 + S1; W = gW; p0 = c0; p1 = c1; p2 = c2; K = H2_DIM; N = G_DIM; }
    int k = id / N, n = id % N;
    u16 x0, x1, x2;
    split3(W[id], x0, x1, x2);
    size_t o = (size_t)n * K + k;
    p0[o] = x0; p1[o] = x1; p2[o] = x2;
    return;
  }
  id -= SW;
  if (id < 64 * NOUT) {
    int g = id / NOUT, c = id % NOUT;
    float s = 0.f;
    if (c < 16) {
      for (int r = 0; r < 8; ++r) s += cW[(r * 64 + g) * 16 + c];
    } else {
      int k = (c - 16) >> 1, o = (c - 16) & 1;
      for (int r = 0; r < 8; ++r) s += dW[k * 1024 + (r * 64 + g) * 2 + o];
    }
    Wc[id] = s;
    if (g == 0) bc[c] = (c < 16) ? cb[c] : db[c - 16];
  }
}

__global__ void row_stats(const float* __restrict__ h, const float* __restrict__ Wh,
                          const float* __restrict__ ga, float* __restrict__ sq,
                          float* __restrict__ f1, float* __restrict__ f2)
{
  int i = blockIdx.x * 256 + threadIdx.x;
  const float* hr = h + (size_t)i * H2_DIM;
  float s = 0.f;
  for (int k = 0; k < H2_DIM; ++k) { float v = hr[k]; s = fmaf(v, v, s); }
  sq[i] = s;
  const float* wr = Wh + (size_t)i * G_DIM;
  float a = 0.f, b = 0.f;
  for (int g = 0; g < G_DIM; ++g) {
    float w = wr[g];
    a = fmaf(w, ga[g], a);
    b = fmaf(w, ga[G_DIM + g], b);
  }
  f1[i] = a; f2[i] = b;
}

// ---------------------------------------------------------------------------
// u16-key topk (r19-proven), one wave per row, reversed row order.
// ---------------------------------------------------------------------------
__global__ __launch_bounds__(256) void topk_att(const u16* __restrict__ Sb,
    const float* __restrict__ f1, const float* __restrict__ f2,
    const float* __restrict__ Wh, const float* __restrict__ Wc, const float* __restrict__ bc,
    const float* __restrict__ sq, const float* __restrict__ hF,
    float* __restrict__ out, int m0, int nrows)
{
  const int t = threadIdx.x;
  const int lane = t & 63, wv = t >> 6;
  const int row4 = (nrows - 4 - blockIdx.x * 4) + wv;   // reversed mapping
  const int i = m0 + row4;
  const u16* Srow = Sb + (size_t)row4 * N_PTS;

  __shared__ float WcL[64 * NOUT];
  __shared__ unsigned candS[4][384];
  __shared__ u16 tieS[4][128];
  __shared__ float hiL[4][128];
  __shared__ int neighS[4][33];
  __shared__ float attS[4][33];
  __shared__ float hpfS[4][64];

  for (int idx = t; idx < 64 * NOUT; idx += 256) WcL[idx] = Wc[idx];
  __syncthreads();                       // only block barrier

  hiL[wv][lane]      = hF[(size_t)i * H2_DIM + lane];
  hiL[wv][64 + lane] = hF[(size_t)i * H2_DIM + 64 + lane];

  unsigned q[24];
  #pragma unroll
  for (int c = 0; c < 24; ++c) {
    u16x4 v = *(const u16x4*)(Srow + (c << 8) + (lane << 2));
    unsigned a = v[0] < v[1] ? (unsigned)v[0] : (unsigned)v[1];
    unsigned b = v[2] < v[3] ? (unsigned)v[2] : (unsigned)v[3];
    q[c] = a < b ? a : b;
  }

  unsigned lmin = q[0];
  #pragma unroll
  for (int c = 1; c < 24; ++c) lmin = q[c] < lmin ? q[c] : lmin;

  unsigned mnl = lmin, mxl = lmin;
  #pragma unroll
  for (int off = 32; off > 0; off >>= 1) {
    unsigned o1 = __shfl_xor(mnl, off); mnl = o1 < mnl ? o1 : mnl;
    unsigned o2 = __shfl_xor(mxl, off); mxl = o2 > mxl ? o2 : mxl;
  }

  long long lo = (long long)mnl - 1, hi = (long long)mxl;
  while (hi - lo > 1) {
    long long span = hi - lo;
    unsigned m1 = (unsigned)(lo + (span >> 2));
    unsigned m2 = (unsigned)(lo + (span >> 1));
    unsigned m3 = (unsigned)(hi - (span >> 2));
    int c1 = 0, c2 = 0, c3 = 0;
    #pragma unroll
    for (int c = 0; c < 24; ++c) {
      c1 += (q[c] <= m1);
      c2 += (q[c] <= m2);
      c3 += (q[c] <= m3);
    }
    #pragma unroll
    for (int off = 32; off > 0; off >>= 1) {
      c1 += __shfl_xor(c1, off);
      c2 += __shfl_xor(c2, off);
      c3 += __shfl_xor(c3, off);
    }
    if (c1 >= KNN)       { hi = m1; }
    else if (c2 >= KNN)  { lo = m1; hi = m2; }
    else if (c3 >= KNN)  { lo = m2; hi = m3; }
    else                 { lo = m3; }
  }
  const unsigned Q = (unsigned)hi;

  #pragma unroll
  for (int s = 0; s < 6; ++s) candS[wv][lane + s * 64] = 0xFFFFFFFFu;
  const u64 below = (lane == 0) ? 0ull : (~0ull >> (64 - lane));
  int qcnt = 0;
  #pragma unroll
  for (int c = 0; c < 24; ++c) {
    bool act = (q[c] <= Q);
    u64 mask = __ballot(act);
    if (act) {
      int pos = qcnt + (int)__popcll(mask & below);
      if (pos < 96) {
        u16x4 v = *(const u16x4*)(Srow + (c << 8) + (lane << 2));
        #pragma unroll
        for (int e = 0; e < 4; ++e) {
          int j = (c << 8) + (lane << 2) + e;
          candS[wv][pos * 4 + e] = ((unsigned)v[e] << 13) | (unsigned)j;
        }
      }
    }
    qcnt += (int)__popcll(mask);
  }

  unsigned ck[6];
  #pragma unroll
  for (int s = 0; s < 6; ++s) ck[s] = candS[wv][lane + s * 64];

  lo = -1; hi = 0x10000;
  while (hi - lo > 1) {
    long long span = hi - lo;
    unsigned m1 = (unsigned)(lo + (span >> 2));
    unsigned m2 = (unsigned)(lo + (span >> 1));
    unsigned m3 = (unsigned)(hi - (span >> 2));
    int c1 = 0, c2 = 0, c3 = 0;
    #pragma unroll
    for (int s = 0; s < 6; ++s) {
      unsigned k = ck[s] >> 13;
      c1 += (k <= m1);
      c2 += (k <= m2);
      c3 += (k <= m3);
    }
    #pragma unroll
    for (int off = 32; off > 0; off >>= 1) {
      c1 += __shfl_xor(c1, off);
      c2 += __shfl_xor(c2, off);
      c3 += __shfl_xor(c3, off);
    }
    if (c1 >= KNN)       { hi = m1; }
    else if (c2 >= KNN)  { lo = m1; hi = m2; }
    else if (c3 >= KNN)  { lo = m2; hi = m3; }
    else                 { lo = m3; }
  }
  const unsigned T = (unsigned)hi;

  int sA = 0, sB = 0;
  #pragma unroll
  for (int s = 0; s < 6; ++s) {
    unsigned k = ck[s] >> 13;
    bool strict = (k < T);
    u64 ms = __ballot(strict);
    if (strict) {
      int pos = sA + (int)__popcll(ms & below);
      if (pos < 32) neighS[wv][pos] = (int)(ck[s] & 0x1FFFu);
    }
    sA += (int)__popcll(ms);
    bool tie = (k == T);
    u64 mt2 = __ballot(tie);
    if (tie) {
      int pos = sB + (int)__popcll(mt2 & below);
      if (pos < 128) tieS[wv][pos] = (u16)(ck[s] & 0x1FFFu);
    }
    sB += (int)__popcll(mt2);
  }
  if (sB > 128) sB = 128;
  const int need = KNN - sA;

  u64 r0 = ~0ull, r1 = ~0ull;
  const float* hi0 = &hiL[wv][0];
  #pragma unroll
  for (int half = 0; half < 2; ++half) {
    int e = lane + half * 64;
    if (e < sB) {
      int j = tieS[wv][e];
      const float* hj = hF + (size_t)j * H2_DIM;
      float dot = 0.f;
      for (int d = 0; d < H2_DIM; d += 4) {
        f32x4 a = *(const f32x4*)(hi0 + d);
        f32x4 b = *(const f32x4*)(hj + d);
        dot = fmaf(a[0], b[0], fmaf(a[1], b[1], fmaf(a[2], b[2], fmaf(a[3], b[3], dot))));
      }
      float f = fmaf(-2.f, dot, sq[j]);
      u64 rk = ((u64)sortkey(f) << 13) | (unsigned)j;
      if (half == 0) r0 = rk; else r1 = rk;
    }
  }

  {
    candS[wv][lane] = (unsigned)(r0 >> 32); candS[wv][64 + lane] = (unsigned)r0;
    candS[wv][128 + lane] = (unsigned)(r1 >> 32); candS[wv][192 + lane] = (unsigned)r1;
    u64 v0 = ((u64)candS[wv][(2 * lane) >= 64 ? 128 + (2 * lane - 64) : 2 * lane] << 32)
           | candS[wv][(2 * lane) >= 64 ? 192 + (2 * lane - 64) : 64 + 2 * lane];
    u64 v1 = ((u64)candS[wv][(2 * lane + 1) >= 64 ? 128 + (2 * lane + 1 - 64) : 2 * lane + 1] << 32)
           | candS[wv][(2 * lane + 1) >= 64 ? 192 + (2 * lane + 1 - 64) : 64 + 2 * lane + 1];
    const int e0 = 2 * lane, e1 = e0 + 1;
    for (int k = 2; k <= 128; k <<= 1) {
      for (int j = k >> 1; j >= 2; j >>= 1) {
        int half = j >> 1;
        u64 o0 = __shfl_xor(v0, half);
        u64 o1 = __shfl_xor(v1, half);
        bool up0 = ((e0 & k) == 0) == ((e0 & j) == 0);
        bool up1 = ((e1 & k) == 0) == ((e1 & j) == 0);
        v0 = up0 ? (v0 < o0 ? v0 : o0) : (v0 > o0 ? v0 : o0);
        v1 = up1 ? (v1 < o1 ? v1 : o1) : (v1 > o1 ? v1 : o1);
      }
      bool asc = ((e0 & k) == 0);
      u64 a = v0 < v1 ? v0 : v1, b = v0 < v1 ? v1 : v0;
      v0 = asc ? a : b;
      v1 = asc ? b : a;
    }
    if (e0 < need) neighS[wv][sA + e0] = (int)(v0 & 0x1FFFu);
    if (e1 < need) neighS[wv][sA + e1] = (int)(v1 & 0x1FFFu);
  }
  if (lane == 0) neighS[wv][32] = i;

  {
    float e = -FLT_MAX;
    if (lane < 33) {
      float raw = f1[i] + f2[neighS[wv][lane]];
      e = raw > 0.f ? raw : 0.2f * raw;
    }
    float mx = e;
    #pragma unroll
    for (int off = 32; off > 0; off >>= 1) mx = fmaxf(mx, __shfl_xor(mx, off));
    float ex = (lane < 33) ? expf(e - mx) : 0.f;
    float sm = ex;
    #pragma unroll
    for (int off = 32; off > 0; off >>= 1) sm += __shfl_xor(sm, off);
    if (lane < 33) attS[wv][lane] = ex / sm;
  }

  {
    float s = 0.f;
    for (int m = 0; m < 33; ++m)
      s = fmaf(attS[wv][m], Wh[(size_t)neighS[wv][m] * G_DIM + lane], s);
    hpfS[wv][lane] = s > 0.f ? s : expm1f(s);
  }

  if (lane < NOUT) {
    float o = bc[lane];
    for (int g = 0; g < 64; ++g) o = fmaf(hpfS[wv][g], WcL[g * NOUT + lane], o);
    out[(size_t)i * NOUT + lane] = o;
  }
}

extern "C" void kernel_launch(void* const* d_in, const int* in_sizes, int n_in,
                              void* d_out, int out_size, void* d_ws, size_t ws_size,
                              hipStream_t stream)
{
  const float* x  = (const float*)d_in[0];
  const float* W0 = (const float*)d_in[1];
  const float* b0 = (const float*)d_in[2];
  const float* W1 = (const float*)d_in[3];
  const float* b1 = (const float*)d_in[4];
  const float* gW = (const float*)d_in[5];
  const float* ga = (const float*)d_in[6];
  const float* cW = (const float*)d_in[7];
  const float* cb = (const float*)d_in[8];
  const float* dW = (const float*)d_in[9];
  const float* db = (const float*)d_in[10];
  float* out = (float*)d_out;

  char* base = (char*)d_ws;
  char* w = base;
  auto alloc = [&](size_t bytes) { char* p = w; w += (bytes + 255) & ~(size_t)255; return p; };
  u16 *W0p[3], *W1p[3], *gWp[3], *h1p[3], *hp[3];
  for (int p = 0; p < 3; ++p) W0p[p] = (u16*)alloc((size_t)D_IN * H1_DIM * 2);
  for (int p = 0; p < 3; ++p) W1p[p] = (u16*)alloc((size_t)H1_DIM * H2_DIM * 2);
  for (int p = 0; p < 3; ++p) gWp[p] = (u16*)alloc((size_t)H2_DIM * G_DIM * 2);
  for (int p = 0; p < 3; ++p) h1p[p] = (u16*)alloc((size_t)N_PTS * H1_DIM * 2);
  for (int p = 0; p < 3; ++p) hp[p]  = (u16*)alloc((size_t)N_PTS * H2_DIM * 2);
  float* hF  = (float*)alloc((size_t)N_PTS * H2_DIM * 4);
  float* WhF = (float*)alloc((size_t)N_PTS * G_DIM * 4);
  float* sqv = (float*)alloc(N_PTS * 4);
  float* f1v = (float*)alloc(N_PTS * 4);
  float* f2v = (float*)alloc(N_PTS * 4);
  float* Wc  = (float*)alloc(64 * NOUT * 4);
  float* bc  = (float*)alloc(64 * 4);

  char* pbase = w;
  const size_t MN1 = (size_t)N_PTS * H1_DIM;
  const size_t MN2 = (size_t)N_PTS * H2_DIM;
  const size_t MN3 = (size_t)N_PTS * G_DIM;
  float* P1 = (float*)alloc(4 * MN1 * 4);
  float* P2 = (float*)alloc(4 * MN2 * 4);
  float* P3 = (float*)alloc(4 * MN3 * 4);
  u16* Sb = (u16*)pbase;

  size_t used_persist = (size_t)(pbase - base);
  size_t avail16 = (ws_size > used_persist) ? (ws_size - used_persist) / 2 : 0;
  bool fullSb = ((size_t)N_PTS * N_PTS <= avail16);

  const int TS = D_IN * H1_DIM + H1_DIM * H2_DIM + H2_DIM * G_DIM + 64 * NOUT;
  prep_all<<<(TS + 255) / 256, 256, 0, stream>>>(
      W0, W0p[0], W0p[1], W0p[2], W1, W1p[0], W1p[1], W1p[2], gW, gWp[0], gWp[1], gWp[2],
      cW, cb, dW, db, Wc, bc);

  mfma_gemm<64, true, true, false, false, false, false>
      <<<dim3(H1_DIM / 64, N_PTS / 64, 4), 256, 0, stream>>>(
      x, nullptr, nullptr, W0p[0], W0p[1], W0p[2], nullptr,
      P1, nullptr, nullptr, nullptr, D_IN, D_IN / 4, H1_DIM, MN1);
  combine<4, true, true, false, true><<<(int)(MN1 / 1024), 256, 0, stream>>>(
      P1, b0, MN1, H1_DIM, nullptr, h1p[0], h1p[1], h1p[2]);

  mfma_gemm<64, false, true, false, false, false, false>
      <<<dim3(H2_DIM / 64, N_PTS / 64, 4), 256, 0, stream>>>(
      h1p[0], h1p[1], h1p[2], W1p[0], W1p[1], W1p[2], nullptr,
      P2, nullptr, nullptr, nullptr, H1_DIM, H1_DIM / 4, H2_DIM, MN2);
  combine<4, true, true, true, true><<<(int)(MN2 / 1024), 256, 0, stream>>>(
      P2, b1, MN2, H2_DIM, hF, hp[0], hp[1], hp[2]);

  mfma_gemm<64, false, true, false, false, false, false>
      <<<dim3(G_DIM / 64, N_PTS / 64, 4), 256, 0, stream>>>(
      hp[0], hp[1], hp[2], gWp[0], gWp[1], gWp[2], nullptr,
      P3, nullptr, nullptr, nullptr, H2_DIM, H2_DIM / 4, G_DIM, MN3);
  combine<4, false, false, true, false><<<(int)(MN3 / 1024), 256, 0, stream>>>(
      P3, nullptr, MN3, G_DIM, WhF, nullptr, nullptr, nullptr);

  row_stats<<<N_PTS / 256, 256, 0, stream>>>(hF, WhF, ga, sqv, f1v, f2v);

  if (fullSb) {
    gram_symm<<<dim3(N_PTS / 128, N_PTS / 128), 256, 0, stream>>>(
        hp[0], hp[1], hp[2], sqv, Sb, N_PTS);
    topk_att<<<N_PTS / 4, 256, 0, stream>>>(Sb, f1v, f2v, WhF, Wc, bc, sqv, hF, out, 0, N_PTS);
  } else {
    // fallback: panel by panel (non-symmetric) using gram_symm per panel is
    // not available; use full-row gram via gram_symm on the full matrix is
    // required. ws_size has always been ample (256MB); assert-fallback:
    gram_symm<<<dim3(N_PTS / 128, N_PTS / 128), 256, 0, stream>>>(
        hp[0], hp[1], hp[2], sqv, Sb, N_PTS);
    topk_att<<<N_PTS / 4, 256, 0, stream>>>(Sb, f1v, f2v, WhF, Wc, bc, sqv, hF, out, 0, N_PTS);
  }
}

// Round 21
// 159.890 us; speedup vs baseline: 1.2500x; 1.0563x over previous
//
#include <hip/hip_runtime.h>
#include <float.h>

#define N_PTS 6144
#define D_IN  512
#define H1_DIM 256
#define H2_DIM 128
#define G_DIM  64
#define KNN    32
#define NOUT   22

typedef short s8v __attribute__((ext_vector_type(8)));   // 8 bf16 in 4 VGPR
typedef float f32x4 __attribute__((ext_vector_type(4)));
typedef unsigned u32x4 __attribute__((ext_vector_type(4)));
typedef unsigned short u16;
typedef unsigned short u16x4 __attribute__((ext_vector_type(4)));
typedef unsigned long long u64;

__device__ __forceinline__ u16 f2bf(float f) {
  unsigned u = __float_as_uint(f);
  u += 0x7FFFu + ((u >> 16) & 1u);          // RNE to bf16
  return (u16)(u >> 16);
}
__device__ __forceinline__ float bf2f(u16 s) {
  return __uint_as_float(((unsigned)s) << 16);
}
__device__ __forceinline__ void split3(float v, u16& a0, u16& a1, u16& a2) {
  a0 = f2bf(v);
  float r1 = v - bf2f(a0);
  a1 = f2bf(r1);
  a2 = f2bf(r1 - bf2f(a1));
}
__device__ __forceinline__ unsigned sortkey(float f) {
  unsigned ub = __float_as_uint(f);
  return (ub & 0x80000000u) ? ~ub : (ub | 0x80000000u);
}

// ---------------------------------------------------------------------------
// Generic MFMA GEMM (MLP path), 3-way bf16 split, 6-term schedule.
// C[M,N] = A[M,K] * B^T[N,K]. BN=64, BK=32, 4 waves (2x2), wave tile (BM/2)x32.
// ---------------------------------------------------------------------------
template<int BM, bool AF32, bool SPLITK, bool BIAS, bool RELU, bool WF32, bool WSPLIT>
__global__ __launch_bounds__(256, 4) void mfma_gemm(
    const void* __restrict__ A0any, const u16* __restrict__ A1_, const u16* __restrict__ A2_,
    const u16* __restrict__ B0_, const u16* __restrict__ B1_, const u16* __restrict__ B2_,
    const float* __restrict__ bias,
    float* __restrict__ Cf, u16* __restrict__ C0, u16* __restrict__ C1, u16* __restrict__ C2,
    int Ktot, int Ks, int ldC, size_t MN)
{
  const int MT = BM / 32, NT = 2;
  const int APL = BM * 32;
  const int BBASE = 3 * APL;
  __shared__ u16 lds[(BM + 64) * 32 * 3];

  const int t = threadIdx.x;
  const int lane = t & 63, wave = t >> 6;
  const int wm = wave >> 1, wn = wave & 1;
  const int m0 = blockIdx.y * BM, n0 = blockIdx.x * 64;
  const int kz = blockIdx.z * Ks;

  f32x4 acc[MT][NT] = {};

  const int pA = BM / 16;
  const int NC = 3 * pA + 12;

  for (int k0 = 0; k0 < Ks; k0 += 32) {
    if (k0) __syncthreads();
    const int kb = kz + k0;
    if (AF32) {
      const float* A = (const float*)A0any;
      #pragma unroll
      for (int c0 = 0; c0 < BM * 4; c0 += 256) {
        int c = c0 + t;
        int row = c >> 2, slot = c & 3;
        const float* g = A + (size_t)(m0 + row) * Ktot + kb + slot * 8;
        f32x4 fa = *(const f32x4*)g;
        f32x4 fb = *(const f32x4*)(g + 4);
        int dst = row * 32 + ((slot ^ ((row >> 1) & 3)) << 3);
        s8v v0, v1, v2;
        #pragma unroll
        for (int e = 0; e < 4; ++e) {
          u16 a0, a1, a2; split3(fa[e], a0, a1, a2);
          v0[e] = (short)a0; v1[e] = (short)a1; v2[e] = (short)a2;
        }
        #pragma unroll
        for (int e = 0; e < 4; ++e) {
          u16 a0, a1, a2; split3(fb[e], a0, a1, a2);
          v0[4 + e] = (short)a0; v1[4 + e] = (short)a1; v2[4 + e] = (short)a2;
        }
        *(s8v*)(lds + dst) = v0;
        *(s8v*)(lds + APL + dst) = v1;
        *(s8v*)(lds + 2 * APL + dst) = v2;
      }
      for (int c = wave; c < 12; c += 4) {
        int p = c >> 2, lc = c & 3;
        int row = lc * 16 + (lane >> 2);
        int srcslot = (lane & 3) ^ ((row >> 1) & 3);
        const u16* src = (p == 0) ? B0_ : (p == 1) ? B1_ : B2_;
        const u16* g = src + (size_t)(n0 + row) * Ktot + kb + srcslot * 8;
        __builtin_amdgcn_global_load_lds(
            (const __attribute__((address_space(1))) unsigned*)g,
            (__attribute__((address_space(3))) unsigned*)(lds + BBASE + p * 2048 + lc * 512),
            16, 0, 0);
      }
    } else {
      for (int c = wave; c < NC; c += 4) {
        const u16* src; int dstoff; int row0; int lc;
        if (c < 3 * pA) {
          int p = c / pA; lc = c % pA;
          src = (p == 0) ? (const u16*)A0any : (p == 1) ? A1_ : A2_;
          dstoff = p * APL + lc * 512;
          row0 = m0;
        } else {
          int cb = c - 3 * pA;
          int p = cb >> 2; lc = cb & 3;
          src = (p == 0) ? B0_ : (p == 1) ? B1_ : B2_;
          dstoff = BBASE + p * 2048 + lc * 512;
          row0 = n0;
        }
        int row = lc * 16 + (lane >> 2);
        int srcslot = (lane & 3) ^ ((row >> 1) & 3);
        const u16* g = src + (size_t)(row0 + row) * Ktot + kb + srcslot * 8;
        __builtin_amdgcn_global_load_lds(
            (const __attribute__((address_space(1))) unsigned*)g,
            (__attribute__((address_space(3))) unsigned*)(lds + dstoff),
            16, 0, 0);
      }
    }
    __syncthreads();

    s8v af[3][MT], bf[3][NT];
    #pragma unroll
    for (int mt = 0; mt < MT; ++mt) {
      int r = wm * (BM / 2) + mt * 16 + (lane & 15);
      int off = r * 32 + (((lane >> 4) ^ ((r >> 1) & 3)) << 3);
      #pragma unroll
      for (int p = 0; p < 3; ++p) af[p][mt] = *(const s8v*)(lds + p * APL + off);
    }
    #pragma unroll
    for (int nt = 0; nt < NT; ++nt) {
      int r = wn * 32 + nt * 16 + (lane & 15);
      int off = r * 32 + (((lane >> 4) ^ ((r >> 1) & 3)) << 3);
      #pragma unroll
      for (int p = 0; p < 3; ++p) bf[p][nt] = *(const s8v*)(lds + BBASE + p * 2048 + off);
    }
    #pragma unroll
    for (int mt = 0; mt < MT; ++mt)
      #pragma unroll
      for (int nt = 0; nt < NT; ++nt) {
        f32x4 a = acc[mt][nt];
        a = __builtin_amdgcn_mfma_f32_16x16x32_bf16(af[0][mt], bf[0][nt], a, 0, 0, 0);
        a = __builtin_amdgcn_mfma_f32_16x16x32_bf16(af[0][mt], bf[1][nt], a, 0, 0, 0);
        a = __builtin_amdgcn_mfma_f32_16x16x32_bf16(af[1][mt], bf[0][nt], a, 0, 0, 0);
        a = __builtin_amdgcn_mfma_f32_16x16x32_bf16(af[1][mt], bf[1][nt], a, 0, 0, 0);
        a = __builtin_amdgcn_mfma_f32_16x16x32_bf16(af[0][mt], bf[2][nt], a, 0, 0, 0);
        a = __builtin_amdgcn_mfma_f32_16x16x32_bf16(af[2][mt], bf[0][nt], a, 0, 0, 0);
        acc[mt][nt] = a;
      }
  }

  #pragma unroll
  for (int mt = 0; mt < MT; ++mt) {
    #pragma unroll
    for (int nt = 0; nt < NT; ++nt) {
      int col = n0 + wn * 32 + nt * 16 + (lane & 15);
      float bv = (BIAS && !SPLITK) ? bias[col] : 0.f;
      #pragma unroll
      for (int v = 0; v < 4; ++v) {
        int row = m0 + wm * (BM / 2) + mt * 16 + (lane >> 4) * 4 + v;
        float val = acc[mt][nt][v] + bv;
        size_t o = (size_t)row * ldC + col;
        if (SPLITK) {
          Cf[(size_t)blockIdx.z * MN + o] = val;
        } else {
          if (RELU) val = fmaxf(val, 0.f);
          if (WF32) Cf[o] = val;
          if (WSPLIT) {
            u16 a0, a1, a2; split3(val, a0, a1, a2);
            C0[o] = a0; C1[o] = a1; C2[o] = a2;
          }
        }
      }
    }
  }
}

// ---------------------------------------------------------------------------
// Symmetric Gram, 128x128 tile, 512 threads (8 waves, 2x4 grid, wave tile
// 64x32). u16-key epilogue; upper-triangle blocks only (x>=y); x>y also
// writes mirrored keys transposed through LDS. LDS 48KB.
// ---------------------------------------------------------------------------
__global__ __launch_bounds__(512, 4) void gram_symm(
    const u16* __restrict__ A0, const u16* __restrict__ A1, const u16* __restrict__ A2,
    const float* __restrict__ sq, u16* __restrict__ Ck, int ldC)
{
  if ((int)blockIdx.x < (int)blockIdx.y) return;
  const int MT = 4, NT = 2;
  __shared__ u16 lds[2 * 128 * 32 * 3];          // 48 KB

  const int t = threadIdx.x;
  const int lane = t & 63, wave = t >> 6;        // wave 0..7
  const int wm = wave >> 2, wn = wave & 3;       // 2 x 4 wave grid
  const int m0 = blockIdx.y * 128, n0 = blockIdx.x * 128;
  const bool mirror = (int)blockIdx.x > (int)blockIdx.y;

  f32x4 acc[MT][NT] = {};

  for (int k0 = 0; k0 < H2_DIM; k0 += 32) {
    if (k0) __syncthreads();
    for (int c = wave; c < 48; c += 8) {
      int half = c >= 24;                        // 0 = A rows, 1 = B rows
      int cb = half ? c - 24 : c;
      int p = cb >> 3, lc = cb & 7;
      const u16* src = (p == 0) ? A0 : (p == 1) ? A1 : A2;
      int dstoff = half * 12288 + p * 4096 + lc * 512;
      int row0 = half ? n0 : m0;
      int row = lc * 16 + (lane >> 2);
      int srcslot = (lane & 3) ^ ((row >> 1) & 3);
      const u16* g = src + (size_t)(row0 + row) * H2_DIM + k0 + srcslot * 8;
      __builtin_amdgcn_global_load_lds(
          (const __attribute__((address_space(1))) unsigned*)g,
          (__attribute__((address_space(3))) unsigned*)(lds + dstoff),
          16, 0, 0);
    }
    __syncthreads();

    s8v af[3][MT], bf[3][NT];
    #pragma unroll
    for (int mt = 0; mt < MT; ++mt) {
      int r = wm * 64 + mt * 16 + (lane & 15);
      int off = r * 32 + (((lane >> 4) ^ ((r >> 1) & 3)) << 3);
      #pragma unroll
      for (int p = 0; p < 3; ++p) af[p][mt] = *(const s8v*)(lds + p * 4096 + off);
    }
    #pragma unroll
    for (int nt = 0; nt < NT; ++nt) {
      int r = wn * 32 + nt * 16 + (lane & 15);
      int off = r * 32 + (((lane >> 4) ^ ((r >> 1) & 3)) << 3);
      #pragma unroll
      for (int p = 0; p < 3; ++p) bf[p][nt] = *(const s8v*)(lds + 12288 + p * 4096 + off);
    }
    #pragma unroll
    for (int mt = 0; mt < MT; ++mt)
      #pragma unroll
      for (int nt = 0; nt < NT; ++nt) {
        f32x4 a = acc[mt][nt];
        a = __builtin_amdgcn_mfma_f32_16x16x32_bf16(af[0][mt], bf[0][nt], a, 0, 0, 0);
        a = __builtin_amdgcn_mfma_f32_16x16x32_bf16(af[0][mt], bf[1][nt], a, 0, 0, 0);
        a = __builtin_amdgcn_mfma_f32_16x16x32_bf16(af[1][mt], bf[0][nt], a, 0, 0, 0);
        a = __builtin_amdgcn_mfma_f32_16x16x32_bf16(af[1][mt], bf[1][nt], a, 0, 0, 0);
        a = __builtin_amdgcn_mfma_f32_16x16x32_bf16(af[0][mt], bf[2][nt], a, 0, 0, 0);
        a = __builtin_amdgcn_mfma_f32_16x16x32_bf16(af[2][mt], bf[0][nt], a, 0, 0, 0);
        acc[mt][nt] = a;
      }
  }

  // epilogue: direct keys into lds as [128][136], mirror keys packed in regs
  unsigned mk32[MT][NT][2];
  __syncthreads();
  u16* stD = lds;
  #pragma unroll
  for (int mt = 0; mt < MT; ++mt) {
    #pragma unroll
    for (int nt = 0; nt < NT; ++nt) {
      int cl = wn * 32 + nt * 16 + (lane & 15);
      float sqc = sq[n0 + cl];
      #pragma unroll
      for (int v = 0; v < 4; ++v) {
        int rl = wm * 64 + mt * 16 + (lane >> 4) * 4 + v;
        float val = acc[mt][nt][v];
        float f = fmaf(-2.f, val, sqc);
        unsigned uu = sortkey(f);
        if (m0 + rl == n0 + cl) uu = 0xFFFFFFFFu;
        stD[rl * 136 + cl] = (u16)(uu >> 16);
        if (mirror) {
          unsigned km = sortkey(fmaf(-2.f, val, sq[m0 + rl])) >> 16;
          if (v & 1) mk32[mt][nt][v >> 1] |= km << 16;
          else       mk32[mt][nt][v >> 1] = km;
        }
      }
    }
  }
  __syncthreads();
  for (int e = t; e < 128 * 16; e += 512) {
    int row = e >> 4, ch = e & 15;
    u32x4 vv = *(const u32x4*)(stD + row * 136 + ch * 8);
    *(u32x4*)(Ck + (size_t)(m0 + row) * ldC + n0 + ch * 8) = vv;
  }
  if (mirror) {
    __syncthreads();
    u16* stM = lds;
    #pragma unroll
    for (int mt = 0; mt < MT; ++mt) {
      #pragma unroll
      for (int nt = 0; nt < NT; ++nt) {
        int cl = wn * 32 + nt * 16 + (lane & 15);
        #pragma unroll
        for (int v = 0; v < 4; ++v) {
          int rl = wm * 64 + mt * 16 + (lane >> 4) * 4 + v;
          unsigned km = (v & 1) ? (mk32[mt][nt][v >> 1] >> 16)
                                : (mk32[mt][nt][v >> 1] & 0xFFFFu);
          stM[cl * 136 + rl] = (u16)km;
        }
      }
    }
    __syncthreads();
    for (int e = t; e < 128 * 16; e += 512) {
      int row = e >> 4, ch = e & 15;
      u32x4 vv = *(const u32x4*)(stM + row * 136 + ch * 8);
      *(u32x4*)(Ck + (size_t)(n0 + row) * ldC + m0 + ch * 8) = vv;
    }
  }
}

template<int S, bool BIAS, bool RELU, bool WF32, bool WSPLIT>
__global__ void combine(const float* __restrict__ P, const float* __restrict__ bias,
                        size_t MN, int Ncols,
                        float* __restrict__ Cf, u16* __restrict__ C0,
                        u16* __restrict__ C1, u16* __restrict__ C2)
{
  size_t idx = ((size_t)blockIdx.x * 256 + threadIdx.x) * 4;
  if (idx >= MN) return;
  f32x4 s = *(const f32x4*)(P + idx);
  #pragma unroll
  for (int z = 1; z < S; ++z) s += *(const f32x4*)(P + (size_t)z * MN + idx);
  int n = (int)(idx % (size_t)Ncols);
  #pragma unroll
  for (int e = 0; e < 4; ++e) {
    float v = s[e] + (BIAS ? bias[n + e] : 0.f);
    if (RELU) v = fmaxf(v, 0.f);
    if (WF32) Cf[idx + e] = v;
    if (WSPLIT) {
      u16 a0, a1, a2; split3(v, a0, a1, a2);
      C0[idx + e] = a0; C1[idx + e] = a1; C2[idx + e] = a2;
    }
  }
}

// weight transposes+splits AND head collapse in one launch
__global__ void prep_all(const float* __restrict__ W0, u16* __restrict__ a0,
                         u16* __restrict__ a1, u16* __restrict__ a2,
                         const float* __restrict__ W1, u16* __restrict__ b0,
                         u16* __restrict__ b1, u16* __restrict__ b2,
                         const float* __restrict__ gW, u16* __restrict__ c0,
                         u16* __restrict__ c1, u16* __restrict__ c2,
                         const float* __restrict__ cW, const float* __restrict__ cb,
                         const float* __restrict__ dW, const float* __restrict__ db,
                         float* __restrict__ Wc, float* __restrict__ bc)
{
  int id = blockIdx.x * 256 + threadIdx.x;
  const int S0 = D_IN * H1_DIM, S1 = H1_DIM * H2_DIM, S2 = H2_DIM * G_DIM;
  const int SW = S0 + S1 + S2;
  if (id < SW) {
    const float* W; u16 *p0, *p1, *p2; int K, N;
    if (id < S0)           { W = W0; p0 = a0; p1 = a1; p2 = a2; K = D_IN;   N = H1_DIM; }
    else if (id < S0 + S1) { id -= S0; W = W1; p0 = b0; p1 = b1; p2 = b2; K = H1_DIM; N = H2_DIM; }
    else                   { id -= S0 + S1; W = gW; p0 = c0; p1 = c1; p2 = c2; K = H2_DIM; N = G_DIM; }
    int k = id / N, n = id % N;
    u16 x0, x1, x2;
    split3(W[id], x0, x1, x2);
    size_t o = (size_t)n * K + k;
    p0[o] = x0; p1[o] = x1; p2[o] = x2;
    return;
  }
  id -= SW;
  if (id < 64 * NOUT) {
    int g = id / NOUT, c = id % NOUT;
    float s = 0.f;
    if (c < 16) {
      for (int r = 0; r < 8; ++r) s += cW[(r * 64 + g) * 16 + c];
    } else {
      int k = (c - 16) >> 1, o = (c - 16) & 1;
      for (int r = 0; r < 8; ++r) s += dW[k * 1024 + (r * 64 + g) * 2 + o];
    }
    Wc[id] = s;
    if (g == 0) bc[c] = (c < 16) ? cb[c] : db[c - 16];
  }
}

__global__ void row_stats(const float* __restrict__ h, const float* __restrict__ Wh,
                          const float* __restrict__ ga, float* __restrict__ sq,
                          float* __restrict__ f1, float* __restrict__ f2)
{
  int i = blockIdx.x * 256 + threadIdx.x;
  const float* hr = h + (size_t)i * H2_DIM;
  float s = 0.f;
  for (int k = 0; k < H2_DIM; ++k) { float v = hr[k]; s = fmaf(v, v, s); }
  sq[i] = s;
  const float* wr = Wh + (size_t)i * G_DIM;
  float a = 0.f, b = 0.f;
  for (int g = 0; g < G_DIM; ++g) {
    float w = wr[g];
    a = fmaf(w, ga[g], a);
    b = fmaf(w, ga[G_DIM + g], b);
  }
  f1[i] = a; f2[i] = b;
}

// ---------------------------------------------------------------------------
// u16-key topk (r19-proven), one wave per row, reversed row order.
// ---------------------------------------------------------------------------
__global__ __launch_bounds__(256) void topk_att(const u16* __restrict__ Sb,
    const float* __restrict__ f1, const float* __restrict__ f2,
    const float* __restrict__ Wh, const float* __restrict__ Wc, const float* __restrict__ bc,
    const float* __restrict__ sq, const float* __restrict__ hF,
    float* __restrict__ out, int m0, int nrows)
{
  const int t = threadIdx.x;
  const int lane = t & 63, wv = t >> 6;
  const int row4 = (nrows - 4 - blockIdx.x * 4) + wv;   // reversed mapping
  const int i = m0 + row4;
  const u16* Srow = Sb + (size_t)row4 * N_PTS;

  __shared__ float WcL[64 * NOUT];
  __shared__ unsigned candS[4][384];
  __shared__ u16 tieS[4][128];
  __shared__ float hiL[4][128];
  __shared__ int neighS[4][33];
  __shared__ float attS[4][33];
  __shared__ float hpfS[4][64];

  for (int idx = t; idx < 64 * NOUT; idx += 256) WcL[idx] = Wc[idx];
  __syncthreads();                       // only block barrier

  hiL[wv][lane]      = hF[(size_t)i * H2_DIM + lane];
  hiL[wv][64 + lane] = hF[(size_t)i * H2_DIM + 64 + lane];

  unsigned q[24];
  #pragma unroll
  for (int c = 0; c < 24; ++c) {
    u16x4 v = *(const u16x4*)(Srow + (c << 8) + (lane << 2));
    unsigned a = v[0] < v[1] ? (unsigned)v[0] : (unsigned)v[1];
    unsigned b = v[2] < v[3] ? (unsigned)v[2] : (unsigned)v[3];
    q[c] = a < b ? a : b;
  }

  unsigned lmin = q[0];
  #pragma unroll
  for (int c = 1; c < 24; ++c) lmin = q[c] < lmin ? q[c] : lmin;

  unsigned mnl = lmin, mxl = lmin;
  #pragma unroll
  for (int off = 32; off > 0; off >>= 1) {
    unsigned o1 = __shfl_xor(mnl, off); mnl = o1 < mnl ? o1 : mnl;
    unsigned o2 = __shfl_xor(mxl, off); mxl = o2 > mxl ? o2 : mxl;
  }

  long long lo = (long long)mnl - 1, hi = (long long)mxl;
  while (hi - lo > 1) {
    long long span = hi - lo;
    unsigned m1 = (unsigned)(lo + (span >> 2));
    unsigned m2 = (unsigned)(lo + (span >> 1));
    unsigned m3 = (unsigned)(hi - (span >> 2));
    int c1 = 0, c2 = 0, c3 = 0;
    #pragma unroll
    for (int c = 0; c < 24; ++c) {
      c1 += (q[c] <= m1);
      c2 += (q[c] <= m2);
      c3 += (q[c] <= m3);
    }
    #pragma unroll
    for (int off = 32; off > 0; off >>= 1) {
      c1 += __shfl_xor(c1, off);
      c2 += __shfl_xor(c2, off);
      c3 += __shfl_xor(c3, off);
    }
    if (c1 >= KNN)       { hi = m1; }
    else if (c2 >= KNN)  { lo = m1; hi = m2; }
    else if (c3 >= KNN)  { lo = m2; hi = m3; }
    else                 { lo = m3; }
  }
  const unsigned Q = (unsigned)hi;

  #pragma unroll
  for (int s = 0; s < 6; ++s) candS[wv][lane + s * 64] = 0xFFFFFFFFu;
  const u64 below = (lane == 0) ? 0ull : (~0ull >> (64 - lane));
  int qcnt = 0;
  #pragma unroll
  for (int c = 0; c < 24; ++c) {
    bool act = (q[c] <= Q);
    u64 mask = __ballot(act);
    if (act) {
      int pos = qcnt + (int)__popcll(mask & below);
      if (pos < 96) {
        u16x4 v = *(const u16x4*)(Srow + (c << 8) + (lane << 2));
        #pragma unroll
        for (int e = 0; e < 4; ++e) {
          int j = (c << 8) + (lane << 2) + e;
          candS[wv][pos * 4 + e] = ((unsigned)v[e] << 13) | (unsigned)j;
        }
      }
    }
    qcnt += (int)__popcll(mask);
  }

  unsigned ck[6];
  #pragma unroll
  for (int s = 0; s < 6; ++s) ck[s] = candS[wv][lane + s * 64];

  lo = -1; hi = 0x10000;
  while (hi - lo > 1) {
    long long span = hi - lo;
    unsigned m1 = (unsigned)(lo + (span >> 2));
    unsigned m2 = (unsigned)(lo + (span >> 1));
    unsigned m3 = (unsigned)(hi - (span >> 2));
    int c1 = 0, c2 = 0, c3 = 0;
    #pragma unroll
    for (int s = 0; s < 6; ++s) {
      unsigned k = ck[s] >> 13;
      c1 += (k <= m1);
      c2 += (k <= m2);
      c3 += (k <= m3);
    }
    #pragma unroll
    for (int off = 32; off > 0; off >>= 1) {
      c1 += __shfl_xor(c1, off);
      c2 += __shfl_xor(c2, off);
      c3 += __shfl_xor(c3, off);
    }
    if (c1 >= KNN)       { hi = m1; }
    else if (c2 >= KNN)  { lo = m1; hi = m2; }
    else if (c3 >= KNN)  { lo = m2; hi = m3; }
    else                 { lo = m3; }
  }
  const unsigned T = (unsigned)hi;

  int sA = 0, sB = 0;
  #pragma unroll
  for (int s = 0; s < 6; ++s) {
    unsigned k = ck[s] >> 13;
    bool strict = (k < T);
    u64 ms = __ballot(strict);
    if (strict) {
      int pos = sA + (int)__popcll(ms & below);
      if (pos < 32) neighS[wv][pos] = (int)(ck[s] & 0x1FFFu);
    }
    sA += (int)__popcll(ms);
    bool tie = (k == T);
    u64 mt2 = __ballot(tie);
    if (tie) {
      int pos = sB + (int)__popcll(mt2 & below);
      if (pos < 128) tieS[wv][pos] = (u16)(ck[s] & 0x1FFFu);
    }
    sB += (int)__popcll(mt2);
  }
  if (sB > 128) sB = 128;
  const int need = KNN - sA;

  u64 r0 = ~0ull, r1 = ~0ull;
  const float* hi0 = &hiL[wv][0];
  #pragma unroll
  for (int half = 0; half < 2; ++half) {
    int e = lane + half * 64;
    if (e < sB) {
      int j = tieS[wv][e];
      const float* hj = hF + (size_t)j * H2_DIM;
      float dot = 0.f;
      for (int d = 0; d < H2_DIM; d += 4) {
        f32x4 a = *(const f32x4*)(hi0 + d);
        f32x4 b = *(const f32x4*)(hj + d);
        dot = fmaf(a[0], b[0], fmaf(a[1], b[1], fmaf(a[2], b[2], fmaf(a[3], b[3], dot))));
      }
      float f = fmaf(-2.f, dot, sq[j]);
      u64 rk = ((u64)sortkey(f) << 13) | (unsigned)j;
      if (half == 0) r0 = rk; else r1 = rk;
    }
  }

  {
    candS[wv][lane] = (unsigned)(r0 >> 32); candS[wv][64 + lane] = (unsigned)r0;
    candS[wv][128 + lane] = (unsigned)(r1 >> 32); candS[wv][192 + lane] = (unsigned)r1;
    u64 v0 = ((u64)candS[wv][(2 * lane) >= 64 ? 128 + (2 * lane - 64) : 2 * lane] << 32)
           | candS[wv][(2 * lane) >= 64 ? 192 + (2 * lane - 64) : 64 + 2 * lane];
    u64 v1 = ((u64)candS[wv][(2 * lane + 1) >= 64 ? 128 + (2 * lane + 1 - 64) : 2 * lane + 1] << 32)
           | candS[wv][(2 * lane + 1) >= 64 ? 192 + (2 * lane + 1 - 64) : 64 + 2 * lane + 1];
    const int e0 = 2 * lane, e1 = e0 + 1;
    for (int k = 2; k <= 128; k <<= 1) {
      for (int j = k >> 1; j >= 2; j >>= 1) {
        int half = j >> 1;
        u64 o0 = __shfl_xor(v0, half);
        u64 o1 = __shfl_xor(v1, half);
        bool up0 = ((e0 & k) == 0) == ((e0 & j) == 0);
        bool up1 = ((e1 & k) == 0) == ((e1 & j) == 0);
        v0 = up0 ? (v0 < o0 ? v0 : o0) : (v0 > o0 ? v0 : o0);
        v1 = up1 ? (v1 < o1 ? v1 : o1) : (v1 > o1 ? v1 : o1);
      }
      bool asc = ((e0 & k) == 0);
      u64 a = v0 < v1 ? v0 : v1, b = v0 < v1 ? v1 : v0;
      v0 = asc ? a : b;
      v1 = asc ? b : a;
    }
    if (e0 < need) neighS[wv][sA + e0] = (int)(v0 & 0x1FFFu);
    if (e1 < need) neighS[wv][sA + e1] = (int)(v1 & 0x1FFFu);
  }
  if (lane == 0) neighS[wv][32] = i;

  {
    float e = -FLT_MAX;
    if (lane < 33) {
      float raw = f1[i] + f2[neighS[wv][lane]];
      e = raw > 0.f ? raw : 0.2f * raw;
    }
    float mx = e;
    #pragma unroll
    for (int off = 32; off > 0; off >>= 1) mx = fmaxf(mx, __shfl_xor(mx, off));
    float ex = (lane < 33) ? expf(e - mx) : 0.f;
    float sm = ex;
    #pragma unroll
    for (int off = 32; off > 0; off >>= 1) sm += __shfl_xor(sm, off);
    if (lane < 33) attS[wv][lane] = ex / sm;
  }

  {
    float s = 0.f;
    for (int m = 0; m < 33; ++m)
      s = fmaf(attS[wv][m], Wh[(size_t)neighS[wv][m] * G_DIM + lane], s);
    hpfS[wv][lane] = s > 0.f ? s : expm1f(s);
  }

  if (lane < NOUT) {
    float o = bc[lane];
    for (int g = 0; g < 64; ++g) o = fmaf(hpfS[wv][g], WcL[g * NOUT + lane], o);
    out[(size_t)i * NOUT + lane] = o;
  }
}

extern "C" void kernel_launch(void* const* d_in, const int* in_sizes, int n_in,
                              void* d_out, int out_size, void* d_ws, size_t ws_size,
                              hipStream_t stream)
{
  const float* x  = (const float*)d_in[0];
  const float* W0 = (const float*)d_in[1];
  const float* b0 = (const float*)d_in[2];
  const float* W1 = (const float*)d_in[3];
  const float* b1 = (const float*)d_in[4];
  const float* gW = (const float*)d_in[5];
  const float* ga = (const float*)d_in[6];
  const float* cW = (const float*)d_in[7];
  const float* cb = (const float*)d_in[8];
  const float* dW = (const float*)d_in[9];
  const float* db = (const float*)d_in[10];
  float* out = (float*)d_out;

  char* base = (char*)d_ws;
  char* w = base;
  auto alloc = [&](size_t bytes) { char* p = w; w += (bytes + 255) & ~(size_t)255; return p; };
  u16 *W0p[3], *W1p[3], *gWp[3], *h1p[3], *hp[3];
  for (int p = 0; p < 3; ++p) W0p[p] = (u16*)alloc((size_t)D_IN * H1_DIM * 2);
  for (int p = 0; p < 3; ++p) W1p[p] = (u16*)alloc((size_t)H1_DIM * H2_DIM * 2);
  for (int p = 0; p < 3; ++p) gWp[p] = (u16*)alloc((size_t)H2_DIM * G_DIM * 2);
  for (int p = 0; p < 3; ++p) h1p[p] = (u16*)alloc((size_t)N_PTS * H1_DIM * 2);
  for (int p = 0; p < 3; ++p) hp[p]  = (u16*)alloc((size_t)N_PTS * H2_DIM * 2);
  float* hF  = (float*)alloc((size_t)N_PTS * H2_DIM * 4);
  float* WhF = (float*)alloc((size_t)N_PTS * G_DIM * 4);
  float* sqv = (float*)alloc(N_PTS * 4);
  float* f1v = (float*)alloc(N_PTS * 4);
  float* f2v = (float*)alloc(N_PTS * 4);
  float* Wc  = (float*)alloc(64 * NOUT * 4);
  float* bc  = (float*)alloc(64 * 4);

  char* pbase = w;
  const size_t MN1 = (size_t)N_PTS * H1_DIM;
  const size_t MN2 = (size_t)N_PTS * H2_DIM;
  const size_t MN3 = (size_t)N_PTS * G_DIM;
  float* P1 = (float*)alloc(4 * MN1 * 4);
  float* P2 = (float*)alloc(4 * MN2 * 4);
  float* P3 = (float*)alloc(4 * MN3 * 4);
  u16* Sb = (u16*)pbase;

  const int TS = D_IN * H1_DIM + H1_DIM * H2_DIM + H2_DIM * G_DIM + 64 * NOUT;
  prep_all<<<(TS + 255) / 256, 256, 0, stream>>>(
      W0, W0p[0], W0p[1], W0p[2], W1, W1p[0], W1p[1], W1p[2], gW, gWp[0], gWp[1], gWp[2],
      cW, cb, dW, db, Wc, bc);

  mfma_gemm<64, true, true, false, false, false, false>
      <<<dim3(H1_DIM / 64, N_PTS / 64, 4), 256, 0, stream>>>(
      x, nullptr, nullptr, W0p[0], W0p[1], W0p[2], nullptr,
      P1, nullptr, nullptr, nullptr, D_IN, D_IN / 4, H1_DIM, MN1);
  combine<4, true, true, false, true><<<(int)(MN1 / 1024), 256, 0, stream>>>(
      P1, b0, MN1, H1_DIM, nullptr, h1p[0], h1p[1], h1p[2]);

  mfma_gemm<64, false, true, false, false, false, false>
      <<<dim3(H2_DIM / 64, N_PTS / 64, 4), 256, 0, stream>>>(
      h1p[0], h1p[1], h1p[2], W1p[0], W1p[1], W1p[2], nullptr,
      P2, nullptr, nullptr, nullptr, H1_DIM, H1_DIM / 4, H2_DIM, MN2);
  combine<4, true, true, true, true><<<(int)(MN2 / 1024), 256, 0, stream>>>(
      P2, b1, MN2, H2_DIM, hF, hp[0], hp[1], hp[2]);

  mfma_gemm<64, false, true, false, false, false, false>
      <<<dim3(G_DIM / 64, N_PTS / 64, 4), 256, 0, stream>>>(
      hp[0], hp[1], hp[2], gWp[0], gWp[1], gWp[2], nullptr,
      P3, nullptr, nullptr, nullptr, H2_DIM, H2_DIM / 4, G_DIM, MN3);
  combine<4, false, false, true, false><<<(int)(MN3 / 1024), 256, 0, stream>>>(
      P3, nullptr, MN3, G_DIM, WhF, nullptr, nullptr, nullptr);

  row_stats<<<N_PTS / 256, 256, 0, stream>>>(hF, WhF, ga, sqv, f1v, f2v);

  gram_symm<<<dim3(N_PTS / 128, N_PTS / 128), 512, 0, stream>>>(
      hp[0], hp[1], hp[2], sqv, Sb, N_PTS);
  topk_att<<<N_PTS / 4, 256, 0, stream>>>(Sb, f1v, f2v, WhF, Wc, bc, sqv, hF, out, 0, N_PTS);
}